// Round 3
// baseline (2025.884 us; speedup 1.0000x reference)
//
#include <hip/hip_runtime.h>
#include <math.h>

#define NN 50000
#define NE 800000
// D = 128, H = 256

typedef __attribute__((ext_vector_type(8))) short s8_t;   // 8 bf16
typedef __attribute__((ext_vector_type(4))) float f4_t;   // 4 fp32

__device__ __forceinline__ short bf16_rne(float v) {
  unsigned u = __float_as_uint(v);
  unsigned r = (u + 0x7FFFu + ((u >> 16) & 1u)) >> 16;
  return (short)r;
}
__device__ __forceinline__ float bf16_tof(short h) {
  return __uint_as_float(((unsigned)(unsigned short)h) << 16);
}
__device__ __forceinline__ void split2(float v, short& hi, short& lo) {
  hi = bf16_rne(v);
  lo = bf16_rne(v - bf16_tof(hi));
}

// ---------------- degree / norm prep ----------------

__global__ __launch_bounds__(256) void k_deg(const int* __restrict__ ei,
                                             const int* __restrict__ nei,
                                             const float* __restrict__ w,
                                             float* __restrict__ deg1,
                                             float* __restrict__ deg2) {
  int e = blockIdx.x * 256 + threadIdx.x;
  if (e < NE) {
    atomicAdd(&deg1[ei[NE + e]], w[e]);
    atomicAdd(&deg2[nei[NE + e]], 1.0f);
  }
}

__global__ __launch_bounds__(256) void k_dinv(float* __restrict__ d, int n) {
  int i = blockIdx.x * 256 + threadIdx.x;
  if (i < n) {
    float v = d[i];
    d[i] = v > 0.0f ? (1.0f / sqrtf(v)) : 0.0f;
  }
}

__global__ __launch_bounds__(256) void k_norm(const int* __restrict__ ei,
                                              const int* __restrict__ nei,
                                              const float* __restrict__ w,
                                              const float* __restrict__ dinv1,
                                              const float* __restrict__ dinv2,
                                              float* __restrict__ norm1,
                                              float* __restrict__ norm2) {
  int e = blockIdx.x * 256 + threadIdx.x;
  if (e < NE) {
    norm1[e] = dinv1[ei[e]] * w[e] * dinv1[ei[NE + e]];
    norm2[e] = dinv2[nei[e]] * dinv2[nei[NE + e]];
  }
}

// ---------------- weight split/transpose for decoder MFMA ----------------

__global__ __launch_bounds__(256) void k_wcvt(const float* __restrict__ W1,
                                              const float* __restrict__ W2,
                                              short* __restrict__ w1th,
                                              short* __restrict__ w1tl,
                                              short* __restrict__ w2th,
                                              short* __restrict__ w2tl) {
  int i = blockIdx.x * 256 + threadIdx.x;
  if (i < 32768) {
    int k = i >> 7, n = i & 127;
    short h, l; split2(W1[i], h, l);
    w1th[n * 256 + k] = h; w1tl[n * 256 + k] = l;
  } else if (i < 49152) {
    int j = i - 32768;
    int k = j >> 7, n = j & 127;
    short h, l; split2(W2[j], h, l);
    w2th[n * 128 + k] = h; w2tl[n * 128 + k] = l;
  }
}

// ---------------- layer1 scatter: aggX[c] += norm * emb[ids[r]]  (128-dim) ----

__global__ __launch_bounds__(256) void k_scatter1x(const float* __restrict__ emb,
                                                   const int* __restrict__ ids,
                                                   const int* __restrict__ ei,
                                                   const float* __restrict__ norm,
                                                   float* __restrict__ agg) {
  int t = threadIdx.x;
  int half = t >> 7, d = t & 127;
  int ebase = blockIdx.x * 16;
#pragma unroll
  for (int j = 0; j < 8; j++) {
    int e = ebase + j * 2 + half;
    float nv = norm[e];
    if (nv != 0.f) {
      int r = ei[e], c = ei[NE + e];
      float val = emb[(size_t)ids[r] * 128 + d] * nv;
      atomicAdd(agg + (size_t)c * 128 + d, val);
    }
  }
}

// ---------------- GEMM1: x1[N,256] = elu(aggX[N,128] @ W_in[128,256] + b) ------

__global__ __launch_bounds__(256) void k_gemm_aggin(const float* __restrict__ X,
                                                    const float* __restrict__ W,
                                                    const float* __restrict__ b,
                                                    float* __restrict__ C) {
  __shared__ float As[32][128];
  int r0 = blockIdx.x * 32;
  int t = threadIdx.x;
  for (int i = t; i < 1024; i += 256) {
    int r = i >> 5, q = (i & 31) << 2;
    int rr = r0 + r;
    float4 v = make_float4(0.f, 0.f, 0.f, 0.f);
    if (rr < NN) v = *(const float4*)(X + (size_t)rr * 128 + q);
    *(float4*)(&As[r][q]) = v;
  }
  __syncthreads();
  int tc = t & 31, tr = t >> 5;
  int c0 = tc * 8, rr0 = tr * 4;
  float acc[4][8];
#pragma unroll
  for (int r = 0; r < 4; r++)
#pragma unroll
    for (int c = 0; c < 8; c++) acc[r][c] = 0.f;

  for (int k0 = 0; k0 < 128; k0 += 4) {
    float a_[4][4];
#pragma unroll
    for (int r = 0; r < 4; r++) {
      float4 v = *(const float4*)(&As[rr0 + r][k0]);
      a_[r][0] = v.x; a_[r][1] = v.y; a_[r][2] = v.z; a_[r][3] = v.w;
    }
#pragma unroll
    for (int kk = 0; kk < 4; kk++) {
      float4 w0 = *(const float4*)(W + (size_t)(k0 + kk) * 256 + c0);
      float4 w1 = *(const float4*)(W + (size_t)(k0 + kk) * 256 + c0 + 4);
#pragma unroll
      for (int r = 0; r < 4; r++) {
        float av = a_[r][kk];
        acc[r][0] += av * w0.x; acc[r][1] += av * w0.y;
        acc[r][2] += av * w0.z; acc[r][3] += av * w0.w;
        acc[r][4] += av * w1.x; acc[r][5] += av * w1.y;
        acc[r][6] += av * w1.z; acc[r][7] += av * w1.w;
      }
    }
  }
  float4 bb0 = *(const float4*)(b + c0);
  float4 bb1 = *(const float4*)(b + c0 + 4);
#pragma unroll
  for (int r = 0; r < 4; r++) {
    int rr = r0 + rr0 + r;
    if (rr < NN) {
      float o[8];
      o[0] = acc[r][0] + bb0.x; o[1] = acc[r][1] + bb0.y;
      o[2] = acc[r][2] + bb0.z; o[3] = acc[r][3] + bb0.w;
      o[4] = acc[r][4] + bb1.x; o[5] = acc[r][5] + bb1.y;
      o[6] = acc[r][6] + bb1.z; o[7] = acc[r][7] + bb1.w;
#pragma unroll
      for (int c = 0; c < 8; c++) o[c] = o[c] > 0.f ? o[c] : expm1f(o[c]);
      *(float4*)(C + (size_t)rr * 256 + c0) = make_float4(o[0], o[1], o[2], o[3]);
      *(float4*)(C + (size_t)rr * 256 + c0 + 4) = make_float4(o[4], o[5], o[6], o[7]);
    }
  }
}

// ---------------- GEMM2: h2[N,128] = x1[N,256] @ W_out[256,128] ----------------

__global__ __launch_bounds__(256) void k_gemm_mid(const float* __restrict__ X,
                                                  const float* __restrict__ W,
                                                  float* __restrict__ C) {
  __shared__ float As[32][256];
  int r0 = blockIdx.x * 32;
  int t = threadIdx.x;
  for (int i = t; i < 2048; i += 256) {
    int r = i >> 6, q = (i & 63) << 2;
    int rr = r0 + r;
    float4 v = make_float4(0.f, 0.f, 0.f, 0.f);
    if (rr < NN) v = *(const float4*)(X + (size_t)rr * 256 + q);
    *(float4*)(&As[r][q]) = v;
  }
  __syncthreads();
  int tc = t & 31, tr = t >> 5;
  int c0 = tc * 4, rr0 = tr * 4;
  float acc[4][4];
#pragma unroll
  for (int r = 0; r < 4; r++)
#pragma unroll
    for (int c = 0; c < 4; c++) acc[r][c] = 0.f;

  for (int k0 = 0; k0 < 256; k0 += 4) {
    float a_[4][4];
#pragma unroll
    for (int r = 0; r < 4; r++) {
      float4 v = *(const float4*)(&As[rr0 + r][k0]);
      a_[r][0] = v.x; a_[r][1] = v.y; a_[r][2] = v.z; a_[r][3] = v.w;
    }
#pragma unroll
    for (int kk = 0; kk < 4; kk++) {
      float4 w = *(const float4*)(W + (size_t)(k0 + kk) * 128 + c0);
#pragma unroll
      for (int r = 0; r < 4; r++) {
        float av = a_[r][kk];
        acc[r][0] += av * w.x; acc[r][1] += av * w.y;
        acc[r][2] += av * w.z; acc[r][3] += av * w.w;
      }
    }
  }
#pragma unroll
  for (int r = 0; r < 4; r++) {
    int rr = r0 + rr0 + r;
    if (rr < NN) {
      float4 o = make_float4(acc[r][0], acc[r][1], acc[r][2], acc[r][3]);
      *(float4*)(C + (size_t)rr * 128 + c0) = o;
    }
  }
}

// ---------------- layer2 scatter (128-dim fp32 atomics) ----------------

__global__ __launch_bounds__(256) void k_scatter2(const float* __restrict__ h,
                                                  const int* __restrict__ nei,
                                                  const float* __restrict__ norm,
                                                  float* __restrict__ agg) {
  int t = threadIdx.x;
  int half = t >> 7, d = t & 127;
  int ebase = blockIdx.x * 16;
#pragma unroll
  for (int j = 0; j < 8; j++) {
    int e = ebase + j * 2 + half;
    float nv = norm[e];
    if (nv != 0.f) {
      int r = nei[e], c = nei[NE + e];
      float val = h[(size_t)r * 128 + d] * nv;
      atomicAdd(agg + (size_t)c * 128 + d, val);
    }
  }
}

// ---------------- bias + ELU + bf16 hi/lo split (decoder input) ----------------

__global__ __launch_bounds__(256) void k_x2cvt(const float* __restrict__ X,
                                               const float* __restrict__ b,
                                               short* __restrict__ xh,
                                               short* __restrict__ xl) {
  int i = blockIdx.x * 256 + threadIdx.x;
  float v = X[i] + b[i & 127];
  v = v > 0.f ? v : expm1f(v);
  short h, l; split2(v, h, l);
  xh[i] = h; xl[i] = l;
}

// ---------------- fused edge decoder, split-bf16 MFMA, pipelined tiles ---------
// 2500 blocks x 10 tiles x 32 edges. 256 thr (4 waves), wave w owns cols
// [w*32, w*32+32). Next tile's gathers prefetched into regs during MFMA.

#define SA 264   // concat-feature LDS stride (shorts)
#define ST 136   // layer-1 output stride (shorts)
#define S2 132   // layer-2 output fp32 stride (floats)
#define TILES 10

__global__ __launch_bounds__(256, 3) void k_decoder(
    const short* __restrict__ xh, const short* __restrict__ xl,
    const int* __restrict__ ei,
    const short* __restrict__ w1th, const short* __restrict__ w1tl,
    const float* __restrict__ b1,
    const short* __restrict__ w2th, const short* __restrict__ w2tl,
    const float* __restrict__ b2,
    const float* __restrict__ W3, const float* __restrict__ b3,
    float* __restrict__ out) {
  __shared__ short Ah[32 * SA];
  __shared__ short Al[32 * SA];
  __shared__ short Th[32 * ST];
  __shared__ short Tl[32 * ST];
  float* T2 = (float*)Ah;   // aliases Ah (dead by the time T2 is written)

  int t = threadIdx.x;
  int w = t >> 6, lane = t & 63;
  int quad = lane >> 4, l16 = lane & 15;
  int nb = w * 32;

  float b1v0 = b1[nb + l16], b1v1 = b1[nb + 16 + l16];
  float b2v0 = b2[nb + l16], b2v1 = b2[nb + 16 + l16];
  float b3v = b3[0];

  int aoff0 = (0 + l16) * SA + quad * 8;
  int aoff1 = (16 + l16) * SA + quad * 8;
  int boff0 = (nb + l16) * 256 + quad * 8;
  int boff1 = (nb + 16 + l16) * 256 + quad * 8;
  int toff0 = (0 + l16) * ST + quad * 8;
  int toff1 = (16 + l16) * ST + quad * 8;
  int coff0 = (nb + l16) * 128 + quad * 8;
  int coff1 = (nb + 16 + l16) * 128 + quad * 8;

  int tile0 = blockIdx.x * TILES;
  uint4 buf[8];

  // prologue: gather tile 0 into regs
  {
    int e0 = tile0 * 32;
#pragma unroll
    for (int j = 0; j < 8; j++) {
      int i = t + 256 * j;
      int arr = i >> 10, rem = i & 1023, le = rem >> 5, q = rem & 31;
      int node = (q < 16) ? ei[e0 + le] : ei[NE + e0 + le];
      const short* src = (arr ? xl : xh) + (size_t)node * 128 + (q & 15) * 8;
      buf[j] = *(const uint4*)src;
    }
  }

  for (int tt = 0; tt < TILES; tt++) {
    int e0 = (tile0 + tt) * 32;
    __syncthreads();   // LDS (incl. T2-aliased Ah) free from previous tile

    // regs -> LDS
#pragma unroll
    for (int j = 0; j < 8; j++) {
      int i = t + 256 * j;
      int arr = i >> 10, rem = i & 1023, le = rem >> 5, q = rem & 31;
      short* dst = (arr ? Al : Ah) + le * SA + q * 8;
      *(uint4*)dst = buf[j];
    }
    __syncthreads();

    // prefetch next tile's gathers (overlaps with MFMA below)
    if (tt + 1 < TILES) {
      int e1 = e0 + 32;
#pragma unroll
      for (int j = 0; j < 8; j++) {
        int i = t + 256 * j;
        int arr = i >> 10, rem = i & 1023, le = rem >> 5, q = rem & 31;
        int node = (q < 16) ? ei[e1 + le] : ei[NE + e1 + le];
        const short* src = (arr ? xl : xh) + (size_t)node * 128 + (q & 15) * 8;
        buf[j] = *(const uint4*)src;
      }
    }

    // ---- layer 1: [32,256] @ W1[256,128] (hi*hi + hi*lo + lo*hi) ----
    f4_t acc[2][2];
#pragma unroll
    for (int mi = 0; mi < 2; mi++)
#pragma unroll
      for (int ni = 0; ni < 2; ni++) acc[mi][ni] = (f4_t){0.f, 0.f, 0.f, 0.f};

#pragma unroll
    for (int k0 = 0; k0 < 256; k0 += 32) {
      s8_t ah0 = *(const s8_t*)&Ah[aoff0 + k0];
      s8_t ah1 = *(const s8_t*)&Ah[aoff1 + k0];
      s8_t al0 = *(const s8_t*)&Al[aoff0 + k0];
      s8_t al1 = *(const s8_t*)&Al[aoff1 + k0];
      s8_t bh0 = *(const s8_t*)(w1th + boff0 + k0);
      s8_t bh1 = *(const s8_t*)(w1th + boff1 + k0);
      s8_t bl0 = *(const s8_t*)(w1tl + boff0 + k0);
      s8_t bl1 = *(const s8_t*)(w1tl + boff1 + k0);
      acc[0][0] = __builtin_amdgcn_mfma_f32_16x16x32_bf16(ah0, bh0, acc[0][0], 0, 0, 0);
      acc[0][0] = __builtin_amdgcn_mfma_f32_16x16x32_bf16(ah0, bl0, acc[0][0], 0, 0, 0);
      acc[0][0] = __builtin_amdgcn_mfma_f32_16x16x32_bf16(al0, bh0, acc[0][0], 0, 0, 0);
      acc[0][1] = __builtin_amdgcn_mfma_f32_16x16x32_bf16(ah0, bh1, acc[0][1], 0, 0, 0);
      acc[0][1] = __builtin_amdgcn_mfma_f32_16x16x32_bf16(ah0, bl1, acc[0][1], 0, 0, 0);
      acc[0][1] = __builtin_amdgcn_mfma_f32_16x16x32_bf16(al0, bh1, acc[0][1], 0, 0, 0);
      acc[1][0] = __builtin_amdgcn_mfma_f32_16x16x32_bf16(ah1, bh0, acc[1][0], 0, 0, 0);
      acc[1][0] = __builtin_amdgcn_mfma_f32_16x16x32_bf16(ah1, bl0, acc[1][0], 0, 0, 0);
      acc[1][0] = __builtin_amdgcn_mfma_f32_16x16x32_bf16(al1, bh0, acc[1][0], 0, 0, 0);
      acc[1][1] = __builtin_amdgcn_mfma_f32_16x16x32_bf16(ah1, bh1, acc[1][1], 0, 0, 0);
      acc[1][1] = __builtin_amdgcn_mfma_f32_16x16x32_bf16(ah1, bl1, acc[1][1], 0, 0, 0);
      acc[1][1] = __builtin_amdgcn_mfma_f32_16x16x32_bf16(al1, bh1, acc[1][1], 0, 0, 0);
    }

    // bias + relu + split -> Th/Tl
#pragma unroll
    for (int mi = 0; mi < 2; mi++)
#pragma unroll
      for (int ni = 0; ni < 2; ni++) {
        float bv = ni ? b1v1 : b1v0;
        int col = nb + ni * 16 + l16;
#pragma unroll
        for (int r = 0; r < 4; r++) {
          int row = mi * 16 + quad * 4 + r;
          float v = fmaxf(acc[mi][ni][r] + bv, 0.f);
          short h, l; split2(v, h, l);
          Th[row * ST + col] = h;
          Tl[row * ST + col] = l;
        }
      }
    __syncthreads();

    // ---- layer 2: [32,128] @ W2[128,128] ----
    f4_t acc2[2][2];
#pragma unroll
    for (int mi = 0; mi < 2; mi++)
#pragma unroll
      for (int ni = 0; ni < 2; ni++) acc2[mi][ni] = (f4_t){0.f, 0.f, 0.f, 0.f};

#pragma unroll
    for (int k0 = 0; k0 < 128; k0 += 32) {
      s8_t ah0 = *(const s8_t*)&Th[toff0 + k0];
      s8_t ah1 = *(const s8_t*)&Th[toff1 + k0];
      s8_t al0 = *(const s8_t*)&Tl[toff0 + k0];
      s8_t al1 = *(const s8_t*)&Tl[toff1 + k0];
      s8_t bh0 = *(const s8_t*)(w2th + coff0 + k0);
      s8_t bh1 = *(const s8_t*)(w2th + coff1 + k0);
      s8_t bl0 = *(const s8_t*)(w2tl + coff0 + k0);
      s8_t bl1 = *(const s8_t*)(w2tl + coff1 + k0);
      acc2[0][0] = __builtin_amdgcn_mfma_f32_16x16x32_bf16(ah0, bh0, acc2[0][0], 0, 0, 0);
      acc2[0][0] = __builtin_amdgcn_mfma_f32_16x16x32_bf16(ah0, bl0, acc2[0][0], 0, 0, 0);
      acc2[0][0] = __builtin_amdgcn_mfma_f32_16x16x32_bf16(al0, bh0, acc2[0][0], 0, 0, 0);
      acc2[0][1] = __builtin_amdgcn_mfma_f32_16x16x32_bf16(ah0, bh1, acc2[0][1], 0, 0, 0);
      acc2[0][1] = __builtin_amdgcn_mfma_f32_16x16x32_bf16(ah0, bl1, acc2[0][1], 0, 0, 0);
      acc2[0][1] = __builtin_amdgcn_mfma_f32_16x16x32_bf16(al0, bh1, acc2[0][1], 0, 0, 0);
      acc2[1][0] = __builtin_amdgcn_mfma_f32_16x16x32_bf16(ah1, bh0, acc2[1][0], 0, 0, 0);
      acc2[1][0] = __builtin_amdgcn_mfma_f32_16x16x32_bf16(ah1, bl0, acc2[1][0], 0, 0, 0);
      acc2[1][0] = __builtin_amdgcn_mfma_f32_16x16x32_bf16(al1, bh0, acc2[1][0], 0, 0, 0);
      acc2[1][1] = __builtin_amdgcn_mfma_f32_16x16x32_bf16(ah1, bh1, acc2[1][1], 0, 0, 0);
      acc2[1][1] = __builtin_amdgcn_mfma_f32_16x16x32_bf16(ah1, bl1, acc2[1][1], 0, 0, 0);
      acc2[1][1] = __builtin_amdgcn_mfma_f32_16x16x32_bf16(al1, bh1, acc2[1][1], 0, 0, 0);
    }
    __syncthreads();   // Th/Tl reads done; T2 (alias Ah) safe to write

    // bias + relu -> T2 (fp32)
#pragma unroll
    for (int mi = 0; mi < 2; mi++)
#pragma unroll
      for (int ni = 0; ni < 2; ni++) {
        float bv = ni ? b2v1 : b2v0;
        int col = nb + ni * 16 + l16;
#pragma unroll
        for (int r = 0; r < 4; r++) {
          int row = mi * 16 + quad * 4 + r;
          T2[row * S2 + col] = fmaxf(acc2[mi][ni][r] + bv, 0.f);
        }
      }
    __syncthreads();

    // ---- layer 3: out[e] = dot(t2[e], W3) + b3 ----
    {
      int le = t >> 3, j0 = (t & 7) * 16;
      float s = 0.f;
#pragma unroll
      for (int j = 0; j < 16; j += 4) {
        float4 v = *(const float4*)(&T2[le * S2 + j0 + j]);
        float4 wv = *(const float4*)(W3 + j0 + j);
        s += v.x * wv.x + v.y * wv.y + v.z * wv.z + v.w * wv.w;
      }
      s += __shfl_down(s, 4);
      s += __shfl_down(s, 2);
      s += __shfl_down(s, 1);
      if ((t & 7) == 0) out[e0 + le] = s + b3v;
    }
  }
}

// ---------------- launch ----------------

extern "C" void kernel_launch(void* const* d_in, const int* in_sizes, int n_in,
                              void* d_out, int out_size, void* d_ws, size_t ws_size,
                              hipStream_t stream) {
  const int*   node_ids = (const int*)d_in[0];
  const int*   ei       = (const int*)d_in[1];
  const int*   nei      = (const int*)d_in[2];
  const float* eattr    = (const float*)d_in[3];
  const float* emb      = (const float*)d_in[4];
  const float* W_in     = (const float*)d_in[5];
  const float* b_in     = (const float*)d_in[6];
  const float* W_out    = (const float*)d_in[7];
  const float* b_out    = (const float*)d_in[8];
  const float* W1       = (const float*)d_in[9];
  const float* b1       = (const float*)d_in[10];
  const float* W2       = (const float*)d_in[11];
  const float* b2       = (const float*)d_in[12];
  const float* W3       = (const float*)d_in[13];
  const float* b3       = (const float*)d_in[14];
  float* out = (float*)d_out;

  // workspace (floats): bufA[N*256] | bufB[N*256] | norm1[E] | norm2[E]
  //                     | dinv1[N] | dinv2[N] | bf16 weight tables
  float* ws    = (float*)d_ws;
  float* bufA  = ws;
  float* bufB  = bufA + (size_t)NN * 256;
  float* norm1 = bufB + (size_t)NN * 256;
  float* norm2 = norm1 + NE;
  float* dinv1 = norm2 + NE;
  float* dinv2 = dinv1 + NN;
  short* w1th  = (short*)(dinv2 + NN);
  short* w1tl  = w1th + 32768;
  short* w2th  = w1tl + 32768;
  short* w2tl  = w2th + 16384;

  float* aggX  = bufA;                       // N*128 (layer1 aggregate)
  float* h2    = bufA;                       // N*128 (overwrites aggX, dead then)
  float* aggB  = bufA + (size_t)NN * 128;    // N*128 (layer2 aggregate)
  short* x2h   = (short*)bufB;               // bufB dead after gemm_mid
  short* x2l   = x2h + (size_t)NN * 128;

  // weight split
  k_wcvt<<<192, 256, 0, stream>>>(W1, W2, w1th, w1tl, w2th, w2tl);

  // degrees -> dinv -> norms
  hipMemsetAsync(dinv1, 0, 2 * (size_t)NN * sizeof(float), stream);
  k_deg<<<NE / 256, 256, 0, stream>>>(ei, nei, eattr, dinv1, dinv2);
  k_dinv<<<(2 * NN + 255) / 256, 256, 0, stream>>>(dinv1, 2 * NN);
  k_norm<<<NE / 256, 256, 0, stream>>>(ei, nei, eattr, dinv1, dinv2, norm1, norm2);

  // layer 1: aggregate-first (128-dim), then GEMM + bias + ELU
  hipMemsetAsync(aggX, 0, (size_t)NN * 128 * sizeof(float), stream);
  k_scatter1x<<<NE / 16, 256, 0, stream>>>(emb, node_ids, ei, norm1, aggX);
  k_gemm_aggin<<<(NN + 31) / 32, 256, 0, stream>>>(aggX, W_in, b_in, bufB);

  // layer 2: transform-first (h2 = x1 @ W_out), aggregate, bias+ELU+split
  k_gemm_mid<<<(NN + 31) / 32, 256, 0, stream>>>(bufB, W_out, h2);
  hipMemsetAsync(aggB, 0, (size_t)NN * 128 * sizeof(float), stream);
  k_scatter2<<<NE / 16, 256, 0, stream>>>(h2, nei, norm2, aggB);
  k_x2cvt<<<NN * 128 / 256, 256, 0, stream>>>(aggB, b_out, x2h, x2l);

  // decoder (pipelined split-bf16 MFMA)
  k_decoder<<<NE / 32 / TILES, 256, 0, stream>>>(x2h, x2l, ei,
                                                 w1th, w1tl, b1,
                                                 w2th, w2tl, b2,
                                                 W3, b3, out);
}

// Round 4
// 1582.965 us; speedup vs baseline: 1.2798x; 1.2798x over previous
//
#include <hip/hip_runtime.h>
#include <math.h>

#define NN 50000
#define NE 800000
// D = 128, H = 256

typedef __attribute__((ext_vector_type(8))) short s8_t;   // 8 bf16
typedef __attribute__((ext_vector_type(4))) float f4_t;   // 4 fp32

__device__ __forceinline__ short bf16_rne(float v) {
  unsigned u = __float_as_uint(v);
  unsigned r = (u + 0x7FFFu + ((u >> 16) & 1u)) >> 16;
  return (short)r;
}
__device__ __forceinline__ float bf16_tof(short h) {
  return __uint_as_float(((unsigned)(unsigned short)h) << 16);
}
__device__ __forceinline__ void split2(float v, short& hi, short& lo) {
  hi = bf16_rne(v);
  lo = bf16_rne(v - bf16_tof(hi));
}

// ---------------- degree / norm prep ----------------

__global__ __launch_bounds__(256) void k_deg(const int* __restrict__ ei,
                                             const int* __restrict__ nei,
                                             const float* __restrict__ w,
                                             float* __restrict__ deg1,
                                             float* __restrict__ deg2) {
  int e = blockIdx.x * 256 + threadIdx.x;
  if (e < NE) {
    atomicAdd(&deg1[ei[NE + e]], w[e]);
    atomicAdd(&deg2[nei[NE + e]], 1.0f);
  }
}

__global__ __launch_bounds__(256) void k_dinv(float* __restrict__ d, int n) {
  int i = blockIdx.x * 256 + threadIdx.x;
  if (i < n) {
    float v = d[i];
    d[i] = v > 0.0f ? (1.0f / sqrtf(v)) : 0.0f;
  }
}

__global__ __launch_bounds__(256) void k_norm(const int* __restrict__ ei,
                                              const int* __restrict__ nei,
                                              const float* __restrict__ w,
                                              const float* __restrict__ dinv1,
                                              const float* __restrict__ dinv2,
                                              float* __restrict__ norm1,
                                              float* __restrict__ norm2) {
  int e = blockIdx.x * 256 + threadIdx.x;
  if (e < NE) {
    norm1[e] = dinv1[ei[e]] * w[e] * dinv1[ei[NE + e]];
    norm2[e] = dinv2[nei[e]] * dinv2[nei[NE + e]];
  }
}

// ---------------- weight split/transpose for decoder MFMA ----------------

__global__ __launch_bounds__(256) void k_wcvt(const float* __restrict__ W1,
                                              const float* __restrict__ W2,
                                              short* __restrict__ w1th,
                                              short* __restrict__ w1tl,
                                              short* __restrict__ w2th,
                                              short* __restrict__ w2tl) {
  int i = blockIdx.x * 256 + threadIdx.x;
  if (i < 32768) {
    int k = i >> 7, n = i & 127;
    short h, l; split2(W1[i], h, l);
    w1th[n * 256 + k] = h; w1tl[n * 256 + k] = l;
  } else if (i < 49152) {
    int j = i - 32768;
    int k = j >> 7, n = j & 127;
    short h, l; split2(W2[j], h, l);
    w2th[n * 128 + k] = h; w2tl[n * 128 + k] = l;
  }
}

// ---------------- layer1 scatter: aggX[c] += norm * emb[ids[r]]  (128-dim) ----

__global__ __launch_bounds__(256) void k_scatter1x(const float* __restrict__ emb,
                                                   const int* __restrict__ ids,
                                                   const int* __restrict__ ei,
                                                   const float* __restrict__ norm,
                                                   float* __restrict__ agg) {
  int t = threadIdx.x;
  int half = t >> 7, d = t & 127;
  int ebase = blockIdx.x * 16;
#pragma unroll
  for (int j = 0; j < 8; j++) {
    int e = ebase + j * 2 + half;
    float nv = norm[e];
    if (nv != 0.f) {
      int r = ei[e], c = ei[NE + e];
      float val = emb[(size_t)ids[r] * 128 + d] * nv;
      atomicAdd(agg + (size_t)c * 128 + d, val);
    }
  }
}

// ---------------- GEMM1: x1[N,256] = elu(aggX[N,128] @ W_in[128,256] + b) ------

__global__ __launch_bounds__(256) void k_gemm_aggin(const float* __restrict__ X,
                                                    const float* __restrict__ W,
                                                    const float* __restrict__ b,
                                                    float* __restrict__ C) {
  __shared__ float As[32][128];
  int r0 = blockIdx.x * 32;
  int t = threadIdx.x;
  for (int i = t; i < 1024; i += 256) {
    int r = i >> 5, q = (i & 31) << 2;
    int rr = r0 + r;
    float4 v = make_float4(0.f, 0.f, 0.f, 0.f);
    if (rr < NN) v = *(const float4*)(X + (size_t)rr * 128 + q);
    *(float4*)(&As[r][q]) = v;
  }
  __syncthreads();
  int tc = t & 31, tr = t >> 5;
  int c0 = tc * 8, rr0 = tr * 4;
  float acc[4][8];
#pragma unroll
  for (int r = 0; r < 4; r++)
#pragma unroll
    for (int c = 0; c < 8; c++) acc[r][c] = 0.f;

  for (int k0 = 0; k0 < 128; k0 += 4) {
    float a_[4][4];
#pragma unroll
    for (int r = 0; r < 4; r++) {
      float4 v = *(const float4*)(&As[rr0 + r][k0]);
      a_[r][0] = v.x; a_[r][1] = v.y; a_[r][2] = v.z; a_[r][3] = v.w;
    }
#pragma unroll
    for (int kk = 0; kk < 4; kk++) {
      float4 w0 = *(const float4*)(W + (size_t)(k0 + kk) * 256 + c0);
      float4 w1 = *(const float4*)(W + (size_t)(k0 + kk) * 256 + c0 + 4);
#pragma unroll
      for (int r = 0; r < 4; r++) {
        float av = a_[r][kk];
        acc[r][0] += av * w0.x; acc[r][1] += av * w0.y;
        acc[r][2] += av * w0.z; acc[r][3] += av * w0.w;
        acc[r][4] += av * w1.x; acc[r][5] += av * w1.y;
        acc[r][6] += av * w1.z; acc[r][7] += av * w1.w;
      }
    }
  }
  float4 bb0 = *(const float4*)(b + c0);
  float4 bb1 = *(const float4*)(b + c0 + 4);
#pragma unroll
  for (int r = 0; r < 4; r++) {
    int rr = r0 + rr0 + r;
    if (rr < NN) {
      float o[8];
      o[0] = acc[r][0] + bb0.x; o[1] = acc[r][1] + bb0.y;
      o[2] = acc[r][2] + bb0.z; o[3] = acc[r][3] + bb0.w;
      o[4] = acc[r][4] + bb1.x; o[5] = acc[r][5] + bb1.y;
      o[6] = acc[r][6] + bb1.z; o[7] = acc[r][7] + bb1.w;
#pragma unroll
      for (int c = 0; c < 8; c++) o[c] = o[c] > 0.f ? o[c] : expm1f(o[c]);
      *(float4*)(C + (size_t)rr * 256 + c0) = make_float4(o[0], o[1], o[2], o[3]);
      *(float4*)(C + (size_t)rr * 256 + c0 + 4) = make_float4(o[4], o[5], o[6], o[7]);
    }
  }
}

// ---------------- GEMM2: h2[N,128] = x1[N,256] @ W_out[256,128] ----------------

__global__ __launch_bounds__(256) void k_gemm_mid(const float* __restrict__ X,
                                                  const float* __restrict__ W,
                                                  float* __restrict__ C) {
  __shared__ float As[32][256];
  int r0 = blockIdx.x * 32;
  int t = threadIdx.x;
  for (int i = t; i < 2048; i += 256) {
    int r = i >> 6, q = (i & 63) << 2;
    int rr = r0 + r;
    float4 v = make_float4(0.f, 0.f, 0.f, 0.f);
    if (rr < NN) v = *(const float4*)(X + (size_t)rr * 256 + q);
    *(float4*)(&As[r][q]) = v;
  }
  __syncthreads();
  int tc = t & 31, tr = t >> 5;
  int c0 = tc * 4, rr0 = tr * 4;
  float acc[4][4];
#pragma unroll
  for (int r = 0; r < 4; r++)
#pragma unroll
    for (int c = 0; c < 4; c++) acc[r][c] = 0.f;

  for (int k0 = 0; k0 < 256; k0 += 4) {
    float a_[4][4];
#pragma unroll
    for (int r = 0; r < 4; r++) {
      float4 v = *(const float4*)(&As[rr0 + r][k0]);
      a_[r][0] = v.x; a_[r][1] = v.y; a_[r][2] = v.z; a_[r][3] = v.w;
    }
#pragma unroll
    for (int kk = 0; kk < 4; kk++) {
      float4 w = *(const float4*)(W + (size_t)(k0 + kk) * 128 + c0);
#pragma unroll
      for (int r = 0; r < 4; r++) {
        float av = a_[r][kk];
        acc[r][0] += av * w.x; acc[r][1] += av * w.y;
        acc[r][2] += av * w.z; acc[r][3] += av * w.w;
      }
    }
  }
#pragma unroll
  for (int r = 0; r < 4; r++) {
    int rr = r0 + rr0 + r;
    if (rr < NN) {
      float4 o = make_float4(acc[r][0], acc[r][1], acc[r][2], acc[r][3]);
      *(float4*)(C + (size_t)rr * 128 + c0) = o;
    }
  }
}

// ---------------- layer2 scatter (128-dim fp32 atomics) ----------------

__global__ __launch_bounds__(256) void k_scatter2(const float* __restrict__ h,
                                                  const int* __restrict__ nei,
                                                  const float* __restrict__ norm,
                                                  float* __restrict__ agg) {
  int t = threadIdx.x;
  int half = t >> 7, d = t & 127;
  int ebase = blockIdx.x * 16;
#pragma unroll
  for (int j = 0; j < 8; j++) {
    int e = ebase + j * 2 + half;
    float nv = norm[e];
    if (nv != 0.f) {
      int r = nei[e], c = nei[NE + e];
      float val = h[(size_t)r * 128 + d] * nv;
      atomicAdd(agg + (size_t)c * 128 + d, val);
    }
  }
}

// ---------------- bias + ELU + bf16 hi/lo split (decoder input) ----------------

__global__ __launch_bounds__(256) void k_x2cvt(const float* __restrict__ X,
                                               const float* __restrict__ b,
                                               short* __restrict__ xh,
                                               short* __restrict__ xl) {
  int i = blockIdx.x * 256 + threadIdx.x;
  float v = X[i] + b[i & 127];
  v = v > 0.f ? v : expm1f(v);
  short h, l; split2(v, h, l);
  xh[i] = h; xl[i] = l;
}

// ---------------- fused edge decoder v3 ----------------
// Persistent: 2500 blocks x TILES tiles x 32 edges. 4 waves, wave w owns cols
// [w*32, w*32+32). Layer-1 HI weights live in registers (loaded once per block);
// lo / layer-2 weights are per-tile L2 loads (hoistable). Next tile's gather is
// issued mid-tile (after layer-1 LDS is dead) straight to LDS -> no reg buffer,
// no spill. T2 aliases Th/Tl (dead after layer-2), NOT Ah (holds prefetch).

#define SA 264   // concat-feature LDS stride (shorts)
#define ST 136   // layer-1 output stride (shorts)
#define S2 132   // layer-2 output fp32 stride (floats)
#define TILES 10

__global__ __launch_bounds__(256, 2) void k_decoder(
    const short* __restrict__ xh, const short* __restrict__ xl,
    const int* __restrict__ ei,
    const short* __restrict__ w1th, const short* __restrict__ w1tl,
    const float* __restrict__ b1,
    const short* __restrict__ w2th, const short* __restrict__ w2tl,
    const float* __restrict__ b2,
    const float* __restrict__ W3, const float* __restrict__ b3,
    float* __restrict__ out) {
  __shared__ short Ah[32 * SA];            // 16.9 KB  (tile t features, hi)
  __shared__ short Al[32 * SA];            // 16.9 KB  (lo)
  __shared__ short ThTl[2 * 32 * ST];      // 17.4 KB  (layer-1 out hi|lo)
  short* Th = ThTl;
  short* Tl = ThTl + 32 * ST;
  float* T2 = (float*)ThTl;                // 16.9 KB fp32, aliases Th/Tl (dead then)

  int t = threadIdx.x;
  int w = t >> 6, lane = t & 63;
  int quad = lane >> 4, l16 = lane & 15;
  int nb = w * 32;

  float b1v0 = b1[nb + l16], b1v1 = b1[nb + 16 + l16];
  float b2v0 = b2[nb + l16], b2v1 = b2[nb + 16 + l16];
  float b3v = b3[0];

  int aoff0 = (0 + l16) * SA + quad * 8;
  int aoff1 = (16 + l16) * SA + quad * 8;
  int boff0 = (nb + l16) * 256 + quad * 8;
  int boff1 = (nb + 16 + l16) * 256 + quad * 8;
  int toff0 = (0 + l16) * ST + quad * 8;
  int toff1 = (16 + l16) * ST + quad * 8;
  int coff0 = (nb + l16) * 128 + quad * 8;
  int coff1 = (nb + 16 + l16) * 128 + quad * 8;

  // ---- preload layer-1 HI weights into registers: 16 s8_t = 64 VGPRs ----
  s8_t w1h0[8], w1h1[8];
#pragma unroll
  for (int k = 0; k < 8; k++) {
    w1h0[k] = *(const s8_t*)(w1th + boff0 + k * 32);
    w1h1[k] = *(const s8_t*)(w1th + boff1 + k * 32);
  }

  int tile0 = blockIdx.x * TILES;

  // ---- prologue: gather tile 0 into LDS ----
  {
    int e0 = tile0 * 32;
#pragma unroll
    for (int j = 0; j < 8; j++) {
      int i = t + 256 * j;
      int arr = i >> 10, rem = i & 1023, le = rem >> 5, q = rem & 31;
      int node = (q < 16) ? ei[e0 + le] : ei[NE + e0 + le];
      const short* src = (arr ? xl : xh) + (size_t)node * 128 + (q & 15) * 8;
      short* dst = (arr ? Al : Ah) + le * SA + q * 8;
      *(uint4*)dst = *(const uint4*)src;
    }
  }

  for (int tt = 0; tt < TILES; tt++) {
    int e0 = (tile0 + tt) * 32;
    __syncthreads();   // (B1) gather writes visible; prev T2 reads done

    // ---- layer 1: [32,256] @ W1[256,128]  (hi regs; lo from L2) ----
    f4_t acc[2][2];
#pragma unroll
    for (int mi = 0; mi < 2; mi++)
#pragma unroll
      for (int ni = 0; ni < 2; ni++) acc[mi][ni] = (f4_t){0.f, 0.f, 0.f, 0.f};

#pragma unroll
    for (int kb = 0; kb < 8; kb++) {
      int k0 = kb * 32;
      s8_t ah0 = *(const s8_t*)&Ah[aoff0 + k0];
      s8_t ah1 = *(const s8_t*)&Ah[aoff1 + k0];
      s8_t al0 = *(const s8_t*)&Al[aoff0 + k0];
      s8_t al1 = *(const s8_t*)&Al[aoff1 + k0];
      s8_t bl0 = *(const s8_t*)(w1tl + boff0 + k0);
      s8_t bl1 = *(const s8_t*)(w1tl + boff1 + k0);
      s8_t bh0 = w1h0[kb];
      s8_t bh1 = w1h1[kb];
      acc[0][0] = __builtin_amdgcn_mfma_f32_16x16x32_bf16(ah0, bh0, acc[0][0], 0, 0, 0);
      acc[0][0] = __builtin_amdgcn_mfma_f32_16x16x32_bf16(ah0, bl0, acc[0][0], 0, 0, 0);
      acc[0][0] = __builtin_amdgcn_mfma_f32_16x16x32_bf16(al0, bh0, acc[0][0], 0, 0, 0);
      acc[0][1] = __builtin_amdgcn_mfma_f32_16x16x32_bf16(ah0, bh1, acc[0][1], 0, 0, 0);
      acc[0][1] = __builtin_amdgcn_mfma_f32_16x16x32_bf16(ah0, bl1, acc[0][1], 0, 0, 0);
      acc[0][1] = __builtin_amdgcn_mfma_f32_16x16x32_bf16(al0, bh1, acc[0][1], 0, 0, 0);
      acc[1][0] = __builtin_amdgcn_mfma_f32_16x16x32_bf16(ah1, bh0, acc[1][0], 0, 0, 0);
      acc[1][0] = __builtin_amdgcn_mfma_f32_16x16x32_bf16(ah1, bl0, acc[1][0], 0, 0, 0);
      acc[1][0] = __builtin_amdgcn_mfma_f32_16x16x32_bf16(al1, bh0, acc[1][0], 0, 0, 0);
      acc[1][1] = __builtin_amdgcn_mfma_f32_16x16x32_bf16(ah1, bh1, acc[1][1], 0, 0, 0);
      acc[1][1] = __builtin_amdgcn_mfma_f32_16x16x32_bf16(ah1, bl1, acc[1][1], 0, 0, 0);
      acc[1][1] = __builtin_amdgcn_mfma_f32_16x16x32_bf16(al1, bh1, acc[1][1], 0, 0, 0);
    }

    // bias + relu + split -> Th/Tl
#pragma unroll
    for (int mi = 0; mi < 2; mi++)
#pragma unroll
      for (int ni = 0; ni < 2; ni++) {
        float bv = ni ? b1v1 : b1v0;
        int col = nb + ni * 16 + l16;
#pragma unroll
        for (int r = 0; r < 4; r++) {
          int row = mi * 16 + quad * 4 + r;
          float v = fmaxf(acc[mi][ni][r] + bv, 0.f);
          short h, l; split2(v, h, l);
          Th[row * ST + col] = h;
          Tl[row * ST + col] = l;
        }
      }
    __syncthreads();   // (B2) Th/Tl ready; Ah/Al dead for all waves

    // ---- gather NEXT tile into Ah/Al (overlaps layer-2/3 compute) ----
    if (tt + 1 < TILES) {
      int e1 = e0 + 32;
#pragma unroll
      for (int j = 0; j < 8; j++) {
        int i = t + 256 * j;
        int arr = i >> 10, rem = i & 1023, le = rem >> 5, q = rem & 31;
        int node = (q < 16) ? ei[e1 + le] : ei[NE + e1 + le];
        const short* src = (arr ? xl : xh) + (size_t)node * 128 + (q & 15) * 8;
        short* dst = (arr ? Al : Ah) + le * SA + q * 8;
        *(uint4*)dst = *(const uint4*)src;
      }
    }

    // ---- layer 2: [32,128] @ W2[128,128] (B from L2) ----
    f4_t acc2[2][2];
#pragma unroll
    for (int mi = 0; mi < 2; mi++)
#pragma unroll
      for (int ni = 0; ni < 2; ni++) acc2[mi][ni] = (f4_t){0.f, 0.f, 0.f, 0.f};

#pragma unroll
    for (int kb = 0; kb < 4; kb++) {
      int k0 = kb * 32;
      s8_t ah0 = *(const s8_t*)&Th[toff0 + k0];
      s8_t ah1 = *(const s8_t*)&Th[toff1 + k0];
      s8_t al0 = *(const s8_t*)&Tl[toff0 + k0];
      s8_t al1 = *(const s8_t*)&Tl[toff1 + k0];
      s8_t bh0 = *(const s8_t*)(w2th + coff0 + k0);
      s8_t bh1 = *(const s8_t*)(w2th + coff1 + k0);
      s8_t bl0 = *(const s8_t*)(w2tl + coff0 + k0);
      s8_t bl1 = *(const s8_t*)(w2tl + coff1 + k0);
      acc2[0][0] = __builtin_amdgcn_mfma_f32_16x16x32_bf16(ah0, bh0, acc2[0][0], 0, 0, 0);
      acc2[0][0] = __builtin_amdgcn_mfma_f32_16x16x32_bf16(ah0, bl0, acc2[0][0], 0, 0, 0);
      acc2[0][0] = __builtin_amdgcn_mfma_f32_16x16x32_bf16(al0, bh0, acc2[0][0], 0, 0, 0);
      acc2[0][1] = __builtin_amdgcn_mfma_f32_16x16x32_bf16(ah0, bh1, acc2[0][1], 0, 0, 0);
      acc2[0][1] = __builtin_amdgcn_mfma_f32_16x16x32_bf16(ah0, bl1, acc2[0][1], 0, 0, 0);
      acc2[0][1] = __builtin_amdgcn_mfma_f32_16x16x32_bf16(al0, bh1, acc2[0][1], 0, 0, 0);
      acc2[1][0] = __builtin_amdgcn_mfma_f32_16x16x32_bf16(ah1, bh0, acc2[1][0], 0, 0, 0);
      acc2[1][0] = __builtin_amdgcn_mfma_f32_16x16x32_bf16(ah1, bl0, acc2[1][0], 0, 0, 0);
      acc2[1][0] = __builtin_amdgcn_mfma_f32_16x16x32_bf16(al1, bh0, acc2[1][0], 0, 0, 0);
      acc2[1][1] = __builtin_amdgcn_mfma_f32_16x16x32_bf16(ah1, bh1, acc2[1][1], 0, 0, 0);
      acc2[1][1] = __builtin_amdgcn_mfma_f32_16x16x32_bf16(ah1, bl1, acc2[1][1], 0, 0, 0);
      acc2[1][1] = __builtin_amdgcn_mfma_f32_16x16x32_bf16(al1, bh1, acc2[1][1], 0, 0, 0);
    }
    __syncthreads();   // (B3) all Th/Tl reads done -> T2 (alias) writable

    // bias + relu -> T2 (fp32)
#pragma unroll
    for (int mi = 0; mi < 2; mi++)
#pragma unroll
      for (int ni = 0; ni < 2; ni++) {
        float bv = ni ? b2v1 : b2v0;
        int col = nb + ni * 16 + l16;
#pragma unroll
        for (int r = 0; r < 4; r++) {
          int row = mi * 16 + quad * 4 + r;
          T2[row * S2 + col] = fmaxf(acc2[mi][ni][r] + bv, 0.f);
        }
      }
    __syncthreads();   // (B4) T2 ready

    // ---- layer 3: out[e] = dot(t2[e], W3) + b3 ----
    {
      int le = t >> 3, j0 = (t & 7) * 16;
      float s = 0.f;
#pragma unroll
      for (int j = 0; j < 16; j += 4) {
        float4 v = *(const float4*)(&T2[le * S2 + j0 + j]);
        float4 wv = *(const float4*)(W3 + j0 + j);
        s += v.x * wv.x + v.y * wv.y + v.z * wv.z + v.w * wv.w;
      }
      s += __shfl_down(s, 4);
      s += __shfl_down(s, 2);
      s += __shfl_down(s, 1);
      if ((t & 7) == 0) out[e0 + le] = s + b3v;
    }
  }
}

// ---------------- launch ----------------

extern "C" void kernel_launch(void* const* d_in, const int* in_sizes, int n_in,
                              void* d_out, int out_size, void* d_ws, size_t ws_size,
                              hipStream_t stream) {
  const int*   node_ids = (const int*)d_in[0];
  const int*   ei       = (const int*)d_in[1];
  const int*   nei      = (const int*)d_in[2];
  const float* eattr    = (const float*)d_in[3];
  const float* emb      = (const float*)d_in[4];
  const float* W_in     = (const float*)d_in[5];
  const float* b_in     = (const float*)d_in[6];
  const float* W_out    = (const float*)d_in[7];
  const float* b_out    = (const float*)d_in[8];
  const float* W1       = (const float*)d_in[9];
  const float* b1       = (const float*)d_in[10];
  const float* W2       = (const float*)d_in[11];
  const float* b2       = (const float*)d_in[12];
  const float* W3       = (const float*)d_in[13];
  const float* b3       = (const float*)d_in[14];
  float* out = (float*)d_out;

  float* ws    = (float*)d_ws;
  float* bufA  = ws;
  float* bufB  = bufA + (size_t)NN * 256;
  float* norm1 = bufB + (size_t)NN * 256;
  float* norm2 = norm1 + NE;
  float* dinv1 = norm2 + NE;
  float* dinv2 = dinv1 + NN;
  short* w1th  = (short*)(dinv2 + NN);
  short* w1tl  = w1th + 32768;
  short* w2th  = w1tl + 32768;
  short* w2tl  = w2th + 16384;

  float* aggX  = bufA;                       // N*128 (layer1 aggregate)
  float* h2    = bufA;                       // N*128 (overwrites aggX, dead then)
  float* aggB  = bufA + (size_t)NN * 128;    // N*128 (layer2 aggregate)
  short* x2h   = (short*)bufB;               // bufB dead after gemm_mid
  short* x2l   = x2h + (size_t)NN * 128;

  // weight split
  k_wcvt<<<192, 256, 0, stream>>>(W1, W2, w1th, w1tl, w2th, w2tl);

  // degrees -> dinv -> norms
  hipMemsetAsync(dinv1, 0, 2 * (size_t)NN * sizeof(float), stream);
  k_deg<<<NE / 256, 256, 0, stream>>>(ei, nei, eattr, dinv1, dinv2);
  k_dinv<<<(2 * NN + 255) / 256, 256, 0, stream>>>(dinv1, 2 * NN);
  k_norm<<<NE / 256, 256, 0, stream>>>(ei, nei, eattr, dinv1, dinv2, norm1, norm2);

  // layer 1: aggregate-first (128-dim), then GEMM + bias + ELU
  hipMemsetAsync(aggX, 0, (size_t)NN * 128 * sizeof(float), stream);
  k_scatter1x<<<NE / 16, 256, 0, stream>>>(emb, node_ids, ei, norm1, aggX);
  k_gemm_aggin<<<(NN + 31) / 32, 256, 0, stream>>>(aggX, W_in, b_in, bufB);

  // layer 2: transform-first (h2 = x1 @ W_out), aggregate, bias+ELU+split
  k_gemm_mid<<<(NN + 31) / 32, 256, 0, stream>>>(bufB, W_out, h2);
  hipMemsetAsync(aggB, 0, (size_t)NN * 128 * sizeof(float), stream);
  k_scatter2<<<NE / 16, 256, 0, stream>>>(h2, nei, norm2, aggB);
  k_x2cvt<<<NN * 128 / 256, 256, 0, stream>>>(aggB, b_out, x2h, x2l);

  // decoder v3 (persistent, reg-weights, mid-tile prefetch)
  k_decoder<<<NE / 32 / TILES, 256, 0, stream>>>(x2h, x2l, ei,
                                                 w1th, w1tl, b1,
                                                 w2th, w2tl, b2,
                                                 W3, b3, out);
}

// Round 5
// 1506.480 us; speedup vs baseline: 1.3448x; 1.0508x over previous
//
#include <hip/hip_runtime.h>
#include <math.h>

#define NN 50000
#define NE 800000
// D = 128, H = 256

typedef __attribute__((ext_vector_type(8))) short s8_t;   // 8 bf16
typedef __attribute__((ext_vector_type(4))) float f4_t;   // 4 fp32

__device__ __forceinline__ short bf16_rne(float v) {
  unsigned u = __float_as_uint(v);
  unsigned r = (u + 0x7FFFu + ((u >> 16) & 1u)) >> 16;
  return (short)r;
}
__device__ __forceinline__ float bf16_tof(short h) {
  return __uint_as_float(((unsigned)(unsigned short)h) << 16);
}
__device__ __forceinline__ void split2(float v, short& hi, short& lo) {
  hi = bf16_rne(v);
  lo = bf16_rne(v - bf16_tof(hi));
}

// ---------------- weight split/transpose for decoder MFMA ----------------

__global__ __launch_bounds__(256) void k_wcvt(const float* __restrict__ W1,
                                              const float* __restrict__ W2,
                                              short* __restrict__ w1th,
                                              short* __restrict__ w1tl,
                                              short* __restrict__ w2th,
                                              short* __restrict__ w2tl) {
  int i = blockIdx.x * 256 + threadIdx.x;
  if (i < 32768) {
    int k = i >> 7, n = i & 127;
    short h, l; split2(W1[i], h, l);
    w1th[n * 256 + k] = h; w1tl[n * 256 + k] = l;
  } else if (i < 49152) {
    int j = i - 32768;
    int k = j >> 7, n = j & 127;
    short h, l; split2(W2[j], h, l);
    w2th[n * 128 + k] = h; w2tl[n * 128 + k] = l;
  }
}

// ---------------- CSR build: histogram (also weighted degree) ----------------

__global__ __launch_bounds__(256) void k_hist(const int* __restrict__ ei,
                                              const int* __restrict__ nei,
                                              const float* __restrict__ w,
                                              int* __restrict__ cnt1,
                                              float* __restrict__ deg1,
                                              int* __restrict__ cnt2) {
  int e = blockIdx.x * 256 + threadIdx.x;
  if (e < NE) {
    int c1 = ei[NE + e];
    atomicAdd(&cnt1[c1], 1);
    atomicAdd(&deg1[c1], w[e]);
    atomicAdd(&cnt2[nei[NE + e]], 1);
  }
}

// ---------------- dinv for both graphs ----------------

__global__ __launch_bounds__(256) void k_dinvs(const float* __restrict__ deg1,
                                               const int* __restrict__ cnt2,
                                               float* __restrict__ dinv1,
                                               float* __restrict__ dinv2) {
  int i = blockIdx.x * 256 + threadIdx.x;
  if (i < NN) {
    float d1 = deg1[i];
    dinv1[i] = d1 > 0.f ? (1.0f / sqrtf(d1)) : 0.f;
    int c2 = cnt2[i];
    dinv2[i] = c2 > 0 ? (1.0f / sqrtf((float)c2)) : 0.f;
  }
}

// ---------------- exclusive prefix scan (single block, both graphs) ----------

__global__ __launch_bounds__(1024) void k_scan(const int* __restrict__ cnt1,
                                               int* __restrict__ off1,
                                               int* __restrict__ pos1,
                                               const int* __restrict__ cnt2,
                                               int* __restrict__ off2,
                                               int* __restrict__ pos2) {
  __shared__ int sd[1024];
  __shared__ int carry;
  int tid = threadIdx.x;
  for (int g = 0; g < 2; g++) {
    const int* cnt = g ? cnt2 : cnt1;
    int* off = g ? off2 : off1;
    int* pos = g ? pos2 : pos1;
    if (tid == 0) carry = 0;
    __syncthreads();
    for (int base = 0; base < NN; base += 1024) {
      int i = base + tid;
      int v = (i < NN) ? cnt[i] : 0;
      sd[tid] = v;
      __syncthreads();
      for (int ofs = 1; ofs < 1024; ofs <<= 1) {
        int x = (tid >= ofs) ? sd[tid - ofs] : 0;
        __syncthreads();
        sd[tid] += x;
        __syncthreads();
      }
      int incl = sd[tid];
      int c = carry;
      if (i < NN) { int ex = c + incl - v; off[i] = ex; pos[i] = ex; }
      __syncthreads();
      if (tid == 1023) carry = c + sd[1023];
      __syncthreads();
    }
    if (tid == 0) off[NN] = carry;
    __syncthreads();
  }
}

// ---------------- fill CSR (src + inline norm) ----------------

__global__ __launch_bounds__(256) void k_fill(const int* __restrict__ ei,
                                              const int* __restrict__ nei,
                                              const float* __restrict__ w,
                                              const float* __restrict__ dinv1,
                                              const float* __restrict__ dinv2,
                                              int* __restrict__ pos1,
                                              int* __restrict__ csr1_src,
                                              float* __restrict__ csr1_nrm,
                                              int* __restrict__ pos2,
                                              int* __restrict__ csr2_src,
                                              float* __restrict__ csr2_nrm) {
  int e = blockIdx.x * 256 + threadIdx.x;
  if (e < NE) {
    int r = ei[e], c = ei[NE + e];
    float nv = dinv1[r] * w[e] * dinv1[c];
    int s = atomicAdd(&pos1[c], 1);
    csr1_src[s] = r; csr1_nrm[s] = nv;
    int r2 = nei[e], c2 = nei[NE + e];
    float nv2 = dinv2[r2] * dinv2[c2];
    int s2 = atomicAdd(&pos2[c2], 1);
    csr2_src[s2] = r2; csr2_nrm[s2] = nv2;
  }
}

// ---------------- layer1 aggregate: aggX[n] = sum norm * emb[ids[src]] --------
// one wave per node, lane owns 2 dims (float2), zero atomics.

__global__ __launch_bounds__(256) void k_agg1(const int* __restrict__ off,
                                              const int* __restrict__ csr_src,
                                              const float* __restrict__ csr_nrm,
                                              const int* __restrict__ ids,
                                              const float* __restrict__ emb,
                                              float* __restrict__ aggX) {
  int wave = threadIdx.x >> 6, lane = threadIdx.x & 63;
  int node = blockIdx.x * 4 + wave;
  int start = off[node], end = off[node + 1];
  float2 acc = make_float2(0.f, 0.f);
  int i = start;
  for (; i + 1 < end; i += 2) {
    int s0 = csr_src[i], s1 = csr_src[i + 1];
    float n0 = csr_nrm[i], n1 = csr_nrm[i + 1];
    float2 v0 = *(const float2*)(emb + (size_t)ids[s0] * 128 + lane * 2);
    float2 v1 = *(const float2*)(emb + (size_t)ids[s1] * 128 + lane * 2);
    acc.x = fmaf(n0, v0.x, fmaf(n1, v1.x, acc.x));
    acc.y = fmaf(n0, v0.y, fmaf(n1, v1.y, acc.y));
  }
  if (i < end) {
    int s0 = csr_src[i];
    float n0 = csr_nrm[i];
    float2 v0 = *(const float2*)(emb + (size_t)ids[s0] * 128 + lane * 2);
    acc.x = fmaf(n0, v0.x, acc.x);
    acc.y = fmaf(n0, v0.y, acc.y);
  }
  *(float2*)(aggX + (size_t)node * 128 + lane * 2) = acc;
}

// ---------------- layer2 aggregate + bias + ELU + bf16 split ----------------

__global__ __launch_bounds__(256) void k_agg2(const int* __restrict__ off,
                                              const int* __restrict__ csr_src,
                                              const float* __restrict__ csr_nrm,
                                              const float* __restrict__ h2,
                                              const float* __restrict__ b,
                                              short* __restrict__ xh,
                                              short* __restrict__ xl) {
  int wave = threadIdx.x >> 6, lane = threadIdx.x & 63;
  int node = blockIdx.x * 4 + wave;
  int start = off[node], end = off[node + 1];
  float2 acc = make_float2(0.f, 0.f);
  int i = start;
  for (; i + 1 < end; i += 2) {
    int s0 = csr_src[i], s1 = csr_src[i + 1];
    float n0 = csr_nrm[i], n1 = csr_nrm[i + 1];
    float2 v0 = *(const float2*)(h2 + (size_t)s0 * 128 + lane * 2);
    float2 v1 = *(const float2*)(h2 + (size_t)s1 * 128 + lane * 2);
    acc.x = fmaf(n0, v0.x, fmaf(n1, v1.x, acc.x));
    acc.y = fmaf(n0, v0.y, fmaf(n1, v1.y, acc.y));
  }
  if (i < end) {
    int s0 = csr_src[i];
    float n0 = csr_nrm[i];
    float2 v0 = *(const float2*)(h2 + (size_t)s0 * 128 + lane * 2);
    acc.x = fmaf(n0, v0.x, acc.x);
    acc.y = fmaf(n0, v0.y, acc.y);
  }
  float vx = acc.x + b[lane * 2];
  float vy = acc.y + b[lane * 2 + 1];
  vx = vx > 0.f ? vx : expm1f(vx);
  vy = vy > 0.f ? vy : expm1f(vy);
  short hx, lx, hy, ly;
  split2(vx, hx, lx);
  split2(vy, hy, ly);
  unsigned hp = (unsigned)(unsigned short)hx | ((unsigned)(unsigned short)hy << 16);
  unsigned lp = (unsigned)(unsigned short)lx | ((unsigned)(unsigned short)ly << 16);
  *(unsigned*)(xh + (size_t)node * 128 + lane * 2) = hp;
  *(unsigned*)(xl + (size_t)node * 128 + lane * 2) = lp;
}

// ---------------- GEMM1: x1[N,256] = elu(aggX[N,128] @ W_in[128,256] + b) ------

__global__ __launch_bounds__(256) void k_gemm_aggin(const float* __restrict__ X,
                                                    const float* __restrict__ W,
                                                    const float* __restrict__ b,
                                                    float* __restrict__ C) {
  __shared__ float As[32][128];
  int r0 = blockIdx.x * 32;
  int t = threadIdx.x;
  for (int i = t; i < 1024; i += 256) {
    int r = i >> 5, q = (i & 31) << 2;
    int rr = r0 + r;
    float4 v = make_float4(0.f, 0.f, 0.f, 0.f);
    if (rr < NN) v = *(const float4*)(X + (size_t)rr * 128 + q);
    *(float4*)(&As[r][q]) = v;
  }
  __syncthreads();
  int tc = t & 31, tr = t >> 5;
  int c0 = tc * 8, rr0 = tr * 4;
  float acc[4][8];
#pragma unroll
  for (int r = 0; r < 4; r++)
#pragma unroll
    for (int c = 0; c < 8; c++) acc[r][c] = 0.f;

  for (int k0 = 0; k0 < 128; k0 += 4) {
    float a_[4][4];
#pragma unroll
    for (int r = 0; r < 4; r++) {
      float4 v = *(const float4*)(&As[rr0 + r][k0]);
      a_[r][0] = v.x; a_[r][1] = v.y; a_[r][2] = v.z; a_[r][3] = v.w;
    }
#pragma unroll
    for (int kk = 0; kk < 4; kk++) {
      float4 w0 = *(const float4*)(W + (size_t)(k0 + kk) * 256 + c0);
      float4 w1 = *(const float4*)(W + (size_t)(k0 + kk) * 256 + c0 + 4);
#pragma unroll
      for (int r = 0; r < 4; r++) {
        float av = a_[r][kk];
        acc[r][0] += av * w0.x; acc[r][1] += av * w0.y;
        acc[r][2] += av * w0.z; acc[r][3] += av * w0.w;
        acc[r][4] += av * w1.x; acc[r][5] += av * w1.y;
        acc[r][6] += av * w1.z; acc[r][7] += av * w1.w;
      }
    }
  }
  float4 bb0 = *(const float4*)(b + c0);
  float4 bb1 = *(const float4*)(b + c0 + 4);
#pragma unroll
  for (int r = 0; r < 4; r++) {
    int rr = r0 + rr0 + r;
    if (rr < NN) {
      float o[8];
      o[0] = acc[r][0] + bb0.x; o[1] = acc[r][1] + bb0.y;
      o[2] = acc[r][2] + bb0.z; o[3] = acc[r][3] + bb0.w;
      o[4] = acc[r][4] + bb1.x; o[5] = acc[r][5] + bb1.y;
      o[6] = acc[r][6] + bb1.z; o[7] = acc[r][7] + bb1.w;
#pragma unroll
      for (int c = 0; c < 8; c++) o[c] = o[c] > 0.f ? o[c] : expm1f(o[c]);
      *(float4*)(C + (size_t)rr * 256 + c0) = make_float4(o[0], o[1], o[2], o[3]);
      *(float4*)(C + (size_t)rr * 256 + c0 + 4) = make_float4(o[4], o[5], o[6], o[7]);
    }
  }
}

// ---------------- GEMM2: h2[N,128] = x1[N,256] @ W_out[256,128] ----------------

__global__ __launch_bounds__(256) void k_gemm_mid(const float* __restrict__ X,
                                                  const float* __restrict__ W,
                                                  float* __restrict__ C) {
  __shared__ float As[32][256];
  int r0 = blockIdx.x * 32;
  int t = threadIdx.x;
  for (int i = t; i < 2048; i += 256) {
    int r = i >> 6, q = (i & 63) << 2;
    int rr = r0 + r;
    float4 v = make_float4(0.f, 0.f, 0.f, 0.f);
    if (rr < NN) v = *(const float4*)(X + (size_t)rr * 256 + q);
    *(float4*)(&As[r][q]) = v;
  }
  __syncthreads();
  int tc = t & 31, tr = t >> 5;
  int c0 = tc * 4, rr0 = tr * 4;
  float acc[4][4];
#pragma unroll
  for (int r = 0; r < 4; r++)
#pragma unroll
    for (int c = 0; c < 4; c++) acc[r][c] = 0.f;

  for (int k0 = 0; k0 < 256; k0 += 4) {
    float a_[4][4];
#pragma unroll
    for (int r = 0; r < 4; r++) {
      float4 v = *(const float4*)(&As[rr0 + r][k0]);
      a_[r][0] = v.x; a_[r][1] = v.y; a_[r][2] = v.z; a_[r][3] = v.w;
    }
#pragma unroll
    for (int kk = 0; kk < 4; kk++) {
      float4 w = *(const float4*)(W + (size_t)(k0 + kk) * 128 + c0);
#pragma unroll
      for (int r = 0; r < 4; r++) {
        float av = a_[r][kk];
        acc[r][0] += av * w.x; acc[r][1] += av * w.y;
        acc[r][2] += av * w.z; acc[r][3] += av * w.w;
      }
    }
  }
#pragma unroll
  for (int r = 0; r < 4; r++) {
    int rr = r0 + rr0 + r;
    if (rr < NN) {
      float4 o = make_float4(acc[r][0], acc[r][1], acc[r][2], acc[r][3]);
      *(float4*)(C + (size_t)rr * 128 + c0) = o;
    }
  }
}

// ---------------- fused edge decoder v4 ----------------
// Persistent: 2500 blocks x TILES tiles x 32 edges. 4 waves, wave w owns cols
// [w*32, w*32+32). Weights stay in L2 (192 KB hot, loaded in-loop -> no VGPR
// spill). Next tile's gather issued mid-tile straight to LDS. T2 aliases
// Th/Tl (dead after layer-2), NOT Ah (holds prefetch).

#define SA 264   // concat-feature LDS stride (shorts)
#define ST 136   // layer-1 output stride (shorts)
#define S2 132   // layer-2 output fp32 stride (floats)
#define TILES 10

__global__ __launch_bounds__(256, 3) void k_decoder(
    const short* __restrict__ xh, const short* __restrict__ xl,
    const int* __restrict__ ei,
    const short* __restrict__ w1th, const short* __restrict__ w1tl,
    const float* __restrict__ b1,
    const short* __restrict__ w2th, const short* __restrict__ w2tl,
    const float* __restrict__ b2,
    const float* __restrict__ W3, const float* __restrict__ b3,
    float* __restrict__ out) {
  __shared__ short Ah[32 * SA];            // 16.9 KB  (tile features, hi)
  __shared__ short Al[32 * SA];            // 16.9 KB  (lo)
  __shared__ short ThTl[2 * 32 * ST];      // 17.4 KB  (layer-1 out hi|lo)
  short* Th = ThTl;
  short* Tl = ThTl + 32 * ST;
  float* T2 = (float*)ThTl;                // fp32, aliases Th/Tl (dead then)

  int t = threadIdx.x;
  int w = t >> 6, lane = t & 63;
  int quad = lane >> 4, l16 = lane & 15;
  int nb = w * 32;

  float b1v0 = b1[nb + l16], b1v1 = b1[nb + 16 + l16];
  float b2v0 = b2[nb + l16], b2v1 = b2[nb + 16 + l16];
  float b3v = b3[0];

  int aoff0 = (0 + l16) * SA + quad * 8;
  int aoff1 = (16 + l16) * SA + quad * 8;
  int boff0 = (nb + l16) * 256 + quad * 8;
  int boff1 = (nb + 16 + l16) * 256 + quad * 8;
  int toff0 = (0 + l16) * ST + quad * 8;
  int toff1 = (16 + l16) * ST + quad * 8;
  int coff0 = (nb + l16) * 128 + quad * 8;
  int coff1 = (nb + 16 + l16) * 128 + quad * 8;

  int tile0 = blockIdx.x * TILES;

  // prologue: gather tile 0 into LDS
  {
    int e0 = tile0 * 32;
#pragma unroll
    for (int j = 0; j < 8; j++) {
      int i = t + 256 * j;
      int arr = i >> 10, rem = i & 1023, le = rem >> 5, q = rem & 31;
      int node = (q < 16) ? ei[e0 + le] : ei[NE + e0 + le];
      const short* src = (arr ? xl : xh) + (size_t)node * 128 + (q & 15) * 8;
      short* dst = (arr ? Al : Ah) + le * SA + q * 8;
      *(uint4*)dst = *(const uint4*)src;
    }
  }

  for (int tt = 0; tt < TILES; tt++) {
    int e0 = (tile0 + tt) * 32;
    __syncthreads();   // (B1) gather visible; prev T2 reads done

    // ---- layer 1: [32,256] @ W1[256,128] (hi*hi + hi*lo + lo*hi) ----
    f4_t acc[2][2];
#pragma unroll
    for (int mi = 0; mi < 2; mi++)
#pragma unroll
      for (int ni = 0; ni < 2; ni++) acc[mi][ni] = (f4_t){0.f, 0.f, 0.f, 0.f};

#pragma unroll
    for (int kb = 0; kb < 8; kb++) {
      int k0 = kb * 32;
      s8_t ah0 = *(const s8_t*)&Ah[aoff0 + k0];
      s8_t ah1 = *(const s8_t*)&Ah[aoff1 + k0];
      s8_t al0 = *(const s8_t*)&Al[aoff0 + k0];
      s8_t al1 = *(const s8_t*)&Al[aoff1 + k0];
      s8_t bh0 = *(const s8_t*)(w1th + boff0 + k0);
      s8_t bh1 = *(const s8_t*)(w1th + boff1 + k0);
      s8_t bl0 = *(const s8_t*)(w1tl + boff0 + k0);
      s8_t bl1 = *(const s8_t*)(w1tl + boff1 + k0);
      acc[0][0] = __builtin_amdgcn_mfma_f32_16x16x32_bf16(ah0, bh0, acc[0][0], 0, 0, 0);
      acc[0][0] = __builtin_amdgcn_mfma_f32_16x16x32_bf16(ah0, bl0, acc[0][0], 0, 0, 0);
      acc[0][0] = __builtin_amdgcn_mfma_f32_16x16x32_bf16(al0, bh0, acc[0][0], 0, 0, 0);
      acc[0][1] = __builtin_amdgcn_mfma_f32_16x16x32_bf16(ah0, bh1, acc[0][1], 0, 0, 0);
      acc[0][1] = __builtin_amdgcn_mfma_f32_16x16x32_bf16(ah0, bl1, acc[0][1], 0, 0, 0);
      acc[0][1] = __builtin_amdgcn_mfma_f32_16x16x32_bf16(al0, bh1, acc[0][1], 0, 0, 0);
      acc[1][0] = __builtin_amdgcn_mfma_f32_16x16x32_bf16(ah1, bh0, acc[1][0], 0, 0, 0);
      acc[1][0] = __builtin_amdgcn_mfma_f32_16x16x32_bf16(ah1, bl0, acc[1][0], 0, 0, 0);
      acc[1][0] = __builtin_amdgcn_mfma_f32_16x16x32_bf16(al1, bh0, acc[1][0], 0, 0, 0);
      acc[1][1] = __builtin_amdgcn_mfma_f32_16x16x32_bf16(ah1, bh1, acc[1][1], 0, 0, 0);
      acc[1][1] = __builtin_amdgcn_mfma_f32_16x16x32_bf16(ah1, bl1, acc[1][1], 0, 0, 0);
      acc[1][1] = __builtin_amdgcn_mfma_f32_16x16x32_bf16(al1, bh1, acc[1][1], 0, 0, 0);
    }

    // bias + relu + split -> Th/Tl
#pragma unroll
    for (int mi = 0; mi < 2; mi++)
#pragma unroll
      for (int ni = 0; ni < 2; ni++) {
        float bv = ni ? b1v1 : b1v0;
        int col = nb + ni * 16 + l16;
#pragma unroll
        for (int r = 0; r < 4; r++) {
          int row = mi * 16 + quad * 4 + r;
          float v = fmaxf(acc[mi][ni][r] + bv, 0.f);
          short h, l; split2(v, h, l);
          Th[row * ST + col] = h;
          Tl[row * ST + col] = l;
        }
      }
    __syncthreads();   // (B2) Th/Tl ready; Ah/Al dead for all waves

    // ---- gather NEXT tile into Ah/Al (overlaps layer-2/3 compute) ----
    if (tt + 1 < TILES) {
      int e1 = e0 + 32;
#pragma unroll
      for (int j = 0; j < 8; j++) {
        int i = t + 256 * j;
        int arr = i >> 10, rem = i & 1023, le = rem >> 5, q = rem & 31;
        int node = (q < 16) ? ei[e1 + le] : ei[NE + e1 + le];
        const short* src = (arr ? xl : xh) + (size_t)node * 128 + (q & 15) * 8;
        short* dst = (arr ? Al : Ah) + le * SA + q * 8;
        *(uint4*)dst = *(const uint4*)src;
      }
    }

    // ---- layer 2: [32,128] @ W2[128,128] ----
    f4_t acc2[2][2];
#pragma unroll
    for (int mi = 0; mi < 2; mi++)
#pragma unroll
      for (int ni = 0; ni < 2; ni++) acc2[mi][ni] = (f4_t){0.f, 0.f, 0.f, 0.f};

#pragma unroll
    for (int kb = 0; kb < 4; kb++) {
      int k0 = kb * 32;
      s8_t ah0 = *(const s8_t*)&Th[toff0 + k0];
      s8_t ah1 = *(const s8_t*)&Th[toff1 + k0];
      s8_t al0 = *(const s8_t*)&Tl[toff0 + k0];
      s8_t al1 = *(const s8_t*)&Tl[toff1 + k0];
      s8_t bh0 = *(const s8_t*)(w2th + coff0 + k0);
      s8_t bh1 = *(const s8_t*)(w2th + coff1 + k0);
      s8_t bl0 = *(const s8_t*)(w2tl + coff0 + k0);
      s8_t bl1 = *(const s8_t*)(w2tl + coff1 + k0);
      acc2[0][0] = __builtin_amdgcn_mfma_f32_16x16x32_bf16(ah0, bh0, acc2[0][0], 0, 0, 0);
      acc2[0][0] = __builtin_amdgcn_mfma_f32_16x16x32_bf16(ah0, bl0, acc2[0][0], 0, 0, 0);
      acc2[0][0] = __builtin_amdgcn_mfma_f32_16x16x32_bf16(al0, bh0, acc2[0][0], 0, 0, 0);
      acc2[0][1] = __builtin_amdgcn_mfma_f32_16x16x32_bf16(ah0, bh1, acc2[0][1], 0, 0, 0);
      acc2[0][1] = __builtin_amdgcn_mfma_f32_16x16x32_bf16(ah0, bl1, acc2[0][1], 0, 0, 0);
      acc2[0][1] = __builtin_amdgcn_mfma_f32_16x16x32_bf16(al0, bh1, acc2[0][1], 0, 0, 0);
      acc2[1][0] = __builtin_amdgcn_mfma_f32_16x16x32_bf16(ah1, bh0, acc2[1][0], 0, 0, 0);
      acc2[1][0] = __builtin_amdgcn_mfma_f32_16x16x32_bf16(ah1, bl0, acc2[1][0], 0, 0, 0);
      acc2[1][0] = __builtin_amdgcn_mfma_f32_16x16x32_bf16(al1, bh0, acc2[1][0], 0, 0, 0);
      acc2[1][1] = __builtin_amdgcn_mfma_f32_16x16x32_bf16(ah1, bh1, acc2[1][1], 0, 0, 0);
      acc2[1][1] = __builtin_amdgcn_mfma_f32_16x16x32_bf16(ah1, bl1, acc2[1][1], 0, 0, 0);
      acc2[1][1] = __builtin_amdgcn_mfma_f32_16x16x32_bf16(al1, bh1, acc2[1][1], 0, 0, 0);
    }
    __syncthreads();   // (B3) Th/Tl reads done -> T2 (alias) writable

    // bias + relu -> T2 (fp32)
#pragma unroll
    for (int mi = 0; mi < 2; mi++)
#pragma unroll
      for (int ni = 0; ni < 2; ni++) {
        float bv = ni ? b2v1 : b2v0;
        int col = nb + ni * 16 + l16;
#pragma unroll
        for (int r = 0; r < 4; r++) {
          int row = mi * 16 + quad * 4 + r;
          T2[row * S2 + col] = fmaxf(acc2[mi][ni][r] + bv, 0.f);
        }
      }
    __syncthreads();   // (B4) T2 ready

    // ---- layer 3: out[e] = dot(t2[e], W3) + b3 ----
    {
      int le = t >> 3, j0 = (t & 7) * 16;
      float s = 0.f;
#pragma unroll
      for (int j = 0; j < 16; j += 4) {
        float4 v = *(const float4*)(&T2[le * S2 + j0 + j]);
        float4 wv = *(const float4*)(W3 + j0 + j);
        s += v.x * wv.x + v.y * wv.y + v.z * wv.z + v.w * wv.w;
      }
      s += __shfl_down(s, 4);
      s += __shfl_down(s, 2);
      s += __shfl_down(s, 1);
      if ((t & 7) == 0) out[e0 + le] = s + b3v;
    }
  }
}

// ---------------- launch ----------------

extern "C" void kernel_launch(void* const* d_in, const int* in_sizes, int n_in,
                              void* d_out, int out_size, void* d_ws, size_t ws_size,
                              hipStream_t stream) {
  const int*   node_ids = (const int*)d_in[0];
  const int*   ei       = (const int*)d_in[1];
  const int*   nei      = (const int*)d_in[2];
  const float* eattr    = (const float*)d_in[3];
  const float* emb      = (const float*)d_in[4];
  const float* W_in     = (const float*)d_in[5];
  const float* b_in     = (const float*)d_in[6];
  const float* W_out    = (const float*)d_in[7];
  const float* b_out    = (const float*)d_in[8];
  const float* W1       = (const float*)d_in[9];
  const float* b1       = (const float*)d_in[10];
  const float* W2       = (const float*)d_in[11];
  const float* b2       = (const float*)d_in[12];
  const float* W3       = (const float*)d_in[13];
  const float* b3       = (const float*)d_in[14];
  float* out = (float*)d_out;

  // workspace layout (floats)
  float* ws    = (float*)d_ws;
  float* bufA  = ws;                          // N*128: aggX, then h2
  float* bufB  = bufA + (size_t)NN * 128;     // N*256: x1, then x2h/x2l (shorts)
  int*   cnt1  = (int*)(bufB + (size_t)NN * 256);
  int*   cnt2  = cnt1 + NN;
  float* deg1  = (float*)(cnt2 + NN);
  float* dinv1 = deg1 + NN;
  float* dinv2 = dinv1 + NN;
  int*   off1  = (int*)(dinv2 + NN);          // N+1
  int*   pos1  = off1 + NN + 1;               // N
  int*   off2  = pos1 + NN;                   // N+1
  int*   pos2  = off2 + NN + 1;               // N
  int*   c1src = pos2 + NN;                   // E
  float* c1nrm = (float*)(c1src + NE);        // E
  int*   c2src = (int*)(c1nrm + NE);          // E
  float* c2nrm = (float*)(c2src + NE);        // E
  short* w1th  = (short*)(c2nrm + NE);
  short* w1tl  = w1th + 32768;
  short* w2th  = w1tl + 32768;
  short* w2tl  = w2th + 16384;

  float* aggX  = bufA;
  float* h2    = bufA;                        // overwrites aggX (dead)
  float* x1    = bufB;
  short* x2h   = (short*)bufB;                // overwrites x1 (dead)
  short* x2l   = x2h + (size_t)NN * 128;

  // weight split
  k_wcvt<<<192, 256, 0, stream>>>(W1, W2, w1th, w1tl, w2th, w2tl);

  // CSR build: hist -> dinv -> scan -> fill
  hipMemsetAsync(cnt1, 0, 3 * (size_t)NN * sizeof(int), stream);  // cnt1,cnt2,deg1
  k_hist<<<NE / 256, 256, 0, stream>>>(ei, nei, eattr, cnt1, deg1, cnt2);
  k_dinvs<<<(NN + 255) / 256, 256, 0, stream>>>(deg1, cnt2, dinv1, dinv2);
  k_scan<<<1, 1024, 0, stream>>>(cnt1, off1, pos1, cnt2, off2, pos2);
  k_fill<<<NE / 256, 256, 0, stream>>>(ei, nei, eattr, dinv1, dinv2,
                                       pos1, c1src, c1nrm, pos2, c2src, c2nrm);

  // layer 1: aggregate (CSR, no atomics) -> GEMM + bias + ELU
  k_agg1<<<NN / 4, 256, 0, stream>>>(off1, c1src, c1nrm, node_ids, emb, aggX);
  k_gemm_aggin<<<(NN + 31) / 32, 256, 0, stream>>>(aggX, W_in, b_in, x1);

  // layer 2: transform-first -> aggregate (+bias+ELU+split fused)
  k_gemm_mid<<<(NN + 31) / 32, 256, 0, stream>>>(x1, W_out, h2);
  k_agg2<<<NN / 4, 256, 0, stream>>>(off2, c2src, c2nrm, h2, b_out, x2h, x2l);

  // decoder v4 (persistent, L2 weights, mid-tile prefetch)
  k_decoder<<<NE / 32 / TILES, 256, 0, stream>>>(x2h, x2l, ei,
                                                 w1th, w1tl, b1,
                                                 w2th, w2tl, b2,
                                                 W3, b3, out);
}

// Round 6
// 1234.655 us; speedup vs baseline: 1.6409x; 1.2202x over previous
//
#include <hip/hip_runtime.h>
#include <math.h>

#define NN 50000
#define NE 800000
// D = 128, H = 256

typedef __attribute__((ext_vector_type(8))) short s8_t;   // 8 bf16
typedef __attribute__((ext_vector_type(4))) float f4_t;   // 4 fp32

__device__ __forceinline__ short bf16_rne(float v) {
  unsigned u = __float_as_uint(v);
  unsigned r = (u + 0x7FFFu + ((u >> 16) & 1u)) >> 16;
  return (short)r;
}
__device__ __forceinline__ float bf16_tof(short h) {
  return __uint_as_float(((unsigned)(unsigned short)h) << 16);
}
__device__ __forceinline__ void split2(float v, short& hi, short& lo) {
  hi = bf16_rne(v);
  lo = bf16_rne(v - bf16_tof(hi));
}

// ---------------- weight split/transpose for decoder MFMA ----------------

__global__ __launch_bounds__(256) void k_wcvt(const float* __restrict__ W1,
                                              const float* __restrict__ W2,
                                              short* __restrict__ w1th,
                                              short* __restrict__ w1tl,
                                              short* __restrict__ w2th,
                                              short* __restrict__ w2tl) {
  int i = blockIdx.x * 256 + threadIdx.x;
  if (i < 32768) {
    int k = i >> 7, n = i & 127;
    short h, l; split2(W1[i], h, l);
    w1th[n * 256 + k] = h; w1tl[n * 256 + k] = l;
  } else if (i < 49152) {
    int j = i - 32768;
    int k = j >> 7, n = j & 127;
    short h, l; split2(W2[j], h, l);
    w2th[n * 128 + k] = h; w2tl[n * 128 + k] = l;
  }
}

// ---------------- CSR build: histogram (also weighted degree) ----------------

__global__ __launch_bounds__(256) void k_hist(const int* __restrict__ ei,
                                              const int* __restrict__ nei,
                                              const float* __restrict__ w,
                                              int* __restrict__ cnt1,
                                              float* __restrict__ deg1,
                                              int* __restrict__ cnt2) {
  int e = blockIdx.x * 256 + threadIdx.x;
  if (e < NE) {
    int c1 = ei[NE + e];
    atomicAdd(&cnt1[c1], 1);
    atomicAdd(&deg1[c1], w[e]);
    atomicAdd(&cnt2[nei[NE + e]], 1);
  }
}

// ---------------- dinv for both graphs ----------------

__global__ __launch_bounds__(256) void k_dinvs(const float* __restrict__ deg1,
                                               const int* __restrict__ cnt2,
                                               float* __restrict__ dinv1,
                                               float* __restrict__ dinv2) {
  int i = blockIdx.x * 256 + threadIdx.x;
  if (i < NN) {
    float d1 = deg1[i];
    dinv1[i] = d1 > 0.f ? (1.0f / sqrtf(d1)) : 0.f;
    int c2 = cnt2[i];
    dinv2[i] = c2 > 0 ? (1.0f / sqrtf((float)c2)) : 0.f;
  }
}

// ---------------- hierarchical exclusive scan ----------------
// NCHUNK chunks of 256; grid = 2*NCHUNK (graph1 then graph2).

#define NCHUNK 196   // ceil(50000/256)

__global__ __launch_bounds__(256) void k_scan_part(const int* __restrict__ cnt1,
                                                   const int* __restrict__ cnt2,
                                                   int* __restrict__ part) {
  int g = blockIdx.x >= NCHUNK;
  int chunk = g ? blockIdx.x - NCHUNK : blockIdx.x;
  const int* cnt = g ? cnt2 : cnt1;
  int i = chunk * 256 + threadIdx.x;
  int v = (i < NN) ? cnt[i] : 0;
  __shared__ int sd[4];
#pragma unroll
  for (int o = 32; o; o >>= 1) v += __shfl_down(v, o);
  if ((threadIdx.x & 63) == 0) sd[threadIdx.x >> 6] = v;
  __syncthreads();
  if (threadIdx.x == 0) part[blockIdx.x] = sd[0] + sd[1] + sd[2] + sd[3];
}

__global__ __launch_bounds__(256) void k_scan_mid(int* __restrict__ part,
                                                  int* __restrict__ off1_last,
                                                  int* __restrict__ off2_last) {
  __shared__ int sd[256];
  for (int g = 0; g < 2; g++) {
    int base = g * NCHUNK;
    int v = (threadIdx.x < NCHUNK) ? part[base + threadIdx.x] : 0;
    sd[threadIdx.x] = v;
    __syncthreads();
    for (int o = 1; o < 256; o <<= 1) {
      int x = (threadIdx.x >= o) ? sd[threadIdx.x - o] : 0;
      __syncthreads();
      sd[threadIdx.x] += x;
      __syncthreads();
    }
    if (threadIdx.x < NCHUNK) part[base + threadIdx.x] = sd[threadIdx.x] - v;
    if (threadIdx.x == 255) *(g ? off2_last : off1_last) = sd[255];
    __syncthreads();
  }
}

__global__ __launch_bounds__(256) void k_scan_final(const int* __restrict__ cnt1,
                                                    const int* __restrict__ cnt2,
                                                    const int* __restrict__ part,
                                                    int* __restrict__ off1,
                                                    int* __restrict__ pos1,
                                                    int* __restrict__ off2,
                                                    int* __restrict__ pos2) {
  int g = blockIdx.x >= NCHUNK;
  int chunk = g ? blockIdx.x - NCHUNK : blockIdx.x;
  const int* cnt = g ? cnt2 : cnt1;
  int* off = g ? off2 : off1;
  int* pos = g ? pos2 : pos1;
  __shared__ int sd[256];
  int i = chunk * 256 + threadIdx.x;
  int v = (i < NN) ? cnt[i] : 0;
  sd[threadIdx.x] = v;
  __syncthreads();
  for (int o = 1; o < 256; o <<= 1) {
    int x = (threadIdx.x >= o) ? sd[threadIdx.x - o] : 0;
    __syncthreads();
    sd[threadIdx.x] += x;
    __syncthreads();
  }
  if (i < NN) {
    int ex = part[blockIdx.x] + sd[threadIdx.x] - v;
    off[i] = ex; pos[i] = ex;
  }
}

// ---------------- fill CSR (src + inline norm) ----------------

__global__ __launch_bounds__(256) void k_fill(const int* __restrict__ ei,
                                              const int* __restrict__ nei,
                                              const float* __restrict__ w,
                                              const float* __restrict__ dinv1,
                                              const float* __restrict__ dinv2,
                                              int* __restrict__ pos1,
                                              int* __restrict__ csr1_src,
                                              float* __restrict__ csr1_nrm,
                                              int* __restrict__ pos2,
                                              int* __restrict__ csr2_src,
                                              float* __restrict__ csr2_nrm) {
  int e = blockIdx.x * 256 + threadIdx.x;
  if (e < NE) {
    int r = ei[e], c = ei[NE + e];
    float nv = dinv1[r] * w[e] * dinv1[c];
    int s = atomicAdd(&pos1[c], 1);
    csr1_src[s] = r; csr1_nrm[s] = nv;
    int r2 = nei[e], c2 = nei[NE + e];
    float nv2 = dinv2[r2] * dinv2[c2];
    int s2 = atomicAdd(&pos2[c2], 1);
    csr2_src[s2] = r2; csr2_nrm[s2] = nv2;
  }
}

// ---------------- layer1 aggregate (CSR, no atomics) ----------------

__global__ __launch_bounds__(256) void k_agg1(const int* __restrict__ off,
                                              const int* __restrict__ csr_src,
                                              const float* __restrict__ csr_nrm,
                                              const int* __restrict__ ids,
                                              const float* __restrict__ emb,
                                              float* __restrict__ aggX) {
  int wave = threadIdx.x >> 6, lane = threadIdx.x & 63;
  int node = blockIdx.x * 4 + wave;
  int start = off[node], end = off[node + 1];
  float2 acc = make_float2(0.f, 0.f);
  int i = start;
  for (; i + 1 < end; i += 2) {
    int s0 = csr_src[i], s1 = csr_src[i + 1];
    float n0 = csr_nrm[i], n1 = csr_nrm[i + 1];
    float2 v0 = *(const float2*)(emb + (size_t)ids[s0] * 128 + lane * 2);
    float2 v1 = *(const float2*)(emb + (size_t)ids[s1] * 128 + lane * 2);
    acc.x = fmaf(n0, v0.x, fmaf(n1, v1.x, acc.x));
    acc.y = fmaf(n0, v0.y, fmaf(n1, v1.y, acc.y));
  }
  if (i < end) {
    int s0 = csr_src[i];
    float n0 = csr_nrm[i];
    float2 v0 = *(const float2*)(emb + (size_t)ids[s0] * 128 + lane * 2);
    acc.x = fmaf(n0, v0.x, acc.x);
    acc.y = fmaf(n0, v0.y, acc.y);
  }
  *(float2*)(aggX + (size_t)node * 128 + lane * 2) = acc;
}

// ---------------- layer2 aggregate + bias + ELU + bf16 split ----------------

__global__ __launch_bounds__(256) void k_agg2(const int* __restrict__ off,
                                              const int* __restrict__ csr_src,
                                              const float* __restrict__ csr_nrm,
                                              const float* __restrict__ h2,
                                              const float* __restrict__ b,
                                              short* __restrict__ xh,
                                              short* __restrict__ xl) {
  int wave = threadIdx.x >> 6, lane = threadIdx.x & 63;
  int node = blockIdx.x * 4 + wave;
  int start = off[node], end = off[node + 1];
  float2 acc = make_float2(0.f, 0.f);
  int i = start;
  for (; i + 1 < end; i += 2) {
    int s0 = csr_src[i], s1 = csr_src[i + 1];
    float n0 = csr_nrm[i], n1 = csr_nrm[i + 1];
    float2 v0 = *(const float2*)(h2 + (size_t)s0 * 128 + lane * 2);
    float2 v1 = *(const float2*)(h2 + (size_t)s1 * 128 + lane * 2);
    acc.x = fmaf(n0, v0.x, fmaf(n1, v1.x, acc.x));
    acc.y = fmaf(n0, v0.y, fmaf(n1, v1.y, acc.y));
  }
  if (i < end) {
    int s0 = csr_src[i];
    float n0 = csr_nrm[i];
    float2 v0 = *(const float2*)(h2 + (size_t)s0 * 128 + lane * 2);
    acc.x = fmaf(n0, v0.x, acc.x);
    acc.y = fmaf(n0, v0.y, acc.y);
  }
  float vx = acc.x + b[lane * 2];
  float vy = acc.y + b[lane * 2 + 1];
  vx = vx > 0.f ? vx : expm1f(vx);
  vy = vy > 0.f ? vy : expm1f(vy);
  short hx, lx, hy, ly;
  split2(vx, hx, lx);
  split2(vy, hy, ly);
  unsigned hp = (unsigned)(unsigned short)hx | ((unsigned)(unsigned short)hy << 16);
  unsigned lp = (unsigned)(unsigned short)lx | ((unsigned)(unsigned short)ly << 16);
  *(unsigned*)(xh + (size_t)node * 128 + lane * 2) = hp;
  *(unsigned*)(xl + (size_t)node * 128 + lane * 2) = lp;
}

// ---------------- GEMM1: x1[N,256] = elu(aggX[N,128] @ W_in[128,256] + b) ------

__global__ __launch_bounds__(256) void k_gemm_aggin(const float* __restrict__ X,
                                                    const float* __restrict__ W,
                                                    const float* __restrict__ b,
                                                    float* __restrict__ C) {
  __shared__ float As[32][128];
  int r0 = blockIdx.x * 32;
  int t = threadIdx.x;
  for (int i = t; i < 1024; i += 256) {
    int r = i >> 5, q = (i & 31) << 2;
    int rr = r0 + r;
    float4 v = make_float4(0.f, 0.f, 0.f, 0.f);
    if (rr < NN) v = *(const float4*)(X + (size_t)rr * 128 + q);
    *(float4*)(&As[r][q]) = v;
  }
  __syncthreads();
  int tc = t & 31, tr = t >> 5;
  int c0 = tc * 8, rr0 = tr * 4;
  float acc[4][8];
#pragma unroll
  for (int r = 0; r < 4; r++)
#pragma unroll
    for (int c = 0; c < 8; c++) acc[r][c] = 0.f;

  for (int k0 = 0; k0 < 128; k0 += 4) {
    float a_[4][4];
#pragma unroll
    for (int r = 0; r < 4; r++) {
      float4 v = *(const float4*)(&As[rr0 + r][k0]);
      a_[r][0] = v.x; a_[r][1] = v.y; a_[r][2] = v.z; a_[r][3] = v.w;
    }
#pragma unroll
    for (int kk = 0; kk < 4; kk++) {
      float4 w0 = *(const float4*)(W + (size_t)(k0 + kk) * 256 + c0);
      float4 w1 = *(const float4*)(W + (size_t)(k0 + kk) * 256 + c0 + 4);
#pragma unroll
      for (int r = 0; r < 4; r++) {
        float av = a_[r][kk];
        acc[r][0] += av * w0.x; acc[r][1] += av * w0.y;
        acc[r][2] += av * w0.z; acc[r][3] += av * w0.w;
        acc[r][4] += av * w1.x; acc[r][5] += av * w1.y;
        acc[r][6] += av * w1.z; acc[r][7] += av * w1.w;
      }
    }
  }
  float4 bb0 = *(const float4*)(b + c0);
  float4 bb1 = *(const float4*)(b + c0 + 4);
#pragma unroll
  for (int r = 0; r < 4; r++) {
    int rr = r0 + rr0 + r;
    if (rr < NN) {
      float o[8];
      o[0] = acc[r][0] + bb0.x; o[1] = acc[r][1] + bb0.y;
      o[2] = acc[r][2] + bb0.z; o[3] = acc[r][3] + bb0.w;
      o[4] = acc[r][4] + bb1.x; o[5] = acc[r][5] + bb1.y;
      o[6] = acc[r][6] + bb1.z; o[7] = acc[r][7] + bb1.w;
#pragma unroll
      for (int c = 0; c < 8; c++) o[c] = o[c] > 0.f ? o[c] : expm1f(o[c]);
      *(float4*)(C + (size_t)rr * 256 + c0) = make_float4(o[0], o[1], o[2], o[3]);
      *(float4*)(C + (size_t)rr * 256 + c0 + 4) = make_float4(o[4], o[5], o[6], o[7]);
    }
  }
}

// ---------------- GEMM2: h2[N,128] = x1[N,256] @ W_out[256,128] ----------------

__global__ __launch_bounds__(256) void k_gemm_mid(const float* __restrict__ X,
                                                  const float* __restrict__ W,
                                                  float* __restrict__ C) {
  __shared__ float As[32][256];
  int r0 = blockIdx.x * 32;
  int t = threadIdx.x;
  for (int i = t; i < 2048; i += 256) {
    int r = i >> 6, q = (i & 63) << 2;
    int rr = r0 + r;
    float4 v = make_float4(0.f, 0.f, 0.f, 0.f);
    if (rr < NN) v = *(const float4*)(X + (size_t)rr * 256 + q);
    *(float4*)(&As[r][q]) = v;
  }
  __syncthreads();
  int tc = t & 31, tr = t >> 5;
  int c0 = tc * 4, rr0 = tr * 4;
  float acc[4][4];
#pragma unroll
  for (int r = 0; r < 4; r++)
#pragma unroll
    for (int c = 0; c < 4; c++) acc[r][c] = 0.f;

  for (int k0 = 0; k0 < 256; k0 += 4) {
    float a_[4][4];
#pragma unroll
    for (int r = 0; r < 4; r++) {
      float4 v = *(const float4*)(&As[rr0 + r][k0]);
      a_[r][0] = v.x; a_[r][1] = v.y; a_[r][2] = v.z; a_[r][3] = v.w;
    }
#pragma unroll
    for (int kk = 0; kk < 4; kk++) {
      float4 w = *(const float4*)(W + (size_t)(k0 + kk) * 128 + c0);
#pragma unroll
      for (int r = 0; r < 4; r++) {
        float av = a_[r][kk];
        acc[r][0] += av * w.x; acc[r][1] += av * w.y;
        acc[r][2] += av * w.z; acc[r][3] += av * w.w;
      }
    }
  }
#pragma unroll
  for (int r = 0; r < 4; r++) {
    int rr = r0 + rr0 + r;
    if (rr < NN) {
      float4 o = make_float4(acc[r][0], acc[r][1], acc[r][2], acc[r][3]);
      *(float4*)(C + (size_t)rr * 128 + c0) = o;
    }
  }
}

// ---------------- fused edge decoder v5 ----------------
// Persistent: 2500 blocks x TILES tiles x 32 edges, mid-tile LDS prefetch.
// Weight loads kept IN the tile loop via an opaque-pointer asm barrier:
// without it, LICM hoists 32 tile-invariant s8_t weight loads, the RA can't
// hold them (launch_bounds cap), and they spill to scratch (r4: 116 MB, r5:
// 366 MB WRITE_SIZE). The barrier re-defines the pointers each iteration.

#define SA 264   // concat-feature LDS stride (shorts)
#define ST 136   // layer-1 output stride (shorts)
#define S2 132   // layer-2 output fp32 stride (floats)
#define TILES 10

__global__ __launch_bounds__(256, 3) void k_decoder(
    const short* __restrict__ xh, const short* __restrict__ xl,
    const int* __restrict__ ei,
    const short* __restrict__ w1th_in, const short* __restrict__ w1tl_in,
    const float* __restrict__ b1,
    const short* __restrict__ w2th_in, const short* __restrict__ w2tl_in,
    const float* __restrict__ b2,
    const float* __restrict__ W3, const float* __restrict__ b3,
    float* __restrict__ out) {
  __shared__ short Ah[32 * SA];            // tile features hi
  __shared__ short Al[32 * SA];            // lo
  __shared__ short ThTl[2 * 32 * ST];      // layer-1 out hi|lo
  short* Th = ThTl;
  short* Tl = ThTl + 32 * ST;
  float* T2 = (float*)ThTl;                // fp32, aliases Th/Tl (dead then)

  int t = threadIdx.x;
  int w = t >> 6, lane = t & 63;
  int quad = lane >> 4, l16 = lane & 15;
  int nb = w * 32;

  float b1v0 = b1[nb + l16], b1v1 = b1[nb + 16 + l16];
  float b2v0 = b2[nb + l16], b2v1 = b2[nb + 16 + l16];
  float b3v = b3[0];

  int aoff0 = (0 + l16) * SA + quad * 8;
  int aoff1 = (16 + l16) * SA + quad * 8;
  int boff0 = (nb + l16) * 256 + quad * 8;
  int boff1 = (nb + 16 + l16) * 256 + quad * 8;
  int toff0 = (0 + l16) * ST + quad * 8;
  int toff1 = (16 + l16) * ST + quad * 8;
  int coff0 = (nb + l16) * 128 + quad * 8;
  int coff1 = (nb + 16 + l16) * 128 + quad * 8;

  int tile0 = blockIdx.x * TILES;

  // prologue: gather tile 0 into LDS
  {
    int e0 = tile0 * 32;
#pragma unroll
    for (int j = 0; j < 8; j++) {
      int i = t + 256 * j;
      int arr = i >> 10, rem = i & 1023, le = rem >> 5, q = rem & 31;
      int node = (q < 16) ? ei[e0 + le] : ei[NE + e0 + le];
      const short* src = (arr ? xl : xh) + (size_t)node * 128 + (q & 15) * 8;
      short* dst = (arr ? Al : Ah) + le * SA + q * 8;
      *(uint4*)dst = *(const uint4*)src;
    }
  }

  for (int tt = 0; tt < TILES; tt++) {
    int e0 = (tile0 + tt) * 32;

    // opaque per-iteration weight pointers: defeats LICM hoist -> no spill
    const short* w1th = w1th_in;
    const short* w1tl = w1tl_in;
    const short* w2th = w2th_in;
    const short* w2tl = w2tl_in;
    asm volatile("" : "+s"(w1th), "+s"(w1tl), "+s"(w2th), "+s"(w2tl));

    __syncthreads();   // (B1) gather visible; prev T2 reads done

    // ---- layer 1: [32,256] @ W1[256,128] (hi*hi + hi*lo + lo*hi) ----
    f4_t acc[2][2];
#pragma unroll
    for (int mi = 0; mi < 2; mi++)
#pragma unroll
      for (int ni = 0; ni < 2; ni++) acc[mi][ni] = (f4_t){0.f, 0.f, 0.f, 0.f};

#pragma unroll
    for (int kb = 0; kb < 8; kb++) {
      int k0 = kb * 32;
      s8_t ah0 = *(const s8_t*)&Ah[aoff0 + k0];
      s8_t ah1 = *(const s8_t*)&Ah[aoff1 + k0];
      s8_t al0 = *(const s8_t*)&Al[aoff0 + k0];
      s8_t al1 = *(const s8_t*)&Al[aoff1 + k0];
      s8_t bh0 = *(const s8_t*)(w1th + boff0 + k0);
      s8_t bh1 = *(const s8_t*)(w1th + boff1 + k0);
      s8_t bl0 = *(const s8_t*)(w1tl + boff0 + k0);
      s8_t bl1 = *(const s8_t*)(w1tl + boff1 + k0);
      acc[0][0] = __builtin_amdgcn_mfma_f32_16x16x32_bf16(ah0, bh0, acc[0][0], 0, 0, 0);
      acc[0][0] = __builtin_amdgcn_mfma_f32_16x16x32_bf16(ah0, bl0, acc[0][0], 0, 0, 0);
      acc[0][0] = __builtin_amdgcn_mfma_f32_16x16x32_bf16(al0, bh0, acc[0][0], 0, 0, 0);
      acc[0][1] = __builtin_amdgcn_mfma_f32_16x16x32_bf16(ah0, bh1, acc[0][1], 0, 0, 0);
      acc[0][1] = __builtin_amdgcn_mfma_f32_16x16x32_bf16(ah0, bl1, acc[0][1], 0, 0, 0);
      acc[0][1] = __builtin_amdgcn_mfma_f32_16x16x32_bf16(al0, bh1, acc[0][1], 0, 0, 0);
      acc[1][0] = __builtin_amdgcn_mfma_f32_16x16x32_bf16(ah1, bh0, acc[1][0], 0, 0, 0);
      acc[1][0] = __builtin_amdgcn_mfma_f32_16x16x32_bf16(ah1, bl0, acc[1][0], 0, 0, 0);
      acc[1][0] = __builtin_amdgcn_mfma_f32_16x16x32_bf16(al1, bh0, acc[1][0], 0, 0, 0);
      acc[1][1] = __builtin_amdgcn_mfma_f32_16x16x32_bf16(ah1, bh1, acc[1][1], 0, 0, 0);
      acc[1][1] = __builtin_amdgcn_mfma_f32_16x16x32_bf16(ah1, bl1, acc[1][1], 0, 0, 0);
      acc[1][1] = __builtin_amdgcn_mfma_f32_16x16x32_bf16(al1, bh1, acc[1][1], 0, 0, 0);
    }

    // bias + relu + split -> Th/Tl
#pragma unroll
    for (int mi = 0; mi < 2; mi++)
#pragma unroll
      for (int ni = 0; ni < 2; ni++) {
        float bv = ni ? b1v1 : b1v0;
        int col = nb + ni * 16 + l16;
#pragma unroll
        for (int r = 0; r < 4; r++) {
          int row = mi * 16 + quad * 4 + r;
          float v = fmaxf(acc[mi][ni][r] + bv, 0.f);
          short h, l; split2(v, h, l);
          Th[row * ST + col] = h;
          Tl[row * ST + col] = l;
        }
      }
    __syncthreads();   // (B2) Th/Tl ready; Ah/Al dead for all waves

    // ---- gather NEXT tile into Ah/Al (overlaps layer-2/3 compute) ----
    if (tt + 1 < TILES) {
      int e1 = e0 + 32;
#pragma unroll
      for (int j = 0; j < 8; j++) {
        int i = t + 256 * j;
        int arr = i >> 10, rem = i & 1023, le = rem >> 5, q = rem & 31;
        int node = (q < 16) ? ei[e1 + le] : ei[NE + e1 + le];
        const short* src = (arr ? xl : xh) + (size_t)node * 128 + (q & 15) * 8;
        short* dst = (arr ? Al : Ah) + le * SA + q * 8;
        *(uint4*)dst = *(const uint4*)src;
      }
    }

    // ---- layer 2: [32,128] @ W2[128,128] ----
    f4_t acc2[2][2];
#pragma unroll
    for (int mi = 0; mi < 2; mi++)
#pragma unroll
      for (int ni = 0; ni < 2; ni++) acc2[mi][ni] = (f4_t){0.f, 0.f, 0.f, 0.f};

#pragma unroll
    for (int kb = 0; kb < 4; kb++) {
      int k0 = kb * 32;
      s8_t ah0 = *(const s8_t*)&Th[toff0 + k0];
      s8_t ah1 = *(const s8_t*)&Th[toff1 + k0];
      s8_t al0 = *(const s8_t*)&Tl[toff0 + k0];
      s8_t al1 = *(const s8_t*)&Tl[toff1 + k0];
      s8_t bh0 = *(const s8_t*)(w2th + coff0 + k0);
      s8_t bh1 = *(const s8_t*)(w2th + coff1 + k0);
      s8_t bl0 = *(const s8_t*)(w2tl + coff0 + k0);
      s8_t bl1 = *(const s8_t*)(w2tl + coff1 + k0);
      acc2[0][0] = __builtin_amdgcn_mfma_f32_16x16x32_bf16(ah0, bh0, acc2[0][0], 0, 0, 0);
      acc2[0][0] = __builtin_amdgcn_mfma_f32_16x16x32_bf16(ah0, bl0, acc2[0][0], 0, 0, 0);
      acc2[0][0] = __builtin_amdgcn_mfma_f32_16x16x32_bf16(al0, bh0, acc2[0][0], 0, 0, 0);
      acc2[0][1] = __builtin_amdgcn_mfma_f32_16x16x32_bf16(ah0, bh1, acc2[0][1], 0, 0, 0);
      acc2[0][1] = __builtin_amdgcn_mfma_f32_16x16x32_bf16(ah0, bl1, acc2[0][1], 0, 0, 0);
      acc2[0][1] = __builtin_amdgcn_mfma_f32_16x16x32_bf16(al0, bh1, acc2[0][1], 0, 0, 0);
      acc2[1][0] = __builtin_amdgcn_mfma_f32_16x16x32_bf16(ah1, bh0, acc2[1][0], 0, 0, 0);
      acc2[1][0] = __builtin_amdgcn_mfma_f32_16x16x32_bf16(ah1, bl0, acc2[1][0], 0, 0, 0);
      acc2[1][0] = __builtin_amdgcn_mfma_f32_16x16x32_bf16(al1, bh0, acc2[1][0], 0, 0, 0);
      acc2[1][1] = __builtin_amdgcn_mfma_f32_16x16x32_bf16(ah1, bh1, acc2[1][1], 0, 0, 0);
      acc2[1][1] = __builtin_amdgcn_mfma_f32_16x16x32_bf16(ah1, bl1, acc2[1][1], 0, 0, 0);
      acc2[1][1] = __builtin_amdgcn_mfma_f32_16x16x32_bf16(al1, bh1, acc2[1][1], 0, 0, 0);
    }
    __syncthreads();   // (B3) Th/Tl reads done -> T2 (alias) writable

    // bias + relu -> T2 (fp32)
#pragma unroll
    for (int mi = 0; mi < 2; mi++)
#pragma unroll
      for (int ni = 0; ni < 2; ni++) {
        float bv = ni ? b2v1 : b2v0;
        int col = nb + ni * 16 + l16;
#pragma unroll
        for (int r = 0; r < 4; r++) {
          int row = mi * 16 + quad * 4 + r;
          T2[row * S2 + col] = fmaxf(acc2[mi][ni][r] + bv, 0.f);
        }
      }
    __syncthreads();   // (B4) T2 ready

    // ---- layer 3: out[e] = dot(t2[e], W3) + b3 ----
    {
      int le = t >> 3, j0 = (t & 7) * 16;
      float s = 0.f;
#pragma unroll
      for (int j = 0; j < 16; j += 4) {
        float4 v = *(const float4*)(&T2[le * S2 + j0 + j]);
        float4 wv = *(const float4*)(W3 + j0 + j);
        s += v.x * wv.x + v.y * wv.y + v.z * wv.z + v.w * wv.w;
      }
      s += __shfl_down(s, 4);
      s += __shfl_down(s, 2);
      s += __shfl_down(s, 1);
      if ((t & 7) == 0) out[e0 + le] = s + b3v;
    }
  }
}

// ---------------- launch ----------------

extern "C" void kernel_launch(void* const* d_in, const int* in_sizes, int n_in,
                              void* d_out, int out_size, void* d_ws, size_t ws_size,
                              hipStream_t stream) {
  const int*   node_ids = (const int*)d_in[0];
  const int*   ei       = (const int*)d_in[1];
  const int*   nei      = (const int*)d_in[2];
  const float* eattr    = (const float*)d_in[3];
  const float* emb      = (const float*)d_in[4];
  const float* W_in     = (const float*)d_in[5];
  const float* b_in     = (const float*)d_in[6];
  const float* W_out    = (const float*)d_in[7];
  const float* b_out    = (const float*)d_in[8];
  const float* W1       = (const float*)d_in[9];
  const float* b1       = (const float*)d_in[10];
  const float* W2       = (const float*)d_in[11];
  const float* b2       = (const float*)d_in[12];
  const float* W3       = (const float*)d_in[13];
  const float* b3       = (const float*)d_in[14];
  float* out = (float*)d_out;

  // workspace layout (floats)
  float* ws    = (float*)d_ws;
  float* bufA  = ws;                          // N*128: aggX, then h2
  float* bufB  = bufA + (size_t)NN * 128;     // N*256: x1, then x2h/x2l (shorts)
  int*   cnt1  = (int*)(bufB + (size_t)NN * 256);
  int*   cnt2  = cnt1 + NN;
  float* deg1  = (float*)(cnt2 + NN);
  float* dinv1 = deg1 + NN;
  float* dinv2 = dinv1 + NN;
  int*   off1  = (int*)(dinv2 + NN);          // N+1
  int*   pos1  = off1 + NN + 1;               // N
  int*   off2  = pos1 + NN;                   // N+1
  int*   pos2  = off2 + NN + 1;               // N
  int*   c1src = pos2 + NN;                   // E
  float* c1nrm = (float*)(c1src + NE);        // E
  int*   c2src = (int*)(c1nrm + NE);          // E
  float* c2nrm = (float*)(c2src + NE);        // E
  short* w1th  = (short*)(c2nrm + NE);
  short* w1tl  = w1th + 32768;
  short* w2th  = w1tl + 32768;
  short* w2tl  = w2th + 16384;
  int*   part  = (int*)(w2tl + 16384);        // 2*NCHUNK

  float* aggX  = bufA;
  float* h2    = bufA;                        // overwrites aggX (dead)
  float* x1    = bufB;
  short* x2h   = (short*)bufB;                // overwrites x1 (dead)
  short* x2l   = x2h + (size_t)NN * 128;

  // weight split
  k_wcvt<<<192, 256, 0, stream>>>(W1, W2, w1th, w1tl, w2th, w2tl);

  // CSR build: hist -> dinv -> scan(3-phase) -> fill
  hipMemsetAsync(cnt1, 0, 3 * (size_t)NN * sizeof(int), stream);  // cnt1,cnt2,deg1
  k_hist<<<NE / 256, 256, 0, stream>>>(ei, nei, eattr, cnt1, deg1, cnt2);
  k_dinvs<<<(NN + 255) / 256, 256, 0, stream>>>(deg1, cnt2, dinv1, dinv2);
  k_scan_part<<<2 * NCHUNK, 256, 0, stream>>>(cnt1, cnt2, part);
  k_scan_mid<<<1, 256, 0, stream>>>(part, off1 + NN, off2 + NN);
  k_scan_final<<<2 * NCHUNK, 256, 0, stream>>>(cnt1, cnt2, part,
                                               off1, pos1, off2, pos2);
  k_fill<<<NE / 256, 256, 0, stream>>>(ei, nei, eattr, dinv1, dinv2,
                                       pos1, c1src, c1nrm, pos2, c2src, c2nrm);

  // layer 1: aggregate (CSR, no atomics) -> GEMM + bias + ELU
  k_agg1<<<NN / 4, 256, 0, stream>>>(off1, c1src, c1nrm, node_ids, emb, aggX);
  k_gemm_aggin<<<(NN + 31) / 32, 256, 0, stream>>>(aggX, W_in, b_in, x1);

  // layer 2: transform-first -> aggregate (+bias+ELU+split fused)
  k_gemm_mid<<<(NN + 31) / 32, 256, 0, stream>>>(x1, W_out, h2);
  k_agg2<<<NN / 4, 256, 0, stream>>>(off2, c2src, c2nrm, h2, b_out, x2h, x2l);

  // decoder v5 (persistent, opaque weight ptrs, mid-tile prefetch)
  k_decoder<<<NE / 32 / TILES, 256, 0, stream>>>(x2h, x2l, ei,
                                                 w1th, w1tl, b1,
                                                 w2th, w2tl, b2,
                                                 W3, b3, out);
}

// Round 7
// 864.675 us; speedup vs baseline: 2.3429x; 1.4279x over previous
//
#include <hip/hip_runtime.h>
#include <math.h>

#define NN 50000
#define NE 800000
// D = 128, H = 256

typedef __attribute__((ext_vector_type(8))) short s8_t;   // 8 bf16
typedef __attribute__((ext_vector_type(4))) float f4_t;   // 4 fp32

__device__ __forceinline__ short bf16_rne(float v) {
  unsigned u = __float_as_uint(v);
  unsigned r = (u + 0x7FFFu + ((u >> 16) & 1u)) >> 16;
  return (short)r;
}
__device__ __forceinline__ float bf16_tof(short h) {
  return __uint_as_float(((unsigned)(unsigned short)h) << 16);
}
__device__ __forceinline__ void split2(float v, short& hi, short& lo) {
  hi = bf16_rne(v);
  lo = bf16_rne(v - bf16_tof(hi));
}

// ---------------- weight split/transpose ----------------

__global__ __launch_bounds__(256) void k_wcvt(const float* __restrict__ W1,
                                              const float* __restrict__ W2,
                                              short* __restrict__ w1th,
                                              short* __restrict__ w1tl,
                                              short* __restrict__ w2th,
                                              short* __restrict__ w2tl) {
  int i = blockIdx.x * 256 + threadIdx.x;
  if (i < 32768) {
    int k = i >> 7, n = i & 127;
    short h, l; split2(W1[i], h, l);
    w1th[n * 256 + k] = h; w1tl[n * 256 + k] = l;
  } else if (i < 49152) {
    int j = i - 32768;
    int k = j >> 7, n = j & 127;
    short h, l; split2(W2[j], h, l);
    w2th[n * 128 + k] = h; w2tl[n * 128 + k] = l;
  }
}

// ---------------- CSR build: histogram ----------------

__global__ __launch_bounds__(256) void k_hist(const int* __restrict__ ei,
                                              const int* __restrict__ nei,
                                              const float* __restrict__ w,
                                              int* __restrict__ cnt1,
                                              float* __restrict__ deg1,
                                              int* __restrict__ cnt2) {
  int e = blockIdx.x * 256 + threadIdx.x;
  if (e < NE) {
    int c1 = ei[NE + e];
    atomicAdd(&cnt1[c1], 1);
    atomicAdd(&deg1[c1], w[e]);
    atomicAdd(&cnt2[nei[NE + e]], 1);
  }
}

__global__ __launch_bounds__(256) void k_dinvs(const float* __restrict__ deg1,
                                               const int* __restrict__ cnt2,
                                               float* __restrict__ dinv1,
                                               float* __restrict__ dinv2) {
  int i = blockIdx.x * 256 + threadIdx.x;
  if (i < NN) {
    float d1 = deg1[i];
    dinv1[i] = d1 > 0.f ? (1.0f / sqrtf(d1)) : 0.f;
    int c2 = cnt2[i];
    dinv2[i] = c2 > 0 ? (1.0f / sqrtf((float)c2)) : 0.f;
  }
}

// ---------------- hierarchical exclusive scan ----------------

#define NCHUNK 196   // ceil(50000/256)

__global__ __launch_bounds__(256) void k_scan_part(const int* __restrict__ cnt1,
                                                   const int* __restrict__ cnt2,
                                                   int* __restrict__ part) {
  int g = blockIdx.x >= NCHUNK;
  int chunk = g ? blockIdx.x - NCHUNK : blockIdx.x;
  const int* cnt = g ? cnt2 : cnt1;
  int i = chunk * 256 + threadIdx.x;
  int v = (i < NN) ? cnt[i] : 0;
  __shared__ int sd[4];
#pragma unroll
  for (int o = 32; o; o >>= 1) v += __shfl_down(v, o);
  if ((threadIdx.x & 63) == 0) sd[threadIdx.x >> 6] = v;
  __syncthreads();
  if (threadIdx.x == 0) part[blockIdx.x] = sd[0] + sd[1] + sd[2] + sd[3];
}

__global__ __launch_bounds__(256) void k_scan_mid(int* __restrict__ part,
                                                  int* __restrict__ off1_last,
                                                  int* __restrict__ off2_last) {
  __shared__ int sd[256];
  for (int g = 0; g < 2; g++) {
    int base = g * NCHUNK;
    int v = (threadIdx.x < NCHUNK) ? part[base + threadIdx.x] : 0;
    sd[threadIdx.x] = v;
    __syncthreads();
    for (int o = 1; o < 256; o <<= 1) {
      int x = (threadIdx.x >= o) ? sd[threadIdx.x - o] : 0;
      __syncthreads();
      sd[threadIdx.x] += x;
      __syncthreads();
    }
    if (threadIdx.x < NCHUNK) part[base + threadIdx.x] = sd[threadIdx.x] - v;
    if (threadIdx.x == 255) *(g ? off2_last : off1_last) = sd[255];
    __syncthreads();
  }
}

__global__ __launch_bounds__(256) void k_scan_final(const int* __restrict__ cnt1,
                                                    const int* __restrict__ cnt2,
                                                    const int* __restrict__ part,
                                                    int* __restrict__ off1,
                                                    int* __restrict__ pos1,
                                                    int* __restrict__ off2,
                                                    int* __restrict__ pos2) {
  int g = blockIdx.x >= NCHUNK;
  int chunk = g ? blockIdx.x - NCHUNK : blockIdx.x;
  const int* cnt = g ? cnt2 : cnt1;
  int* off = g ? off2 : off1;
  int* pos = g ? pos2 : pos1;
  __shared__ int sd[256];
  int i = chunk * 256 + threadIdx.x;
  int v = (i < NN) ? cnt[i] : 0;
  sd[threadIdx.x] = v;
  __syncthreads();
  for (int o = 1; o < 256; o <<= 1) {
    int x = (threadIdx.x >= o) ? sd[threadIdx.x - o] : 0;
    __syncthreads();
    sd[threadIdx.x] += x;
    __syncthreads();
  }
  if (i < NN) {
    int ex = part[blockIdx.x] + sd[threadIdx.x] - v;
    off[i] = ex; pos[i] = ex;
  }
}

// ---------------- fill CSR ----------------

__global__ __launch_bounds__(256) void k_fill(const int* __restrict__ ei,
                                              const int* __restrict__ nei,
                                              const float* __restrict__ w,
                                              const float* __restrict__ dinv1,
                                              const float* __restrict__ dinv2,
                                              int* __restrict__ pos1,
                                              int* __restrict__ csr1_src,
                                              float* __restrict__ csr1_nrm,
                                              int* __restrict__ pos2,
                                              int* __restrict__ csr2_src,
                                              float* __restrict__ csr2_nrm) {
  int e = blockIdx.x * 256 + threadIdx.x;
  if (e < NE) {
    int r = ei[e], c = ei[NE + e];
    float nv = dinv1[r] * w[e] * dinv1[c];
    int s = atomicAdd(&pos1[c], 1);
    csr1_src[s] = r; csr1_nrm[s] = nv;
    int r2 = nei[e], c2 = nei[NE + e];
    float nv2 = dinv2[r2] * dinv2[c2];
    int s2 = atomicAdd(&pos2[c2], 1);
    csr2_src[s2] = r2; csr2_nrm[s2] = nv2;
  }
}

// ---------------- layer1 aggregate (CSR, no atomics) ----------------

__global__ __launch_bounds__(256) void k_agg1(const int* __restrict__ off,
                                              const int* __restrict__ csr_src,
                                              const float* __restrict__ csr_nrm,
                                              const int* __restrict__ ids,
                                              const float* __restrict__ emb,
                                              float* __restrict__ aggX) {
  int wave = threadIdx.x >> 6, lane = threadIdx.x & 63;
  int node = blockIdx.x * 4 + wave;
  int start = off[node], end = off[node + 1];
  float2 acc = make_float2(0.f, 0.f);
  int i = start;
  for (; i + 1 < end; i += 2) {
    int s0 = csr_src[i], s1 = csr_src[i + 1];
    float n0 = csr_nrm[i], n1 = csr_nrm[i + 1];
    float2 v0 = *(const float2*)(emb + (size_t)ids[s0] * 128 + lane * 2);
    float2 v1 = *(const float2*)(emb + (size_t)ids[s1] * 128 + lane * 2);
    acc.x = fmaf(n0, v0.x, fmaf(n1, v1.x, acc.x));
    acc.y = fmaf(n0, v0.y, fmaf(n1, v1.y, acc.y));
  }
  if (i < end) {
    int s0 = csr_src[i];
    float n0 = csr_nrm[i];
    float2 v0 = *(const float2*)(emb + (size_t)ids[s0] * 128 + lane * 2);
    acc.x = fmaf(n0, v0.x, acc.x);
    acc.y = fmaf(n0, v0.y, acc.y);
  }
  *(float2*)(aggX + (size_t)node * 128 + lane * 2) = acc;
}

// ---------------- layer2 aggregate + bias + ELU + bf16 split ----------------

__global__ __launch_bounds__(256) void k_agg2(const int* __restrict__ off,
                                              const int* __restrict__ csr_src,
                                              const float* __restrict__ csr_nrm,
                                              const float* __restrict__ h2,
                                              const float* __restrict__ b,
                                              short* __restrict__ xh,
                                              short* __restrict__ xl) {
  int wave = threadIdx.x >> 6, lane = threadIdx.x & 63;
  int node = blockIdx.x * 4 + wave;
  int start = off[node], end = off[node + 1];
  float2 acc = make_float2(0.f, 0.f);
  int i = start;
  for (; i + 1 < end; i += 2) {
    int s0 = csr_src[i], s1 = csr_src[i + 1];
    float n0 = csr_nrm[i], n1 = csr_nrm[i + 1];
    float2 v0 = *(const float2*)(h2 + (size_t)s0 * 128 + lane * 2);
    float2 v1 = *(const float2*)(h2 + (size_t)s1 * 128 + lane * 2);
    acc.x = fmaf(n0, v0.x, fmaf(n1, v1.x, acc.x));
    acc.y = fmaf(n0, v0.y, fmaf(n1, v1.y, acc.y));
  }
  if (i < end) {
    int s0 = csr_src[i];
    float n0 = csr_nrm[i];
    float2 v0 = *(const float2*)(h2 + (size_t)s0 * 128 + lane * 2);
    acc.x = fmaf(n0, v0.x, acc.x);
    acc.y = fmaf(n0, v0.y, acc.y);
  }
  float vx = acc.x + b[lane * 2];
  float vy = acc.y + b[lane * 2 + 1];
  vx = vx > 0.f ? vx : expm1f(vx);
  vy = vy > 0.f ? vy : expm1f(vy);
  short hx, lx, hy, ly;
  split2(vx, hx, lx);
  split2(vy, hy, ly);
  unsigned hp = (unsigned)(unsigned short)hx | ((unsigned)(unsigned short)hy << 16);
  unsigned lp = (unsigned)(unsigned short)lx | ((unsigned)(unsigned short)ly << 16);
  *(unsigned*)(xh + (size_t)node * 128 + lane * 2) = hp;
  *(unsigned*)(xl + (size_t)node * 128 + lane * 2) = lp;
}

// ---------------- GEMM1: x1[N,256] = elu(aggX[N,128] @ W_in[128,256] + b) ------

__global__ __launch_bounds__(256) void k_gemm_aggin(const float* __restrict__ X,
                                                    const float* __restrict__ W,
                                                    const float* __restrict__ b,
                                                    float* __restrict__ C) {
  __shared__ float As[32][128];
  int r0 = blockIdx.x * 32;
  int t = threadIdx.x;
  for (int i = t; i < 1024; i += 256) {
    int r = i >> 5, q = (i & 31) << 2;
    int rr = r0 + r;
    float4 v = make_float4(0.f, 0.f, 0.f, 0.f);
    if (rr < NN) v = *(const float4*)(X + (size_t)rr * 128 + q);
    *(float4*)(&As[r][q]) = v;
  }
  __syncthreads();
  int tc = t & 31, tr = t >> 5;
  int c0 = tc * 8, rr0 = tr * 4;
  float acc[4][8];
#pragma unroll
  for (int r = 0; r < 4; r++)
#pragma unroll
    for (int c = 0; c < 8; c++) acc[r][c] = 0.f;

  for (int k0 = 0; k0 < 128; k0 += 4) {
    float a_[4][4];
#pragma unroll
    for (int r = 0; r < 4; r++) {
      float4 v = *(const float4*)(&As[rr0 + r][k0]);
      a_[r][0] = v.x; a_[r][1] = v.y; a_[r][2] = v.z; a_[r][3] = v.w;
    }
#pragma unroll
    for (int kk = 0; kk < 4; kk++) {
      float4 w0 = *(const float4*)(W + (size_t)(k0 + kk) * 256 + c0);
      float4 w1 = *(const float4*)(W + (size_t)(k0 + kk) * 256 + c0 + 4);
#pragma unroll
      for (int r = 0; r < 4; r++) {
        float av = a_[r][kk];
        acc[r][0] += av * w0.x; acc[r][1] += av * w0.y;
        acc[r][2] += av * w0.z; acc[r][3] += av * w0.w;
        acc[r][4] += av * w1.x; acc[r][5] += av * w1.y;
        acc[r][6] += av * w1.z; acc[r][7] += av * w1.w;
      }
    }
  }
  float4 bb0 = *(const float4*)(b + c0);
  float4 bb1 = *(const float4*)(b + c0 + 4);
#pragma unroll
  for (int r = 0; r < 4; r++) {
    int rr = r0 + rr0 + r;
    if (rr < NN) {
      float o[8];
      o[0] = acc[r][0] + bb0.x; o[1] = acc[r][1] + bb0.y;
      o[2] = acc[r][2] + bb0.z; o[3] = acc[r][3] + bb0.w;
      o[4] = acc[r][4] + bb1.x; o[5] = acc[r][5] + bb1.y;
      o[6] = acc[r][6] + bb1.z; o[7] = acc[r][7] + bb1.w;
#pragma unroll
      for (int c = 0; c < 8; c++) o[c] = o[c] > 0.f ? o[c] : expm1f(o[c]);
      *(float4*)(C + (size_t)rr * 256 + c0) = make_float4(o[0], o[1], o[2], o[3]);
      *(float4*)(C + (size_t)rr * 256 + c0 + 4) = make_float4(o[4], o[5], o[6], o[7]);
    }
  }
}

// ---------------- GEMM2: h2[N,128] = x1[N,256] @ W_out[256,128] ----------------

__global__ __launch_bounds__(256) void k_gemm_mid(const float* __restrict__ X,
                                                  const float* __restrict__ W,
                                                  float* __restrict__ C) {
  __shared__ float As[32][256];
  int r0 = blockIdx.x * 32;
  int t = threadIdx.x;
  for (int i = t; i < 2048; i += 256) {
    int r = i >> 6, q = (i & 63) << 2;
    int rr = r0 + r;
    float4 v = make_float4(0.f, 0.f, 0.f, 0.f);
    if (rr < NN) v = *(const float4*)(X + (size_t)rr * 256 + q);
    *(float4*)(&As[r][q]) = v;
  }
  __syncthreads();
  int tc = t & 31, tr = t >> 5;
  int c0 = tc * 4, rr0 = tr * 4;
  float acc[4][4];
#pragma unroll
  for (int r = 0; r < 4; r++)
#pragma unroll
    for (int c = 0; c < 4; c++) acc[r][c] = 0.f;

  for (int k0 = 0; k0 < 256; k0 += 4) {
    float a_[4][4];
#pragma unroll
    for (int r = 0; r < 4; r++) {
      float4 v = *(const float4*)(&As[rr0 + r][k0]);
      a_[r][0] = v.x; a_[r][1] = v.y; a_[r][2] = v.z; a_[r][3] = v.w;
    }
#pragma unroll
    for (int kk = 0; kk < 4; kk++) {
      float4 w = *(const float4*)(W + (size_t)(k0 + kk) * 128 + c0);
#pragma unroll
      for (int r = 0; r < 4; r++) {
        float av = a_[r][kk];
        acc[r][0] += av * w.x; acc[r][1] += av * w.y;
        acc[r][2] += av * w.z; acc[r][3] += av * w.w;
      }
    }
  }
#pragma unroll
  for (int r = 0; r < 4; r++) {
    int rr = r0 + rr0 + r;
    if (rr < NN) {
      float4 o = make_float4(acc[r][0], acc[r][1], acc[r][2], acc[r][3]);
      *(float4*)(C + (size_t)rr * 128 + c0) = o;
    }
  }
}

// ---------------- node-level decoder-layer1 factorization ----------------
// Pa[n] = x2[n] @ W1[:128,:], Pb[n] = x2[n] @ W1[128:,:]  (fp32 out)
// Then per-edge t1 = relu(Pa[src] + Pb[dst] + b1) — no per-edge layer-1 GEMM.

__global__ __launch_bounds__(256) void k_pab(const short* __restrict__ x2h,
                                             const short* __restrict__ x2l,
                                             const short* __restrict__ w1th,
                                             const short* __restrict__ w1tl,
                                             float* __restrict__ Pa,
                                             float* __restrict__ Pb) {
  __shared__ short Xh[32 * 136];
  __shared__ short Xl[32 * 136];
  int t = threadIdx.x;
  int n0 = blockIdx.x * 32;
#pragma unroll
  for (int j = 0; j < 2; j++) {
    int i = t + 256 * j;
    int row = i >> 4, q = i & 15;
    int node = n0 + row; if (node >= NN) node = NN - 1;
    *(uint4*)&Xh[row * 136 + q * 8] = *(const uint4*)(x2h + (size_t)node * 128 + q * 8);
    *(uint4*)&Xl[row * 136 + q * 8] = *(const uint4*)(x2l + (size_t)node * 128 + q * 8);
  }
  __syncthreads();

  int w = t >> 6, lane = t & 63;
  int quad = lane >> 4, l16 = lane & 15;
  int nb = w * 32;
  int aoff0 = l16 * 136 + quad * 8;
  int aoff1 = (16 + l16) * 136 + quad * 8;
  int bo0 = (nb + l16) * 256 + quad * 8;
  int bo1 = (nb + 16 + l16) * 256 + quad * 8;

  f4_t aa[2][2], ab[2][2];
#pragma unroll
  for (int mi = 0; mi < 2; mi++)
#pragma unroll
    for (int ni = 0; ni < 2; ni++) {
      aa[mi][ni] = (f4_t){0.f, 0.f, 0.f, 0.f};
      ab[mi][ni] = (f4_t){0.f, 0.f, 0.f, 0.f};
    }

#pragma unroll
  for (int kb = 0; kb < 4; kb++) {
    int k0 = kb * 32;
    s8_t ah0 = *(const s8_t*)&Xh[aoff0 + k0];
    s8_t ah1 = *(const s8_t*)&Xh[aoff1 + k0];
    s8_t al0 = *(const s8_t*)&Xl[aoff0 + k0];
    s8_t al1 = *(const s8_t*)&Xl[aoff1 + k0];
    // Pa: W1 rows k0..k0+31 (src half)
    {
      s8_t bh0 = *(const s8_t*)(w1th + bo0 + k0);
      s8_t bh1 = *(const s8_t*)(w1th + bo1 + k0);
      s8_t bl0 = *(const s8_t*)(w1tl + bo0 + k0);
      s8_t bl1 = *(const s8_t*)(w1tl + bo1 + k0);
      aa[0][0] = __builtin_amdgcn_mfma_f32_16x16x32_bf16(ah0, bh0, aa[0][0], 0, 0, 0);
      aa[0][0] = __builtin_amdgcn_mfma_f32_16x16x32_bf16(ah0, bl0, aa[0][0], 0, 0, 0);
      aa[0][0] = __builtin_amdgcn_mfma_f32_16x16x32_bf16(al0, bh0, aa[0][0], 0, 0, 0);
      aa[0][1] = __builtin_amdgcn_mfma_f32_16x16x32_bf16(ah0, bh1, aa[0][1], 0, 0, 0);
      aa[0][1] = __builtin_amdgcn_mfma_f32_16x16x32_bf16(ah0, bl1, aa[0][1], 0, 0, 0);
      aa[0][1] = __builtin_amdgcn_mfma_f32_16x16x32_bf16(al0, bh1, aa[0][1], 0, 0, 0);
      aa[1][0] = __builtin_amdgcn_mfma_f32_16x16x32_bf16(ah1, bh0, aa[1][0], 0, 0, 0);
      aa[1][0] = __builtin_amdgcn_mfma_f32_16x16x32_bf16(ah1, bl0, aa[1][0], 0, 0, 0);
      aa[1][0] = __builtin_amdgcn_mfma_f32_16x16x32_bf16(al1, bh0, aa[1][0], 0, 0, 0);
      aa[1][1] = __builtin_amdgcn_mfma_f32_16x16x32_bf16(ah1, bh1, aa[1][1], 0, 0, 0);
      aa[1][1] = __builtin_amdgcn_mfma_f32_16x16x32_bf16(ah1, bl1, aa[1][1], 0, 0, 0);
      aa[1][1] = __builtin_amdgcn_mfma_f32_16x16x32_bf16(al1, bh1, aa[1][1], 0, 0, 0);
    }
    // Pb: W1 rows 128+k0.. (dst half)
    {
      s8_t bh0 = *(const s8_t*)(w1th + bo0 + 128 + k0);
      s8_t bh1 = *(const s8_t*)(w1th + bo1 + 128 + k0);
      s8_t bl0 = *(const s8_t*)(w1tl + bo0 + 128 + k0);
      s8_t bl1 = *(const s8_t*)(w1tl + bo1 + 128 + k0);
      ab[0][0] = __builtin_amdgcn_mfma_f32_16x16x32_bf16(ah0, bh0, ab[0][0], 0, 0, 0);
      ab[0][0] = __builtin_amdgcn_mfma_f32_16x16x32_bf16(ah0, bl0, ab[0][0], 0, 0, 0);
      ab[0][0] = __builtin_amdgcn_mfma_f32_16x16x32_bf16(al0, bh0, ab[0][0], 0, 0, 0);
      ab[0][1] = __builtin_amdgcn_mfma_f32_16x16x32_bf16(ah0, bh1, ab[0][1], 0, 0, 0);
      ab[0][1] = __builtin_amdgcn_mfma_f32_16x16x32_bf16(ah0, bl1, ab[0][1], 0, 0, 0);
      ab[0][1] = __builtin_amdgcn_mfma_f32_16x16x32_bf16(al0, bh1, ab[0][1], 0, 0, 0);
      ab[1][0] = __builtin_amdgcn_mfma_f32_16x16x32_bf16(ah1, bh0, ab[1][0], 0, 0, 0);
      ab[1][0] = __builtin_amdgcn_mfma_f32_16x16x32_bf16(ah1, bl0, ab[1][0], 0, 0, 0);
      ab[1][0] = __builtin_amdgcn_mfma_f32_16x16x32_bf16(al1, bh0, ab[1][0], 0, 0, 0);
      ab[1][1] = __builtin_amdgcn_mfma_f32_16x16x32_bf16(ah1, bh1, ab[1][1], 0, 0, 0);
      ab[1][1] = __builtin_amdgcn_mfma_f32_16x16x32_bf16(ah1, bl1, ab[1][1], 0, 0, 0);
      ab[1][1] = __builtin_amdgcn_mfma_f32_16x16x32_bf16(al1, bh1, ab[1][1], 0, 0, 0);
    }
  }

#pragma unroll
  for (int mi = 0; mi < 2; mi++)
#pragma unroll
    for (int ni = 0; ni < 2; ni++) {
      int col = nb + ni * 16 + l16;
#pragma unroll
      for (int r = 0; r < 4; r++) {
        int node = n0 + mi * 16 + quad * 4 + r;
        if (node < NN) {
          Pa[(size_t)node * 128 + col] = aa[mi][ni][r];
          Pb[(size_t)node * 128 + col] = ab[mi][ni][r];
        }
      }
    }
}

// ---------------- fused edge decoder v6 ----------------
// 25000 blocks x 32 edges, 256 thr (4 waves). No layer-1 GEMM: t1 =
// relu(Pa[src]+Pb[dst]+b1) computed straight from global gathers into the
// layer-2 MFMA A-layout (vector ds_write_b128). LDS = 17.4 KB -> ~6 blocks/CU.

#define ST 136   // t1 LDS stride (shorts)
#define S2 132   // layer-2 output fp32 stride (floats)

__global__ __launch_bounds__(256, 4) void k_decoder(
    const float* __restrict__ Pa, const float* __restrict__ Pb,
    const int* __restrict__ ei, const float* __restrict__ b1,
    const short* __restrict__ w2th, const short* __restrict__ w2tl,
    const float* __restrict__ b2,
    const float* __restrict__ W3, const float* __restrict__ b3,
    float* __restrict__ out) {
  __shared__ short ThTl[2 * 32 * ST];
  short* Th = ThTl;
  short* Tl = ThTl + 32 * ST;
  float* T2 = (float*)ThTl;   // 32*S2*4 = 16.9 KB <= 17.4 KB, aliases (dead then)

  int t = threadIdx.x;
  int e0 = blockIdx.x * 32;

  // ---- t1 stage: 512 items (edge, 8-dim chunk), 2 per thread ----
#pragma unroll
  for (int j = 0; j < 2; j++) {
    int i = t + 256 * j;
    int le = i >> 4, q = i & 15;
    int src = ei[e0 + le], dst = ei[NE + e0 + le];
    const float* pa = Pa + (size_t)src * 128 + q * 8;
    const float* pb = Pb + (size_t)dst * 128 + q * 8;
    float4 a0 = *(const float4*)(pa);
    float4 a1 = *(const float4*)(pa + 4);
    float4 c0 = *(const float4*)(pb);
    float4 c1 = *(const float4*)(pb + 4);
    float4 d0 = *(const float4*)(b1 + q * 8);
    float4 d1 = *(const float4*)(b1 + q * 8 + 4);
    float v[8];
    v[0] = a0.x + c0.x + d0.x; v[1] = a0.y + c0.y + d0.y;
    v[2] = a0.z + c0.z + d0.z; v[3] = a0.w + c0.w + d0.w;
    v[4] = a1.x + c1.x + d1.x; v[5] = a1.y + c1.y + d1.y;
    v[6] = a1.z + c1.z + d1.z; v[7] = a1.w + c1.w + d1.w;
    s8_t hv, lv;
#pragma unroll
    for (int k = 0; k < 8; k++) {
      float x = fmaxf(v[k], 0.f);
      short h, l; split2(x, h, l);
      hv[k] = h; lv[k] = l;
    }
    *(s8_t*)&Th[le * ST + q * 8] = hv;
    *(s8_t*)&Tl[le * ST + q * 8] = lv;
  }
  __syncthreads();   // (B1) Th/Tl ready

  int w = t >> 6, lane = t & 63;
  int quad = lane >> 4, l16 = lane & 15;
  int nb = w * 32;
  float b2v0 = b2[nb + l16], b2v1 = b2[nb + 16 + l16];
  float b3v = b3[0];

  int toff0 = l16 * ST + quad * 8;
  int toff1 = (16 + l16) * ST + quad * 8;
  int coff0 = (nb + l16) * 128 + quad * 8;
  int coff1 = (nb + 16 + l16) * 128 + quad * 8;

  // ---- layer 2: [32,128] @ W2[128,128] (hi*hi + hi*lo + lo*hi) ----
  f4_t acc2[2][2];
#pragma unroll
  for (int mi = 0; mi < 2; mi++)
#pragma unroll
    for (int ni = 0; ni < 2; ni++) acc2[mi][ni] = (f4_t){0.f, 0.f, 0.f, 0.f};

#pragma unroll
  for (int kb = 0; kb < 4; kb++) {
    int k0 = kb * 32;
    s8_t ah0 = *(const s8_t*)&Th[toff0 + k0];
    s8_t ah1 = *(const s8_t*)&Th[toff1 + k0];
    s8_t al0 = *(const s8_t*)&Tl[toff0 + k0];
    s8_t al1 = *(const s8_t*)&Tl[toff1 + k0];
    s8_t bh0 = *(const s8_t*)(w2th + coff0 + k0);
    s8_t bh1 = *(const s8_t*)(w2th + coff1 + k0);
    s8_t bl0 = *(const s8_t*)(w2tl + coff0 + k0);
    s8_t bl1 = *(const s8_t*)(w2tl + coff1 + k0);
    acc2[0][0] = __builtin_amdgcn_mfma_f32_16x16x32_bf16(ah0, bh0, acc2[0][0], 0, 0, 0);
    acc2[0][0] = __builtin_amdgcn_mfma_f32_16x16x32_bf16(ah0, bl0, acc2[0][0], 0, 0, 0);
    acc2[0][0] = __builtin_amdgcn_mfma_f32_16x16x32_bf16(al0, bh0, acc2[0][0], 0, 0, 0);
    acc2[0][1] = __builtin_amdgcn_mfma_f32_16x16x32_bf16(ah0, bh1, acc2[0][1], 0, 0, 0);
    acc2[0][1] = __builtin_amdgcn_mfma_f32_16x16x32_bf16(ah0, bl1, acc2[0][1], 0, 0, 0);
    acc2[0][1] = __builtin_amdgcn_mfma_f32_16x16x32_bf16(al0, bh1, acc2[0][1], 0, 0, 0);
    acc2[1][0] = __builtin_amdgcn_mfma_f32_16x16x32_bf16(ah1, bh0, acc2[1][0], 0, 0, 0);
    acc2[1][0] = __builtin_amdgcn_mfma_f32_16x16x32_bf16(ah1, bl0, acc2[1][0], 0, 0, 0);
    acc2[1][0] = __builtin_amdgcn_mfma_f32_16x16x32_bf16(al1, bh0, acc2[1][0], 0, 0, 0);
    acc2[1][1] = __builtin_amdgcn_mfma_f32_16x16x32_bf16(ah1, bh1, acc2[1][1], 0, 0, 0);
    acc2[1][1] = __builtin_amdgcn_mfma_f32_16x16x32_bf16(ah1, bl1, acc2[1][1], 0, 0, 0);
    acc2[1][1] = __builtin_amdgcn_mfma_f32_16x16x32_bf16(al1, bh1, acc2[1][1], 0, 0, 0);
  }
  __syncthreads();   // (B2) Th/Tl reads done -> T2 (alias) writable

  // bias + relu -> T2 (fp32)
#pragma unroll
  for (int mi = 0; mi < 2; mi++)
#pragma unroll
    for (int ni = 0; ni < 2; ni++) {
      float bv = ni ? b2v1 : b2v0;
      int col = nb + ni * 16 + l16;
#pragma unroll
      for (int r = 0; r < 4; r++) {
        int row = mi * 16 + quad * 4 + r;
        T2[row * S2 + col] = fmaxf(acc2[mi][ni][r] + bv, 0.f);
      }
    }
  __syncthreads();   // (B3) T2 ready

  // ---- layer 3: out[e] = dot(t2[e], W3) + b3 ----
  {
    int le = t >> 3, j0 = (t & 7) * 16;
    float s = 0.f;
#pragma unroll
    for (int j = 0; j < 16; j += 4) {
      float4 v = *(const float4*)(&T2[le * S2 + j0 + j]);
      float4 wv = *(const float4*)(W3 + j0 + j);
      s += v.x * wv.x + v.y * wv.y + v.z * wv.z + v.w * wv.w;
    }
    s += __shfl_down(s, 4);
    s += __shfl_down(s, 2);
    s += __shfl_down(s, 1);
    if ((t & 7) == 0) out[e0 + le] = s + b3v;
  }
}

// ---------------- launch ----------------

extern "C" void kernel_launch(void* const* d_in, const int* in_sizes, int n_in,
                              void* d_out, int out_size, void* d_ws, size_t ws_size,
                              hipStream_t stream) {
  const int*   node_ids = (const int*)d_in[0];
  const int*   ei       = (const int*)d_in[1];
  const int*   nei      = (const int*)d_in[2];
  const float* eattr    = (const float*)d_in[3];
  const float* emb      = (const float*)d_in[4];
  const float* W_in     = (const float*)d_in[5];
  const float* b_in     = (const float*)d_in[6];
  const float* W_out    = (const float*)d_in[7];
  const float* b_out    = (const float*)d_in[8];
  const float* W1       = (const float*)d_in[9];
  const float* b1       = (const float*)d_in[10];
  const float* W2       = (const float*)d_in[11];
  const float* b2       = (const float*)d_in[12];
  const float* W3       = (const float*)d_in[13];
  const float* b3       = (const float*)d_in[14];
  float* out = (float*)d_out;

  // workspace layout (floats)
  float* ws    = (float*)d_ws;
  float* bufA  = ws;                          // N*128: aggX -> h2 -> Pa
  float* bufB  = bufA + (size_t)NN * 128;     // N*256: x1 -> [x2h|x2l | Pb]
  int*   cnt1  = (int*)(bufB + (size_t)NN * 256);
  int*   cnt2  = cnt1 + NN;
  float* deg1  = (float*)(cnt2 + NN);
  float* dinv1 = deg1 + NN;
  float* dinv2 = dinv1 + NN;
  int*   off1  = (int*)(dinv2 + NN);          // N+1
  int*   pos1  = off1 + NN + 1;               // N
  int*   off2  = pos1 + NN;                   // N+1
  int*   pos2  = off2 + NN + 1;               // N
  int*   c1src = pos2 + NN;                   // E
  float* c1nrm = (float*)(c1src + NE);        // E
  int*   c2src = (int*)(c1nrm + NE);          // E
  float* c2nrm = (float*)(c2src + NE);        // E
  short* w1th  = (short*)(c2nrm + NE);
  short* w1tl  = w1th + 32768;
  short* w2th  = w1tl + 32768;
  short* w2tl  = w2th + 16384;
  int*   part  = (int*)(w2tl + 16384);        // 2*NCHUNK

  float* aggX  = bufA;
  float* h2    = bufA;                        // overwrites aggX (dead)
  float* Pa    = bufA;                        // overwrites h2 (dead after agg2)
  float* x1    = bufB;
  short* x2h   = (short*)bufB;                // overwrites x1 (dead)
  short* x2l   = x2h + (size_t)NN * 128;
  float* Pb    = bufB + (size_t)NN * 128;     // second half of bufB (free)

  // weight split
  k_wcvt<<<192, 256, 0, stream>>>(W1, W2, w1th, w1tl, w2th, w2tl);

  // CSR build: hist -> dinv -> scan(3-phase) -> fill
  hipMemsetAsync(cnt1, 0, 3 * (size_t)NN * sizeof(int), stream);  // cnt1,cnt2,deg1
  k_hist<<<NE / 256, 256, 0, stream>>>(ei, nei, eattr, cnt1, deg1, cnt2);
  k_dinvs<<<(NN + 255) / 256, 256, 0, stream>>>(deg1, cnt2, dinv1, dinv2);
  k_scan_part<<<2 * NCHUNK, 256, 0, stream>>>(cnt1, cnt2, part);
  k_scan_mid<<<1, 256, 0, stream>>>(part, off1 + NN, off2 + NN);
  k_scan_final<<<2 * NCHUNK, 256, 0, stream>>>(cnt1, cnt2, part,
                                               off1, pos1, off2, pos2);
  k_fill<<<NE / 256, 256, 0, stream>>>(ei, nei, eattr, dinv1, dinv2,
                                       pos1, c1src, c1nrm, pos2, c2src, c2nrm);

  // layer 1: aggregate (CSR) -> GEMM + bias + ELU
  k_agg1<<<NN / 4, 256, 0, stream>>>(off1, c1src, c1nrm, node_ids, emb, aggX);
  k_gemm_aggin<<<(NN + 31) / 32, 256, 0, stream>>>(aggX, W_in, b_in, x1);

  // layer 2: transform-first -> aggregate (+bias+ELU+split fused)
  k_gemm_mid<<<(NN + 31) / 32, 256, 0, stream>>>(x1, W_out, h2);
  k_agg2<<<NN / 4, 256, 0, stream>>>(off2, c2src, c2nrm, h2, b_out, x2h, x2l);

  // decoder layer-1 factorization: Pa/Pb per node (h2 dead -> Pa reuses bufA)
  k_pab<<<(NN + 31) / 32, 256, 0, stream>>>(x2h, x2l, w1th, w1tl, Pa, Pb);

  // decoder v6 (no per-edge layer-1)
  k_decoder<<<NE / 32, 256, 0, stream>>>(Pa, Pb, ei, b1,
                                         w2th, w2tl, b2, W3, b3, out);
}

// Round 8
// 829.103 us; speedup vs baseline: 2.4435x; 1.0429x over previous
//
#include <hip/hip_runtime.h>
#include <math.h>

#define NN 50000
#define NE 800000
// D = 128, H = 256

typedef __attribute__((ext_vector_type(8))) short s8_t;   // 8 bf16
typedef __attribute__((ext_vector_type(4))) float f4_t;   // 4 fp32

__device__ __forceinline__ short bf16_rne(float v) {
  unsigned u = __float_as_uint(v);
  unsigned r = (u + 0x7FFFu + ((u >> 16) & 1u)) >> 16;
  return (short)r;
}
__device__ __forceinline__ float bf16_tof(short h) {
  return __uint_as_float(((unsigned)(unsigned short)h) << 16);
}
__device__ __forceinline__ void split2(float v, short& hi, short& lo) {
  hi = bf16_rne(v);
  lo = bf16_rne(v - bf16_tof(hi));
}

// ---------------- weight split/transpose ----------------

__global__ __launch_bounds__(256) void k_wcvt(const float* __restrict__ W1,
                                              const float* __restrict__ W2,
                                              short* __restrict__ w1th,
                                              short* __restrict__ w1tl,
                                              short* __restrict__ w2th,
                                              short* __restrict__ w2tl) {
  int i = blockIdx.x * 256 + threadIdx.x;
  if (i < 32768) {
    int k = i >> 7, n = i & 127;
    short h, l; split2(W1[i], h, l);
    w1th[n * 256 + k] = h; w1tl[n * 256 + k] = l;
  } else if (i < 49152) {
    int j = i - 32768;
    int k = j >> 7, n = j & 127;
    short h, l; split2(W2[j], h, l);
    w2th[n * 128 + k] = h; w2tl[n * 128 + k] = l;
  }
}

// ---------------- CSR build: histogram ----------------

__global__ __launch_bounds__(256) void k_hist(const int* __restrict__ ei,
                                              const int* __restrict__ nei,
                                              const float* __restrict__ w,
                                              int* __restrict__ cnt1,
                                              float* __restrict__ deg1,
                                              int* __restrict__ cnt2) {
  int e = blockIdx.x * 256 + threadIdx.x;
  if (e < NE) {
    int c1 = ei[NE + e];
    atomicAdd(&cnt1[c1], 1);
    atomicAdd(&deg1[c1], w[e]);
    atomicAdd(&cnt2[nei[NE + e]], 1);
  }
}

__global__ __launch_bounds__(256) void k_dinvs(const float* __restrict__ deg1,
                                               const int* __restrict__ cnt2,
                                               float* __restrict__ dinv1,
                                               float* __restrict__ dinv2) {
  int i = blockIdx.x * 256 + threadIdx.x;
  if (i < NN) {
    float d1 = deg1[i];
    dinv1[i] = d1 > 0.f ? (1.0f / sqrtf(d1)) : 0.f;
    int c2 = cnt2[i];
    dinv2[i] = c2 > 0 ? (1.0f / sqrtf((float)c2)) : 0.f;
  }
}

// ---------------- hierarchical exclusive scan ----------------

#define NCHUNK 196   // ceil(50000/256)

__global__ __launch_bounds__(256) void k_scan_part(const int* __restrict__ cnt1,
                                                   const int* __restrict__ cnt2,
                                                   int* __restrict__ part) {
  int g = blockIdx.x >= NCHUNK;
  int chunk = g ? blockIdx.x - NCHUNK : blockIdx.x;
  const int* cnt = g ? cnt2 : cnt1;
  int i = chunk * 256 + threadIdx.x;
  int v = (i < NN) ? cnt[i] : 0;
  __shared__ int sd[4];
#pragma unroll
  for (int o = 32; o; o >>= 1) v += __shfl_down(v, o);
  if ((threadIdx.x & 63) == 0) sd[threadIdx.x >> 6] = v;
  __syncthreads();
  if (threadIdx.x == 0) part[blockIdx.x] = sd[0] + sd[1] + sd[2] + sd[3];
}

__global__ __launch_bounds__(256) void k_scan_mid(int* __restrict__ part,
                                                  int* __restrict__ off1_last,
                                                  int* __restrict__ off2_last) {
  __shared__ int sd[256];
  for (int g = 0; g < 2; g++) {
    int base = g * NCHUNK;
    int v = (threadIdx.x < NCHUNK) ? part[base + threadIdx.x] : 0;
    sd[threadIdx.x] = v;
    __syncthreads();
    for (int o = 1; o < 256; o <<= 1) {
      int x = (threadIdx.x >= o) ? sd[threadIdx.x - o] : 0;
      __syncthreads();
      sd[threadIdx.x] += x;
      __syncthreads();
    }
    if (threadIdx.x < NCHUNK) part[base + threadIdx.x] = sd[threadIdx.x] - v;
    if (threadIdx.x == 255) *(g ? off2_last : off1_last) = sd[255];
    __syncthreads();
  }
}

__global__ __launch_bounds__(256) void k_scan_final(const int* __restrict__ cnt1,
                                                    const int* __restrict__ cnt2,
                                                    const int* __restrict__ part,
                                                    int* __restrict__ off1,
                                                    int* __restrict__ pos1,
                                                    int* __restrict__ off2,
                                                    int* __restrict__ pos2) {
  int g = blockIdx.x >= NCHUNK;
  int chunk = g ? blockIdx.x - NCHUNK : blockIdx.x;
  const int* cnt = g ? cnt2 : cnt1;
  int* off = g ? off2 : off1;
  int* pos = g ? pos2 : pos1;
  __shared__ int sd[256];
  int i = chunk * 256 + threadIdx.x;
  int v = (i < NN) ? cnt[i] : 0;
  sd[threadIdx.x] = v;
  __syncthreads();
  for (int o = 1; o < 256; o <<= 1) {
    int x = (threadIdx.x >= o) ? sd[threadIdx.x - o] : 0;
    __syncthreads();
    sd[threadIdx.x] += x;
    __syncthreads();
  }
  if (i < NN) {
    int ex = part[blockIdx.x] + sd[threadIdx.x] - v;
    off[i] = ex; pos[i] = ex;
  }
}

// ---------------- fill CSR (graph1 also stores dst + edge id) ----------------

__global__ __launch_bounds__(256) void k_fill(const int* __restrict__ ei,
                                              const int* __restrict__ nei,
                                              const float* __restrict__ w,
                                              const float* __restrict__ dinv1,
                                              const float* __restrict__ dinv2,
                                              int* __restrict__ pos1,
                                              int* __restrict__ csr1_src,
                                              float* __restrict__ csr1_nrm,
                                              int* __restrict__ csr1_dst,
                                              int* __restrict__ csr1_eid,
                                              int* __restrict__ pos2,
                                              int* __restrict__ csr2_src,
                                              float* __restrict__ csr2_nrm) {
  int e = blockIdx.x * 256 + threadIdx.x;
  if (e < NE) {
    int r = ei[e], c = ei[NE + e];
    float nv = dinv1[r] * w[e] * dinv1[c];
    int s = atomicAdd(&pos1[c], 1);
    csr1_src[s] = r; csr1_nrm[s] = nv; csr1_dst[s] = c; csr1_eid[s] = e;
    int r2 = nei[e], c2 = nei[NE + e];
    float nv2 = dinv2[r2] * dinv2[c2];
    int s2 = atomicAdd(&pos2[c2], 1);
    csr2_src[s2] = r2; csr2_nrm[s2] = nv2;
  }
}

// ---------------- layer1 aggregate (CSR, no atomics, 4-wide ILP) ----------------

__global__ __launch_bounds__(256) void k_agg1(const int* __restrict__ off,
                                              const int* __restrict__ csr_src,
                                              const float* __restrict__ csr_nrm,
                                              const int* __restrict__ ids,
                                              const float* __restrict__ emb,
                                              float* __restrict__ aggX) {
  int wave = threadIdx.x >> 6, lane = threadIdx.x & 63;
  int node = blockIdx.x * 4 + wave;
  int start = off[node], end = off[node + 1];
  float2 acc = make_float2(0.f, 0.f);
  int i = start;
  for (; i + 3 < end; i += 4) {
    int s0 = csr_src[i], s1 = csr_src[i + 1], s2 = csr_src[i + 2], s3 = csr_src[i + 3];
    float n0 = csr_nrm[i], n1 = csr_nrm[i + 1], n2 = csr_nrm[i + 2], n3 = csr_nrm[i + 3];
    float2 v0 = *(const float2*)(emb + (size_t)ids[s0] * 128 + lane * 2);
    float2 v1 = *(const float2*)(emb + (size_t)ids[s1] * 128 + lane * 2);
    float2 v2 = *(const float2*)(emb + (size_t)ids[s2] * 128 + lane * 2);
    float2 v3 = *(const float2*)(emb + (size_t)ids[s3] * 128 + lane * 2);
    acc.x = fmaf(n0, v0.x, fmaf(n1, v1.x, fmaf(n2, v2.x, fmaf(n3, v3.x, acc.x))));
    acc.y = fmaf(n0, v0.y, fmaf(n1, v1.y, fmaf(n2, v2.y, fmaf(n3, v3.y, acc.y))));
  }
  for (; i < end; i++) {
    int s0 = csr_src[i];
    float n0 = csr_nrm[i];
    float2 v0 = *(const float2*)(emb + (size_t)ids[s0] * 128 + lane * 2);
    acc.x = fmaf(n0, v0.x, acc.x);
    acc.y = fmaf(n0, v0.y, acc.y);
  }
  *(float2*)(aggX + (size_t)node * 128 + lane * 2) = acc;
}

// ---------------- layer2 aggregate + bias + ELU + bf16 split ----------------

__global__ __launch_bounds__(256) void k_agg2(const int* __restrict__ off,
                                              const int* __restrict__ csr_src,
                                              const float* __restrict__ csr_nrm,
                                              const float* __restrict__ h2,
                                              const float* __restrict__ b,
                                              short* __restrict__ xh,
                                              short* __restrict__ xl) {
  int wave = threadIdx.x >> 6, lane = threadIdx.x & 63;
  int node = blockIdx.x * 4 + wave;
  int start = off[node], end = off[node + 1];
  float2 acc = make_float2(0.f, 0.f);
  int i = start;
  for (; i + 3 < end; i += 4) {
    int s0 = csr_src[i], s1 = csr_src[i + 1], s2 = csr_src[i + 2], s3 = csr_src[i + 3];
    float n0 = csr_nrm[i], n1 = csr_nrm[i + 1], n2 = csr_nrm[i + 2], n3 = csr_nrm[i + 3];
    float2 v0 = *(const float2*)(h2 + (size_t)s0 * 128 + lane * 2);
    float2 v1 = *(const float2*)(h2 + (size_t)s1 * 128 + lane * 2);
    float2 v2 = *(const float2*)(h2 + (size_t)s2 * 128 + lane * 2);
    float2 v3 = *(const float2*)(h2 + (size_t)s3 * 128 + lane * 2);
    acc.x = fmaf(n0, v0.x, fmaf(n1, v1.x, fmaf(n2, v2.x, fmaf(n3, v3.x, acc.x))));
    acc.y = fmaf(n0, v0.y, fmaf(n1, v1.y, fmaf(n2, v2.y, fmaf(n3, v3.y, acc.y))));
  }
  for (; i < end; i++) {
    int s0 = csr_src[i];
    float n0 = csr_nrm[i];
    float2 v0 = *(const float2*)(h2 + (size_t)s0 * 128 + lane * 2);
    acc.x = fmaf(n0, v0.x, acc.x);
    acc.y = fmaf(n0, v0.y, acc.y);
  }
  float vx = acc.x + b[lane * 2];
  float vy = acc.y + b[lane * 2 + 1];
  vx = vx > 0.f ? vx : expm1f(vx);
  vy = vy > 0.f ? vy : expm1f(vy);
  short hx, lx, hy, ly;
  split2(vx, hx, lx);
  split2(vy, hy, ly);
  unsigned hp = (unsigned)(unsigned short)hx | ((unsigned)(unsigned short)hy << 16);
  unsigned lp = (unsigned)(unsigned short)lx | ((unsigned)(unsigned short)ly << 16);
  *(unsigned*)(xh + (size_t)node * 128 + lane * 2) = hp;
  *(unsigned*)(xl + (size_t)node * 128 + lane * 2) = lp;
}

// ---------------- GEMM1: x1[N,256] = elu(aggX[N,128] @ W_in[128,256] + b) ------

__global__ __launch_bounds__(256) void k_gemm_aggin(const float* __restrict__ X,
                                                    const float* __restrict__ W,
                                                    const float* __restrict__ b,
                                                    float* __restrict__ C) {
  __shared__ float As[32][128];
  int r0 = blockIdx.x * 32;
  int t = threadIdx.x;
  for (int i = t; i < 1024; i += 256) {
    int r = i >> 5, q = (i & 31) << 2;
    int rr = r0 + r;
    float4 v = make_float4(0.f, 0.f, 0.f, 0.f);
    if (rr < NN) v = *(const float4*)(X + (size_t)rr * 128 + q);
    *(float4*)(&As[r][q]) = v;
  }
  __syncthreads();
  int tc = t & 31, tr = t >> 5;
  int c0 = tc * 8, rr0 = tr * 4;
  float acc[4][8];
#pragma unroll
  for (int r = 0; r < 4; r++)
#pragma unroll
    for (int c = 0; c < 8; c++) acc[r][c] = 0.f;

  for (int k0 = 0; k0 < 128; k0 += 4) {
    float a_[4][4];
#pragma unroll
    for (int r = 0; r < 4; r++) {
      float4 v = *(const float4*)(&As[rr0 + r][k0]);
      a_[r][0] = v.x; a_[r][1] = v.y; a_[r][2] = v.z; a_[r][3] = v.w;
    }
#pragma unroll
    for (int kk = 0; kk < 4; kk++) {
      float4 w0 = *(const float4*)(W + (size_t)(k0 + kk) * 256 + c0);
      float4 w1 = *(const float4*)(W + (size_t)(k0 + kk) * 256 + c0 + 4);
#pragma unroll
      for (int r = 0; r < 4; r++) {
        float av = a_[r][kk];
        acc[r][0] += av * w0.x; acc[r][1] += av * w0.y;
        acc[r][2] += av * w0.z; acc[r][3] += av * w0.w;
        acc[r][4] += av * w1.x; acc[r][5] += av * w1.y;
        acc[r][6] += av * w1.z; acc[r][7] += av * w1.w;
      }
    }
  }
  float4 bb0 = *(const float4*)(b + c0);
  float4 bb1 = *(const float4*)(b + c0 + 4);
#pragma unroll
  for (int r = 0; r < 4; r++) {
    int rr = r0 + rr0 + r;
    if (rr < NN) {
      float o[8];
      o[0] = acc[r][0] + bb0.x; o[1] = acc[r][1] + bb0.y;
      o[2] = acc[r][2] + bb0.z; o[3] = acc[r][3] + bb0.w;
      o[4] = acc[r][4] + bb1.x; o[5] = acc[r][5] + bb1.y;
      o[6] = acc[r][6] + bb1.z; o[7] = acc[r][7] + bb1.w;
#pragma unroll
      for (int c = 0; c < 8; c++) o[c] = o[c] > 0.f ? o[c] : expm1f(o[c]);
      *(float4*)(C + (size_t)rr * 256 + c0) = make_float4(o[0], o[1], o[2], o[3]);
      *(float4*)(C + (size_t)rr * 256 + c0 + 4) = make_float4(o[4], o[5], o[6], o[7]);
    }
  }
}

// ---------------- GEMM2: h2[N,128] = x1[N,256] @ W_out[256,128] ----------------

__global__ __launch_bounds__(256) void k_gemm_mid(const float* __restrict__ X,
                                                  const float* __restrict__ W,
                                                  float* __restrict__ C) {
  __shared__ float As[32][256];
  int r0 = blockIdx.x * 32;
  int t = threadIdx.x;
  for (int i = t; i < 2048; i += 256) {
    int r = i >> 6, q = (i & 63) << 2;
    int rr = r0 + r;
    float4 v = make_float4(0.f, 0.f, 0.f, 0.f);
    if (rr < NN) v = *(const float4*)(X + (size_t)rr * 256 + q);
    *(float4*)(&As[r][q]) = v;
  }
  __syncthreads();
  int tc = t & 31, tr = t >> 5;
  int c0 = tc * 4, rr0 = tr * 4;
  float acc[4][4];
#pragma unroll
  for (int r = 0; r < 4; r++)
#pragma unroll
    for (int c = 0; c < 4; c++) acc[r][c] = 0.f;

  for (int k0 = 0; k0 < 256; k0 += 4) {
    float a_[4][4];
#pragma unroll
    for (int r = 0; r < 4; r++) {
      float4 v = *(const float4*)(&As[rr0 + r][k0]);
      a_[r][0] = v.x; a_[r][1] = v.y; a_[r][2] = v.z; a_[r][3] = v.w;
    }
#pragma unroll
    for (int kk = 0; kk < 4; kk++) {
      float4 w = *(const float4*)(W + (size_t)(k0 + kk) * 128 + c0);
#pragma unroll
      for (int r = 0; r < 4; r++) {
        float av = a_[r][kk];
        acc[r][0] += av * w.x; acc[r][1] += av * w.y;
        acc[r][2] += av * w.z; acc[r][3] += av * w.w;
      }
    }
  }
#pragma unroll
  for (int r = 0; r < 4; r++) {
    int rr = r0 + rr0 + r;
    if (rr < NN) {
      float4 o = make_float4(acc[r][0], acc[r][1], acc[r][2], acc[r][3]);
      *(float4*)(C + (size_t)rr * 128 + c0) = o;
    }
  }
}

// ---------------- node-level decoder-layer1 factorization ----------------
// Pa[n] = x2[n] @ W1[:128,:], Pb[n] = x2[n] @ W1[128:,:] + b1  (b1 folded)

__global__ __launch_bounds__(256) void k_pab(const short* __restrict__ x2h,
                                             const short* __restrict__ x2l,
                                             const short* __restrict__ w1th,
                                             const short* __restrict__ w1tl,
                                             const float* __restrict__ b1,
                                             float* __restrict__ Pa,
                                             float* __restrict__ Pb) {
  __shared__ short Xh[32 * 136];
  __shared__ short Xl[32 * 136];
  int t = threadIdx.x;
  int n0 = blockIdx.x * 32;
#pragma unroll
  for (int j = 0; j < 2; j++) {
    int i = t + 256 * j;
    int row = i >> 4, q = i & 15;
    int node = n0 + row; if (node >= NN) node = NN - 1;
    *(uint4*)&Xh[row * 136 + q * 8] = *(const uint4*)(x2h + (size_t)node * 128 + q * 8);
    *(uint4*)&Xl[row * 136 + q * 8] = *(const uint4*)(x2l + (size_t)node * 128 + q * 8);
  }
  __syncthreads();

  int w = t >> 6, lane = t & 63;
  int quad = lane >> 4, l16 = lane & 15;
  int nb = w * 32;
  int aoff0 = l16 * 136 + quad * 8;
  int aoff1 = (16 + l16) * 136 + quad * 8;
  int bo0 = (nb + l16) * 256 + quad * 8;
  int bo1 = (nb + 16 + l16) * 256 + quad * 8;

  f4_t aa[2][2], ab[2][2];
#pragma unroll
  for (int mi = 0; mi < 2; mi++)
#pragma unroll
    for (int ni = 0; ni < 2; ni++) {
      aa[mi][ni] = (f4_t){0.f, 0.f, 0.f, 0.f};
      ab[mi][ni] = (f4_t){0.f, 0.f, 0.f, 0.f};
    }

#pragma unroll
  for (int kb = 0; kb < 4; kb++) {
    int k0 = kb * 32;
    s8_t ah0 = *(const s8_t*)&Xh[aoff0 + k0];
    s8_t ah1 = *(const s8_t*)&Xh[aoff1 + k0];
    s8_t al0 = *(const s8_t*)&Xl[aoff0 + k0];
    s8_t al1 = *(const s8_t*)&Xl[aoff1 + k0];
    {
      s8_t bh0 = *(const s8_t*)(w1th + bo0 + k0);
      s8_t bh1 = *(const s8_t*)(w1th + bo1 + k0);
      s8_t bl0 = *(const s8_t*)(w1tl + bo0 + k0);
      s8_t bl1 = *(const s8_t*)(w1tl + bo1 + k0);
      aa[0][0] = __builtin_amdgcn_mfma_f32_16x16x32_bf16(ah0, bh0, aa[0][0], 0, 0, 0);
      aa[0][0] = __builtin_amdgcn_mfma_f32_16x16x32_bf16(ah0, bl0, aa[0][0], 0, 0, 0);
      aa[0][0] = __builtin_amdgcn_mfma_f32_16x16x32_bf16(al0, bh0, aa[0][0], 0, 0, 0);
      aa[0][1] = __builtin_amdgcn_mfma_f32_16x16x32_bf16(ah0, bh1, aa[0][1], 0, 0, 0);
      aa[0][1] = __builtin_amdgcn_mfma_f32_16x16x32_bf16(ah0, bl1, aa[0][1], 0, 0, 0);
      aa[0][1] = __builtin_amdgcn_mfma_f32_16x16x32_bf16(al0, bh1, aa[0][1], 0, 0, 0);
      aa[1][0] = __builtin_amdgcn_mfma_f32_16x16x32_bf16(ah1, bh0, aa[1][0], 0, 0, 0);
      aa[1][0] = __builtin_amdgcn_mfma_f32_16x16x32_bf16(ah1, bl0, aa[1][0], 0, 0, 0);
      aa[1][0] = __builtin_amdgcn_mfma_f32_16x16x32_bf16(al1, bh0, aa[1][0], 0, 0, 0);
      aa[1][1] = __builtin_amdgcn_mfma_f32_16x16x32_bf16(ah1, bh1, aa[1][1], 0, 0, 0);
      aa[1][1] = __builtin_amdgcn_mfma_f32_16x16x32_bf16(ah1, bl1, aa[1][1], 0, 0, 0);
      aa[1][1] = __builtin_amdgcn_mfma_f32_16x16x32_bf16(al1, bh1, aa[1][1], 0, 0, 0);
    }
    {
      s8_t bh0 = *(const s8_t*)(w1th + bo0 + 128 + k0);
      s8_t bh1 = *(const s8_t*)(w1th + bo1 + 128 + k0);
      s8_t bl0 = *(const s8_t*)(w1tl + bo0 + 128 + k0);
      s8_t bl1 = *(const s8_t*)(w1tl + bo1 + 128 + k0);
      ab[0][0] = __builtin_amdgcn_mfma_f32_16x16x32_bf16(ah0, bh0, ab[0][0], 0, 0, 0);
      ab[0][0] = __builtin_amdgcn_mfma_f32_16x16x32_bf16(ah0, bl0, ab[0][0], 0, 0, 0);
      ab[0][0] = __builtin_amdgcn_mfma_f32_16x16x32_bf16(al0, bh0, ab[0][0], 0, 0, 0);
      ab[0][1] = __builtin_amdgcn_mfma_f32_16x16x32_bf16(ah0, bh1, ab[0][1], 0, 0, 0);
      ab[0][1] = __builtin_amdgcn_mfma_f32_16x16x32_bf16(ah0, bl1, ab[0][1], 0, 0, 0);
      ab[0][1] = __builtin_amdgcn_mfma_f32_16x16x32_bf16(al0, bh1, ab[0][1], 0, 0, 0);
      ab[1][0] = __builtin_amdgcn_mfma_f32_16x16x32_bf16(ah1, bh0, ab[1][0], 0, 0, 0);
      ab[1][0] = __builtin_amdgcn_mfma_f32_16x16x32_bf16(ah1, bl0, ab[1][0], 0, 0, 0);
      ab[1][0] = __builtin_amdgcn_mfma_f32_16x16x32_bf16(al1, bh0, ab[1][0], 0, 0, 0);
      ab[1][1] = __builtin_amdgcn_mfma_f32_16x16x32_bf16(ah1, bh1, ab[1][1], 0, 0, 0);
      ab[1][1] = __builtin_amdgcn_mfma_f32_16x16x32_bf16(ah1, bl1, ab[1][1], 0, 0, 0);
      ab[1][1] = __builtin_amdgcn_mfma_f32_16x16x32_bf16(al1, bh1, ab[1][1], 0, 0, 0);
    }
  }

  float b1v0 = b1[nb + l16], b1v1 = b1[nb + 16 + l16];
#pragma unroll
  for (int mi = 0; mi < 2; mi++)
#pragma unroll
    for (int ni = 0; ni < 2; ni++) {
      int col = nb + ni * 16 + l16;
      float bv = ni ? b1v1 : b1v0;
#pragma unroll
      for (int r = 0; r < 4; r++) {
        int node = n0 + mi * 16 + quad * 4 + r;
        if (node < NN) {
          Pa[(size_t)node * 128 + col] = aa[mi][ni][r];
          Pb[(size_t)node * 128 + col] = ab[mi][ni][r] + bv;
        }
      }
    }
}

// ---------------- fused edge decoder v7 (CSR-ordered) ----------------
// Blocks walk 32 consecutive CSR slots (dst-sorted): Pb[dst] reads hit L1
// (runs of ~16 same dst). Pa[src] random. Output scattered via eid.

#define ST 136   // t1 LDS stride (shorts)
#define S2 132   // layer-2 output fp32 stride (floats)

__global__ __launch_bounds__(256, 4) void k_decoder(
    const float* __restrict__ Pa, const float* __restrict__ Pb,
    const int* __restrict__ c1src, const int* __restrict__ c1dst,
    const int* __restrict__ c1eid,
    const short* __restrict__ w2th, const short* __restrict__ w2tl,
    const float* __restrict__ b2,
    const float* __restrict__ W3, const float* __restrict__ b3,
    float* __restrict__ out) {
  __shared__ short ThTl[2 * 32 * ST];
  short* Th = ThTl;
  short* Tl = ThTl + 32 * ST;
  float* T2 = (float*)ThTl;   // aliases (dead after layer-2 reads)

  int t = threadIdx.x;
  int s0base = blockIdx.x * 32;

  // ---- t1 stage: 512 items (slot, 8-dim chunk), 2 per thread ----
#pragma unroll
  for (int j = 0; j < 2; j++) {
    int i = t + 256 * j;
    int le = i >> 4, q = i & 15;
    int src = c1src[s0base + le], dst = c1dst[s0base + le];
    const float* pa = Pa + (size_t)src * 128 + q * 8;
    const float* pb = Pb + (size_t)dst * 128 + q * 8;
    float4 a0 = *(const float4*)(pa);
    float4 a1 = *(const float4*)(pa + 4);
    float4 c0 = *(const float4*)(pb);
    float4 c1 = *(const float4*)(pb + 4);
    float v[8];
    v[0] = a0.x + c0.x; v[1] = a0.y + c0.y;
    v[2] = a0.z + c0.z; v[3] = a0.w + c0.w;
    v[4] = a1.x + c1.x; v[5] = a1.y + c1.y;
    v[6] = a1.z + c1.z; v[7] = a1.w + c1.w;
    s8_t hv, lv;
#pragma unroll
    for (int k = 0; k < 8; k++) {
      float x = fmaxf(v[k], 0.f);
      short h, l; split2(x, h, l);
      hv[k] = h; lv[k] = l;
    }
    *(s8_t*)&Th[le * ST + q * 8] = hv;
    *(s8_t*)&Tl[le * ST + q * 8] = lv;
  }
  __syncthreads();   // (B1) Th/Tl ready

  int w = t >> 6, lane = t & 63;
  int quad = lane >> 4, l16 = lane & 15;
  int nb = w * 32;
  float b2v0 = b2[nb + l16], b2v1 = b2[nb + 16 + l16];
  float b3v = b3[0];

  int toff0 = l16 * ST + quad * 8;
  int toff1 = (16 + l16) * ST + quad * 8;
  int coff0 = (nb + l16) * 128 + quad * 8;
  int coff1 = (nb + 16 + l16) * 128 + quad * 8;

  // ---- layer 2: [32,128] @ W2[128,128] (hi*hi + hi*lo + lo*hi) ----
  f4_t acc2[2][2];
#pragma unroll
  for (int mi = 0; mi < 2; mi++)
#pragma unroll
    for (int ni = 0; ni < 2; ni++) acc2[mi][ni] = (f4_t){0.f, 0.f, 0.f, 0.f};

#pragma unroll
  for (int kb = 0; kb < 4; kb++) {
    int k0 = kb * 32;
    s8_t ah0 = *(const s8_t*)&Th[toff0 + k0];
    s8_t ah1 = *(const s8_t*)&Th[toff1 + k0];
    s8_t al0 = *(const s8_t*)&Tl[toff0 + k0];
    s8_t al1 = *(const s8_t*)&Tl[toff1 + k0];
    s8_t bh0 = *(const s8_t*)(w2th + coff0 + k0);
    s8_t bh1 = *(const s8_t*)(w2th + coff1 + k0);
    s8_t bl0 = *(const s8_t*)(w2tl + coff0 + k0);
    s8_t bl1 = *(const s8_t*)(w2tl + coff1 + k0);
    acc2[0][0] = __builtin_amdgcn_mfma_f32_16x16x32_bf16(ah0, bh0, acc2[0][0], 0, 0, 0);
    acc2[0][0] = __builtin_amdgcn_mfma_f32_16x16x32_bf16(ah0, bl0, acc2[0][0], 0, 0, 0);
    acc2[0][0] = __builtin_amdgcn_mfma_f32_16x16x32_bf16(al0, bh0, acc2[0][0], 0, 0, 0);
    acc2[0][1] = __builtin_amdgcn_mfma_f32_16x16x32_bf16(ah0, bh1, acc2[0][1], 0, 0, 0);
    acc2[0][1] = __builtin_amdgcn_mfma_f32_16x16x32_bf16(ah0, bl1, acc2[0][1], 0, 0, 0);
    acc2[0][1] = __builtin_amdgcn_mfma_f32_16x16x32_bf16(al0, bh1, acc2[0][1], 0, 0, 0);
    acc2[1][0] = __builtin_amdgcn_mfma_f32_16x16x32_bf16(ah1, bh0, acc2[1][0], 0, 0, 0);
    acc2[1][0] = __builtin_amdgcn_mfma_f32_16x16x32_bf16(ah1, bl0, acc2[1][0], 0, 0, 0);
    acc2[1][0] = __builtin_amdgcn_mfma_f32_16x16x32_bf16(al1, bh0, acc2[1][0], 0, 0, 0);
    acc2[1][1] = __builtin_amdgcn_mfma_f32_16x16x32_bf16(ah1, bh1, acc2[1][1], 0, 0, 0);
    acc2[1][1] = __builtin_amdgcn_mfma_f32_16x16x32_bf16(ah1, bl1, acc2[1][1], 0, 0, 0);
    acc2[1][1] = __builtin_amdgcn_mfma_f32_16x16x32_bf16(al1, bh1, acc2[1][1], 0, 0, 0);
  }
  __syncthreads();   // (B2) Th/Tl reads done -> T2 (alias) writable

  // bias + relu -> T2 (fp32)
#pragma unroll
  for (int mi = 0; mi < 2; mi++)
#pragma unroll
    for (int ni = 0; ni < 2; ni++) {
      float bv = ni ? b2v1 : b2v0;
      int col = nb + ni * 16 + l16;
#pragma unroll
      for (int r = 0; r < 4; r++) {
        int row = mi * 16 + quad * 4 + r;
        T2[row * S2 + col] = fmaxf(acc2[mi][ni][r] + bv, 0.f);
      }
    }
  __syncthreads();   // (B3) T2 ready

  // ---- layer 3: out[eid] = dot(t2[slot], W3) + b3 ----
  {
    int le = t >> 3, j0 = (t & 7) * 16;
    float s = 0.f;
#pragma unroll
    for (int j = 0; j < 16; j += 4) {
      float4 v = *(const float4*)(&T2[le * S2 + j0 + j]);
      float4 wv = *(const float4*)(W3 + j0 + j);
      s += v.x * wv.x + v.y * wv.y + v.z * wv.z + v.w * wv.w;
    }
    s += __shfl_down(s, 4);
    s += __shfl_down(s, 2);
    s += __shfl_down(s, 1);
    if ((t & 7) == 0) out[c1eid[s0base + le]] = s + b3v;
  }
}

// ---------------- launch ----------------

extern "C" void kernel_launch(void* const* d_in, const int* in_sizes, int n_in,
                              void* d_out, int out_size, void* d_ws, size_t ws_size,
                              hipStream_t stream) {
  const int*   node_ids = (const int*)d_in[0];
  const int*   ei       = (const int*)d_in[1];
  const int*   nei      = (const int*)d_in[2];
  const float* eattr    = (const float*)d_in[3];
  const float* emb      = (const float*)d_in[4];
  const float* W_in     = (const float*)d_in[5];
  const float* b_in     = (const float*)d_in[6];
  const float* W_out    = (const float*)d_in[7];
  const float* b_out    = (const float*)d_in[8];
  const float* W1       = (const float*)d_in[9];
  const float* b1       = (const float*)d_in[10];
  const float* W2       = (const float*)d_in[11];
  const float* b2       = (const float*)d_in[12];
  const float* W3       = (const float*)d_in[13];
  const float* b3       = (const float*)d_in[14];
  float* out = (float*)d_out;

  // workspace layout (floats)
  float* ws    = (float*)d_ws;
  float* bufA  = ws;                          // N*128: aggX -> h2 -> Pa
  float* bufB  = bufA + (size_t)NN * 128;     // N*256: x1 -> [x2h|x2l | Pb]
  int*   cnt1  = (int*)(bufB + (size_t)NN * 256);
  int*   cnt2  = cnt1 + NN;
  float* deg1  = (float*)(cnt2 + NN);
  float* dinv1 = deg1 + NN;
  float* dinv2 = dinv1 + NN;
  int*   off1  = (int*)(dinv2 + NN);          // N+1
  int*   pos1  = off1 + NN + 1;               // N
  int*   off2  = pos1 + NN;                   // N+1
  int*   pos2  = off2 + NN + 1;               // N
  int*   c1src = pos2 + NN;                   // E
  float* c1nrm = (float*)(c1src + NE);        // E
  int*   c1dst = (int*)(c1nrm + NE);          // E
  int*   c1eid = c1dst + NE;                  // E
  int*   c2src = c1eid + NE;                  // E
  float* c2nrm = (float*)(c2src + NE);        // E
  short* w1th  = (short*)(c2nrm + NE);
  short* w1tl  = w1th + 32768;
  short* w2th  = w1tl + 32768;
  short* w2tl  = w2th + 16384;
  int*   part  = (int*)(w2tl + 16384);        // 2*NCHUNK

  float* aggX  = bufA;
  float* h2    = bufA;                        // overwrites aggX (dead)
  float* Pa    = bufA;                        // overwrites h2 (dead after agg2)
  float* x1    = bufB;
  short* x2h   = (short*)bufB;                // overwrites x1 (dead)
  short* x2l   = x2h + (size_t)NN * 128;
  float* Pb    = bufB + (size_t)NN * 128;     // second half of bufB (free)

  // weight split
  k_wcvt<<<192, 256, 0, stream>>>(W1, W2, w1th, w1tl, w2th, w2tl);

  // CSR build: hist -> dinv -> scan(3-phase) -> fill
  hipMemsetAsync(cnt1, 0, 3 * (size_t)NN * sizeof(int), stream);  // cnt1,cnt2,deg1
  k_hist<<<NE / 256, 256, 0, stream>>>(ei, nei, eattr, cnt1, deg1, cnt2);
  k_dinvs<<<(NN + 255) / 256, 256, 0, stream>>>(deg1, cnt2, dinv1, dinv2);
  k_scan_part<<<2 * NCHUNK, 256, 0, stream>>>(cnt1, cnt2, part);
  k_scan_mid<<<1, 256, 0, stream>>>(part, off1 + NN, off2 + NN);
  k_scan_final<<<2 * NCHUNK, 256, 0, stream>>>(cnt1, cnt2, part,
                                               off1, pos1, off2, pos2);
  k_fill<<<NE / 256, 256, 0, stream>>>(ei, nei, eattr, dinv1, dinv2,
                                       pos1, c1src, c1nrm, c1dst, c1eid,
                                       pos2, c2src, c2nrm);

  // layer 1: aggregate (CSR) -> GEMM + bias + ELU
  k_agg1<<<NN / 4, 256, 0, stream>>>(off1, c1src, c1nrm, node_ids, emb, aggX);
  k_gemm_aggin<<<(NN + 31) / 32, 256, 0, stream>>>(aggX, W_in, b_in, x1);

  // layer 2: transform-first -> aggregate (+bias+ELU+split fused)
  k_gemm_mid<<<(NN + 31) / 32, 256, 0, stream>>>(x1, W_out, h2);
  k_agg2<<<NN / 4, 256, 0, stream>>>(off2, c2src, c2nrm, h2, b_out, x2h, x2l);

  // decoder layer-1 factorization: Pa/Pb per node (b1 folded into Pb)
  k_pab<<<(NN + 31) / 32, 256, 0, stream>>>(x2h, x2l, w1th, w1tl, b1, Pa, Pb);

  // decoder v7 (CSR-ordered edges)
  k_decoder<<<NE / 32, 256, 0, stream>>>(Pa, Pb, c1src, c1dst, c1eid,
                                         w2th, w2tl, b2, W3, b3, out);
}

// Round 9
// 806.588 us; speedup vs baseline: 2.5117x; 1.0279x over previous
//
#include <hip/hip_runtime.h>
#include <math.h>

#define NN 50000
#define NE 800000
// D = 128, H = 256

typedef __attribute__((ext_vector_type(8))) short s8_t;   // 8 bf16
typedef __attribute__((ext_vector_type(4))) float f4_t;   // 4 fp32

__device__ __forceinline__ short bf16_rne(float v) {
  unsigned u = __float_as_uint(v);
  unsigned r = (u + 0x7FFFu + ((u >> 16) & 1u)) >> 16;
  return (short)r;
}
__device__ __forceinline__ float bf16_tof(short h) {
  return __uint_as_float(((unsigned)(unsigned short)h) << 16);
}
__device__ __forceinline__ void split2(float v, short& hi, short& lo) {
  hi = bf16_rne(v);
  lo = bf16_rne(v - bf16_tof(hi));
}

// ---------------- weight split/transpose ----------------

__global__ __launch_bounds__(256) void k_wcvt(const float* __restrict__ W1,
                                              const float* __restrict__ W2,
                                              short* __restrict__ w1th,
                                              short* __restrict__ w1tl,
                                              short* __restrict__ w2th,
                                              short* __restrict__ w2tl) {
  int i = blockIdx.x * 256 + threadIdx.x;
  if (i < 32768) {
    int k = i >> 7, n = i & 127;
    short h, l; split2(W1[i], h, l);
    w1th[n * 256 + k] = h; w1tl[n * 256 + k] = l;
  } else if (i < 49152) {
    int j = i - 32768;
    int k = j >> 7, n = j & 127;
    short h, l; split2(W2[j], h, l);
    w2th[n * 128 + k] = h; w2tl[n * 128 + k] = l;
  }
}

// ---------------- CSR build: histogram ----------------

__global__ __launch_bounds__(256) void k_hist(const int* __restrict__ ei,
                                              const int* __restrict__ nei,
                                              const float* __restrict__ w,
                                              int* __restrict__ cnt1,
                                              float* __restrict__ deg1,
                                              int* __restrict__ cnt2) {
  int e = blockIdx.x * 256 + threadIdx.x;
  if (e < NE) {
    int c1 = ei[NE + e];
    atomicAdd(&cnt1[c1], 1);
    atomicAdd(&deg1[c1], w[e]);
    atomicAdd(&cnt2[nei[NE + e]], 1);
  }
}

__global__ __launch_bounds__(256) void k_dinvs(const float* __restrict__ deg1,
                                               const int* __restrict__ cnt2,
                                               float* __restrict__ dinv1,
                                               float* __restrict__ dinv2) {
  int i = blockIdx.x * 256 + threadIdx.x;
  if (i < NN) {
    float d1 = deg1[i];
    dinv1[i] = d1 > 0.f ? (1.0f / sqrtf(d1)) : 0.f;
    int c2 = cnt2[i];
    dinv2[i] = c2 > 0 ? (1.0f / sqrtf((float)c2)) : 0.f;
  }
}

// ---------------- hierarchical exclusive scan ----------------

#define NCHUNK 196   // ceil(50000/256)

__global__ __launch_bounds__(256) void k_scan_part(const int* __restrict__ cnt1,
                                                   const int* __restrict__ cnt2,
                                                   int* __restrict__ part) {
  int g = blockIdx.x >= NCHUNK;
  int chunk = g ? blockIdx.x - NCHUNK : blockIdx.x;
  const int* cnt = g ? cnt2 : cnt1;
  int i = chunk * 256 + threadIdx.x;
  int v = (i < NN) ? cnt[i] : 0;
  __shared__ int sd[4];
#pragma unroll
  for (int o = 32; o; o >>= 1) v += __shfl_down(v, o);
  if ((threadIdx.x & 63) == 0) sd[threadIdx.x >> 6] = v;
  __syncthreads();
  if (threadIdx.x == 0) part[blockIdx.x] = sd[0] + sd[1] + sd[2] + sd[3];
}

__global__ __launch_bounds__(256) void k_scan_mid(int* __restrict__ part,
                                                  int* __restrict__ off1_last,
                                                  int* __restrict__ off2_last) {
  __shared__ int sd[256];
  for (int g = 0; g < 2; g++) {
    int base = g * NCHUNK;
    int v = (threadIdx.x < NCHUNK) ? part[base + threadIdx.x] : 0;
    sd[threadIdx.x] = v;
    __syncthreads();
    for (int o = 1; o < 256; o <<= 1) {
      int x = (threadIdx.x >= o) ? sd[threadIdx.x - o] : 0;
      __syncthreads();
      sd[threadIdx.x] += x;
      __syncthreads();
    }
    if (threadIdx.x < NCHUNK) part[base + threadIdx.x] = sd[threadIdx.x] - v;
    if (threadIdx.x == 255) *(g ? off2_last : off1_last) = sd[255];
    __syncthreads();
  }
}

__global__ __launch_bounds__(256) void k_scan_final(const int* __restrict__ cnt1,
                                                    const int* __restrict__ cnt2,
                                                    const int* __restrict__ part,
                                                    int* __restrict__ off1,
                                                    int* __restrict__ pos1,
                                                    int* __restrict__ off2,
                                                    int* __restrict__ pos2) {
  int g = blockIdx.x >= NCHUNK;
  int chunk = g ? blockIdx.x - NCHUNK : blockIdx.x;
  const int* cnt = g ? cnt2 : cnt1;
  int* off = g ? off2 : off1;
  int* pos = g ? pos2 : pos1;
  __shared__ int sd[256];
  int i = chunk * 256 + threadIdx.x;
  int v = (i < NN) ? cnt[i] : 0;
  sd[threadIdx.x] = v;
  __syncthreads();
  for (int o = 1; o < 256; o <<= 1) {
    int x = (threadIdx.x >= o) ? sd[threadIdx.x - o] : 0;
    __syncthreads();
    sd[threadIdx.x] += x;
    __syncthreads();
  }
  if (i < NN) {
    int ex = part[blockIdx.x] + sd[threadIdx.x] - v;
    off[i] = ex; pos[i] = ex;
  }
}

// ---------------- fill CSR (packed records, one aligned store per slot) --------

__global__ __launch_bounds__(256) void k_fill(const int* __restrict__ ei,
                                              const int* __restrict__ nei,
                                              const float* __restrict__ w,
                                              const float* __restrict__ dinv1,
                                              const float* __restrict__ dinv2,
                                              int* __restrict__ pos1,
                                              int4* __restrict__ c1pack,
                                              int* __restrict__ pos2,
                                              int2* __restrict__ c2pack) {
  int e = blockIdx.x * 256 + threadIdx.x;
  if (e < NE) {
    int r = ei[e], c = ei[NE + e];
    float nv = dinv1[r] * w[e] * dinv1[c];
    int s = atomicAdd(&pos1[c], 1);
    c1pack[s] = make_int4(r, c, e, __float_as_int(nv));
    int r2 = nei[e], c2v = nei[NE + e];
    float nv2 = dinv2[r2] * dinv2[c2v];
    int s2 = atomicAdd(&pos2[c2v], 1);
    c2pack[s2] = make_int2(r2, __float_as_int(nv2));
  }
}

// ---------------- layer1 aggregate (CSR, no atomics, 8-wide ILP) ----------------

__global__ __launch_bounds__(256) void k_agg1(const int* __restrict__ off,
                                              const int4* __restrict__ c1pack,
                                              const int* __restrict__ ids,
                                              const float* __restrict__ emb,
                                              float* __restrict__ aggX) {
  int wave = threadIdx.x >> 6, lane = threadIdx.x & 63;
  int node = blockIdx.x * 4 + wave;
  int start = off[node], end = off[node + 1];
  float2 acc = make_float2(0.f, 0.f);
  int i = start;
  for (; i + 7 < end; i += 8) {
    float2 v[8]; float n[8];
#pragma unroll
    for (int k = 0; k < 8; k++) {
      int4 p = c1pack[i + k];
      n[k] = __int_as_float(p.w);
      v[k] = *(const float2*)(emb + (size_t)ids[p.x] * 128 + lane * 2);
    }
#pragma unroll
    for (int k = 0; k < 8; k++) {
      acc.x = fmaf(n[k], v[k].x, acc.x);
      acc.y = fmaf(n[k], v[k].y, acc.y);
    }
  }
  for (; i < end; i++) {
    int4 p = c1pack[i];
    float n0 = __int_as_float(p.w);
    float2 v0 = *(const float2*)(emb + (size_t)ids[p.x] * 128 + lane * 2);
    acc.x = fmaf(n0, v0.x, acc.x);
    acc.y = fmaf(n0, v0.y, acc.y);
  }
  *(float2*)(aggX + (size_t)node * 128 + lane * 2) = acc;
}

// ---------------- layer2 aggregate + bias + ELU + bf16 split ----------------

__global__ __launch_bounds__(256) void k_agg2(const int* __restrict__ off,
                                              const int2* __restrict__ c2pack,
                                              const float* __restrict__ h2,
                                              const float* __restrict__ b,
                                              short* __restrict__ xh,
                                              short* __restrict__ xl) {
  int wave = threadIdx.x >> 6, lane = threadIdx.x & 63;
  int node = blockIdx.x * 4 + wave;
  int start = off[node], end = off[node + 1];
  float2 acc = make_float2(0.f, 0.f);
  int i = start;
  for (; i + 7 < end; i += 8) {
    float2 v[8]; float n[8];
#pragma unroll
    for (int k = 0; k < 8; k++) {
      int2 p = c2pack[i + k];
      n[k] = __int_as_float(p.y);
      v[k] = *(const float2*)(h2 + (size_t)p.x * 128 + lane * 2);
    }
#pragma unroll
    for (int k = 0; k < 8; k++) {
      acc.x = fmaf(n[k], v[k].x, acc.x);
      acc.y = fmaf(n[k], v[k].y, acc.y);
    }
  }
  for (; i < end; i++) {
    int2 p = c2pack[i];
    float n0 = __int_as_float(p.y);
    float2 v0 = *(const float2*)(h2 + (size_t)p.x * 128 + lane * 2);
    acc.x = fmaf(n0, v0.x, acc.x);
    acc.y = fmaf(n0, v0.y, acc.y);
  }
  float vx = acc.x + b[lane * 2];
  float vy = acc.y + b[lane * 2 + 1];
  vx = vx > 0.f ? vx : expm1f(vx);
  vy = vy > 0.f ? vy : expm1f(vy);
  short hx, lx, hy, ly;
  split2(vx, hx, lx);
  split2(vy, hy, ly);
  unsigned hp = (unsigned)(unsigned short)hx | ((unsigned)(unsigned short)hy << 16);
  unsigned lp = (unsigned)(unsigned short)lx | ((unsigned)(unsigned short)ly << 16);
  *(unsigned*)(xh + (size_t)node * 128 + lane * 2) = hp;
  *(unsigned*)(xl + (size_t)node * 128 + lane * 2) = lp;
}

// ---------------- GEMM1: x1[N,256] = elu(aggX[N,128] @ W_in[128,256] + b) ------

__global__ __launch_bounds__(256) void k_gemm_aggin(const float* __restrict__ X,
                                                    const float* __restrict__ W,
                                                    const float* __restrict__ b,
                                                    float* __restrict__ C) {
  __shared__ float As[32][128];
  int r0 = blockIdx.x * 32;
  int t = threadIdx.x;
  for (int i = t; i < 1024; i += 256) {
    int r = i >> 5, q = (i & 31) << 2;
    int rr = r0 + r;
    float4 v = make_float4(0.f, 0.f, 0.f, 0.f);
    if (rr < NN) v = *(const float4*)(X + (size_t)rr * 128 + q);
    *(float4*)(&As[r][q]) = v;
  }
  __syncthreads();
  int tc = t & 31, tr = t >> 5;
  int c0 = tc * 8, rr0 = tr * 4;
  float acc[4][8];
#pragma unroll
  for (int r = 0; r < 4; r++)
#pragma unroll
    for (int c = 0; c < 8; c++) acc[r][c] = 0.f;

  for (int k0 = 0; k0 < 128; k0 += 4) {
    float a_[4][4];
#pragma unroll
    for (int r = 0; r < 4; r++) {
      float4 v = *(const float4*)(&As[rr0 + r][k0]);
      a_[r][0] = v.x; a_[r][1] = v.y; a_[r][2] = v.z; a_[r][3] = v.w;
    }
#pragma unroll
    for (int kk = 0; kk < 4; kk++) {
      float4 w0 = *(const float4*)(W + (size_t)(k0 + kk) * 256 + c0);
      float4 w1 = *(const float4*)(W + (size_t)(k0 + kk) * 256 + c0 + 4);
#pragma unroll
      for (int r = 0; r < 4; r++) {
        float av = a_[r][kk];
        acc[r][0] += av * w0.x; acc[r][1] += av * w0.y;
        acc[r][2] += av * w0.z; acc[r][3] += av * w0.w;
        acc[r][4] += av * w1.x; acc[r][5] += av * w1.y;
        acc[r][6] += av * w1.z; acc[r][7] += av * w1.w;
      }
    }
  }
  float4 bb0 = *(const float4*)(b + c0);
  float4 bb1 = *(const float4*)(b + c0 + 4);
#pragma unroll
  for (int r = 0; r < 4; r++) {
    int rr = r0 + rr0 + r;
    if (rr < NN) {
      float o[8];
      o[0] = acc[r][0] + bb0.x; o[1] = acc[r][1] + bb0.y;
      o[2] = acc[r][2] + bb0.z; o[3] = acc[r][3] + bb0.w;
      o[4] = acc[r][4] + bb1.x; o[5] = acc[r][5] + bb1.y;
      o[6] = acc[r][6] + bb1.z; o[7] = acc[r][7] + bb1.w;
#pragma unroll
      for (int c = 0; c < 8; c++) o[c] = o[c] > 0.f ? o[c] : expm1f(o[c]);
      *(float4*)(C + (size_t)rr * 256 + c0) = make_float4(o[0], o[1], o[2], o[3]);
      *(float4*)(C + (size_t)rr * 256 + c0 + 4) = make_float4(o[4], o[5], o[6], o[7]);
    }
  }
}

// ---------------- GEMM2: h2[N,128] = x1[N,256] @ W_out[256,128] ----------------

__global__ __launch_bounds__(256) void k_gemm_mid(const float* __restrict__ X,
                                                  const float* __restrict__ W,
                                                  float* __restrict__ C) {
  __shared__ float As[32][256];
  int r0 = blockIdx.x * 32;
  int t = threadIdx.x;
  for (int i = t; i < 2048; i += 256) {
    int r = i >> 6, q = (i & 63) << 2;
    int rr = r0 + r;
    float4 v = make_float4(0.f, 0.f, 0.f, 0.f);
    if (rr < NN) v = *(const float4*)(X + (size_t)rr * 256 + q);
    *(float4*)(&As[r][q]) = v;
  }
  __syncthreads();
  int tc = t & 31, tr = t >> 5;
  int c0 = tc * 4, rr0 = tr * 4;
  float acc[4][4];
#pragma unroll
  for (int r = 0; r < 4; r++)
#pragma unroll
    for (int c = 0; c < 4; c++) acc[r][c] = 0.f;

  for (int k0 = 0; k0 < 256; k0 += 4) {
    float a_[4][4];
#pragma unroll
    for (int r = 0; r < 4; r++) {
      float4 v = *(const float4*)(&As[rr0 + r][k0]);
      a_[r][0] = v.x; a_[r][1] = v.y; a_[r][2] = v.z; a_[r][3] = v.w;
    }
#pragma unroll
    for (int kk = 0; kk < 4; kk++) {
      float4 w = *(const float4*)(W + (size_t)(k0 + kk) * 128 + c0);
#pragma unroll
      for (int r = 0; r < 4; r++) {
        float av = a_[r][kk];
        acc[r][0] += av * w.x; acc[r][1] += av * w.y;
        acc[r][2] += av * w.z; acc[r][3] += av * w.w;
      }
    }
  }
#pragma unroll
  for (int r = 0; r < 4; r++) {
    int rr = r0 + rr0 + r;
    if (rr < NN) {
      float4 o = make_float4(acc[r][0], acc[r][1], acc[r][2], acc[r][3]);
      *(float4*)(C + (size_t)rr * 128 + c0) = o;
    }
  }
}

// ---------------- node-level decoder-layer1 factorization ----------------
// Pa[n] = x2[n] @ W1[:128,:], Pb[n] = x2[n] @ W1[128:,:] + b1  (b1 folded)

__global__ __launch_bounds__(256) void k_pab(const short* __restrict__ x2h,
                                             const short* __restrict__ x2l,
                                             const short* __restrict__ w1th,
                                             const short* __restrict__ w1tl,
                                             const float* __restrict__ b1,
                                             float* __restrict__ Pa,
                                             float* __restrict__ Pb) {
  __shared__ short Xh[32 * 136];
  __shared__ short Xl[32 * 136];
  int t = threadIdx.x;
  int n0 = blockIdx.x * 32;
#pragma unroll
  for (int j = 0; j < 2; j++) {
    int i = t + 256 * j;
    int row = i >> 4, q = i & 15;
    int node = n0 + row; if (node >= NN) node = NN - 1;
    *(uint4*)&Xh[row * 136 + q * 8] = *(const uint4*)(x2h + (size_t)node * 128 + q * 8);
    *(uint4*)&Xl[row * 136 + q * 8] = *(const uint4*)(x2l + (size_t)node * 128 + q * 8);
  }
  __syncthreads();

  int w = t >> 6, lane = t & 63;
  int quad = lane >> 4, l16 = lane & 15;
  int nb = w * 32;
  int aoff0 = l16 * 136 + quad * 8;
  int aoff1 = (16 + l16) * 136 + quad * 8;
  int bo0 = (nb + l16) * 256 + quad * 8;
  int bo1 = (nb + 16 + l16) * 256 + quad * 8;

  f4_t aa[2][2], ab[2][2];
#pragma unroll
  for (int mi = 0; mi < 2; mi++)
#pragma unroll
    for (int ni = 0; ni < 2; ni++) {
      aa[mi][ni] = (f4_t){0.f, 0.f, 0.f, 0.f};
      ab[mi][ni] = (f4_t){0.f, 0.f, 0.f, 0.f};
    }

#pragma unroll
  for (int kb = 0; kb < 4; kb++) {
    int k0 = kb * 32;
    s8_t ah0 = *(const s8_t*)&Xh[aoff0 + k0];
    s8_t ah1 = *(const s8_t*)&Xh[aoff1 + k0];
    s8_t al0 = *(const s8_t*)&Xl[aoff0 + k0];
    s8_t al1 = *(const s8_t*)&Xl[aoff1 + k0];
    {
      s8_t bh0 = *(const s8_t*)(w1th + bo0 + k0);
      s8_t bh1 = *(const s8_t*)(w1th + bo1 + k0);
      s8_t bl0 = *(const s8_t*)(w1tl + bo0 + k0);
      s8_t bl1 = *(const s8_t*)(w1tl + bo1 + k0);
      aa[0][0] = __builtin_amdgcn_mfma_f32_16x16x32_bf16(ah0, bh0, aa[0][0], 0, 0, 0);
      aa[0][0] = __builtin_amdgcn_mfma_f32_16x16x32_bf16(ah0, bl0, aa[0][0], 0, 0, 0);
      aa[0][0] = __builtin_amdgcn_mfma_f32_16x16x32_bf16(al0, bh0, aa[0][0], 0, 0, 0);
      aa[0][1] = __builtin_amdgcn_mfma_f32_16x16x32_bf16(ah0, bh1, aa[0][1], 0, 0, 0);
      aa[0][1] = __builtin_amdgcn_mfma_f32_16x16x32_bf16(ah0, bl1, aa[0][1], 0, 0, 0);
      aa[0][1] = __builtin_amdgcn_mfma_f32_16x16x32_bf16(al0, bh1, aa[0][1], 0, 0, 0);
      aa[1][0] = __builtin_amdgcn_mfma_f32_16x16x32_bf16(ah1, bh0, aa[1][0], 0, 0, 0);
      aa[1][0] = __builtin_amdgcn_mfma_f32_16x16x32_bf16(ah1, bl0, aa[1][0], 0, 0, 0);
      aa[1][0] = __builtin_amdgcn_mfma_f32_16x16x32_bf16(al1, bh0, aa[1][0], 0, 0, 0);
      aa[1][1] = __builtin_amdgcn_mfma_f32_16x16x32_bf16(ah1, bh1, aa[1][1], 0, 0, 0);
      aa[1][1] = __builtin_amdgcn_mfma_f32_16x16x32_bf16(ah1, bl1, aa[1][1], 0, 0, 0);
      aa[1][1] = __builtin_amdgcn_mfma_f32_16x16x32_bf16(al1, bh1, aa[1][1], 0, 0, 0);
    }
    {
      s8_t bh0 = *(const s8_t*)(w1th + bo0 + 128 + k0);
      s8_t bh1 = *(const s8_t*)(w1th + bo1 + 128 + k0);
      s8_t bl0 = *(const s8_t*)(w1tl + bo0 + 128 + k0);
      s8_t bl1 = *(const s8_t*)(w1tl + bo1 + 128 + k0);
      ab[0][0] = __builtin_amdgcn_mfma_f32_16x16x32_bf16(ah0, bh0, ab[0][0], 0, 0, 0);
      ab[0][0] = __builtin_amdgcn_mfma_f32_16x16x32_bf16(ah0, bl0, ab[0][0], 0, 0, 0);
      ab[0][0] = __builtin_amdgcn_mfma_f32_16x16x32_bf16(al0, bh0, ab[0][0], 0, 0, 0);
      ab[0][1] = __builtin_amdgcn_mfma_f32_16x16x32_bf16(ah0, bh1, ab[0][1], 0, 0, 0);
      ab[0][1] = __builtin_amdgcn_mfma_f32_16x16x32_bf16(ah0, bl1, ab[0][1], 0, 0, 0);
      ab[0][1] = __builtin_amdgcn_mfma_f32_16x16x32_bf16(al0, bh1, ab[0][1], 0, 0, 0);
      ab[1][0] = __builtin_amdgcn_mfma_f32_16x16x32_bf16(ah1, bh0, ab[1][0], 0, 0, 0);
      ab[1][0] = __builtin_amdgcn_mfma_f32_16x16x32_bf16(ah1, bl0, ab[1][0], 0, 0, 0);
      ab[1][0] = __builtin_amdgcn_mfma_f32_16x16x32_bf16(al1, bh0, ab[1][0], 0, 0, 0);
      ab[1][1] = __builtin_amdgcn_mfma_f32_16x16x32_bf16(ah1, bh1, ab[1][1], 0, 0, 0);
      ab[1][1] = __builtin_amdgcn_mfma_f32_16x16x32_bf16(ah1, bl1, ab[1][1], 0, 0, 0);
      ab[1][1] = __builtin_amdgcn_mfma_f32_16x16x32_bf16(al1, bh1, ab[1][1], 0, 0, 0);
    }
  }

  float b1v0 = b1[nb + l16], b1v1 = b1[nb + 16 + l16];
#pragma unroll
  for (int mi = 0; mi < 2; mi++)
#pragma unroll
    for (int ni = 0; ni < 2; ni++) {
      int col = nb + ni * 16 + l16;
      float bv = ni ? b1v1 : b1v0;
#pragma unroll
      for (int r = 0; r < 4; r++) {
        int node = n0 + mi * 16 + quad * 4 + r;
        if (node < NN) {
          Pa[(size_t)node * 128 + col] = aa[mi][ni][r];
          Pb[(size_t)node * 128 + col] = ab[mi][ni][r] + bv;
        }
      }
    }
}

// ---------------- fused edge decoder v8 ----------------
// CSR-ordered 32-edge tiles, XCD-swizzled (each XCD walks a contiguous CSR
// range -> its Pb slice fits the private 4 MB L2). Layer-3 computed as
// per-wave partial dots on the MFMA accumulators (relu+b2 in regs) ->
// no T2 LDS round-trip, barriers 4 -> 2. LDS 17.9 KB -> 8 blocks/CU.

#define ST 136   // t1 LDS stride (shorts)

__global__ __launch_bounds__(256, 4) void k_decoder(
    const float* __restrict__ Pa, const float* __restrict__ Pb,
    const int4* __restrict__ c1pack,
    const short* __restrict__ w2th, const short* __restrict__ w2tl,
    const float* __restrict__ b2,
    const float* __restrict__ W3, const float* __restrict__ b3,
    float* __restrict__ out) {
  __shared__ short Th[32 * ST];
  __shared__ short Tl[32 * ST];
  __shared__ float part[4][32];

  int t = threadIdx.x;
  int b = blockIdx.x;
  int id = (b & 7) * 3125 + (b >> 3);   // XCD-contiguous CSR ranges
  int s0base = id * 32;

  // ---- t1 stage: 512 items (slot, 8-dim chunk), 2 per thread ----
#pragma unroll
  for (int j = 0; j < 2; j++) {
    int i = t + 256 * j;
    int le = i >> 4, q = i & 15;
    int4 p = c1pack[s0base + le];
    const float* pa = Pa + (size_t)p.x * 128 + q * 8;
    const float* pb = Pb + (size_t)p.y * 128 + q * 8;
    float4 a0 = *(const float4*)(pa);
    float4 a1 = *(const float4*)(pa + 4);
    float4 c0 = *(const float4*)(pb);
    float4 c1 = *(const float4*)(pb + 4);
    float v[8];
    v[0] = a0.x + c0.x; v[1] = a0.y + c0.y;
    v[2] = a0.z + c0.z; v[3] = a0.w + c0.w;
    v[4] = a1.x + c1.x; v[5] = a1.y + c1.y;
    v[6] = a1.z + c1.z; v[7] = a1.w + c1.w;
    s8_t hv, lv;
#pragma unroll
    for (int k = 0; k < 8; k++) {
      float x = fmaxf(v[k], 0.f);
      short h, l; split2(x, h, l);
      hv[k] = h; lv[k] = l;
    }
    *(s8_t*)&Th[le * ST + q * 8] = hv;
    *(s8_t*)&Tl[le * ST + q * 8] = lv;
  }
  __syncthreads();   // (B1) Th/Tl ready

  int w = t >> 6, lane = t & 63;
  int quad = lane >> 4, l16 = lane & 15;
  int nb = w * 32;
  float b2v0 = b2[nb + l16], b2v1 = b2[nb + 16 + l16];
  float w3a = W3[nb + l16], w3b = W3[nb + 16 + l16];

  int toff0 = l16 * ST + quad * 8;
  int toff1 = (16 + l16) * ST + quad * 8;
  int coff0 = (nb + l16) * 128 + quad * 8;
  int coff1 = (nb + 16 + l16) * 128 + quad * 8;

  // ---- layer 2: [32,128] @ W2[128,128] (hi*hi + hi*lo + lo*hi) ----
  f4_t acc2[2][2];
#pragma unroll
  for (int mi = 0; mi < 2; mi++)
#pragma unroll
    for (int ni = 0; ni < 2; ni++) acc2[mi][ni] = (f4_t){0.f, 0.f, 0.f, 0.f};

#pragma unroll
  for (int kb = 0; kb < 4; kb++) {
    int k0 = kb * 32;
    s8_t ah0 = *(const s8_t*)&Th[toff0 + k0];
    s8_t ah1 = *(const s8_t*)&Th[toff1 + k0];
    s8_t al0 = *(const s8_t*)&Tl[toff0 + k0];
    s8_t al1 = *(const s8_t*)&Tl[toff1 + k0];
    s8_t bh0 = *(const s8_t*)(w2th + coff0 + k0);
    s8_t bh1 = *(const s8_t*)(w2th + coff1 + k0);
    s8_t bl0 = *(const s8_t*)(w2tl + coff0 + k0);
    s8_t bl1 = *(const s8_t*)(w2tl + coff1 + k0);
    acc2[0][0] = __builtin_amdgcn_mfma_f32_16x16x32_bf16(ah0, bh0, acc2[0][0], 0, 0, 0);
    acc2[0][0] = __builtin_amdgcn_mfma_f32_16x16x32_bf16(ah0, bl0, acc2[0][0], 0, 0, 0);
    acc2[0][0] = __builtin_amdgcn_mfma_f32_16x16x32_bf16(al0, bh0, acc2[0][0], 0, 0, 0);
    acc2[0][1] = __builtin_amdgcn_mfma_f32_16x16x32_bf16(ah0, bh1, acc2[0][1], 0, 0, 0);
    acc2[0][1] = __builtin_amdgcn_mfma_f32_16x16x32_bf16(ah0, bl1, acc2[0][1], 0, 0, 0);
    acc2[0][1] = __builtin_amdgcn_mfma_f32_16x16x32_bf16(al0, bh1, acc2[0][1], 0, 0, 0);
    acc2[1][0] = __builtin_amdgcn_mfma_f32_16x16x32_bf16(ah1, bh0, acc2[1][0], 0, 0, 0);
    acc2[1][0] = __builtin_amdgcn_mfma_f32_16x16x32_bf16(ah1, bl0, acc2[1][0], 0, 0, 0);
    acc2[1][0] = __builtin_amdgcn_mfma_f32_16x16x32_bf16(al1, bh0, acc2[1][0], 0, 0, 0);
    acc2[1][1] = __builtin_amdgcn_mfma_f32_16x16x32_bf16(ah1, bh1, acc2[1][1], 0, 0, 0);
    acc2[1][1] = __builtin_amdgcn_mfma_f32_16x16x32_bf16(ah1, bl1, acc2[1][1], 0, 0, 0);
    acc2[1][1] = __builtin_amdgcn_mfma_f32_16x16x32_bf16(al1, bh1, acc2[1][1], 0, 0, 0);
  }

  // ---- layer 3 partials: relu(acc2 + b2) . W3, reduced over 16-lane groups ----
#pragma unroll
  for (int mi = 0; mi < 2; mi++) {
#pragma unroll
    for (int r = 0; r < 4; r++) {
      float pv = fmaxf(acc2[mi][0][r] + b2v0, 0.f) * w3a +
                 fmaxf(acc2[mi][1][r] + b2v1, 0.f) * w3b;
      pv += __shfl_xor(pv, 1);
      pv += __shfl_xor(pv, 2);
      pv += __shfl_xor(pv, 4);
      pv += __shfl_xor(pv, 8);
      if (l16 == 0) part[w][mi * 16 + quad * 4 + r] = pv;
    }
  }
  __syncthreads();   // (B2) partials ready

  if (t < 32) {
    float s = part[0][t] + part[1][t] + part[2][t] + part[3][t] + b3[0];
    int4 p = c1pack[s0base + t];
    out[p.z] = s;
  }
}

// ---------------- launch ----------------

extern "C" void kernel_launch(void* const* d_in, const int* in_sizes, int n_in,
                              void* d_out, int out_size, void* d_ws, size_t ws_size,
                              hipStream_t stream) {
  const int*   node_ids = (const int*)d_in[0];
  const int*   ei       = (const int*)d_in[1];
  const int*   nei      = (const int*)d_in[2];
  const float* eattr    = (const float*)d_in[3];
  const float* emb      = (const float*)d_in[4];
  const float* W_in     = (const float*)d_in[5];
  const float* b_in     = (const float*)d_in[6];
  const float* W_out    = (const float*)d_in[7];
  const float* b_out    = (const float*)d_in[8];
  const float* W1       = (const float*)d_in[9];
  const float* b1       = (const float*)d_in[10];
  const float* W2       = (const float*)d_in[11];
  const float* b2       = (const float*)d_in[12];
  const float* W3       = (const float*)d_in[13];
  const float* b3       = (const float*)d_in[14];
  float* out = (float*)d_out;

  // workspace layout (floats)
  float* ws    = (float*)d_ws;
  float* bufA  = ws;                          // N*128: aggX -> h2 -> Pa
  float* bufB  = bufA + (size_t)NN * 128;     // N*256: x1 -> [x2h|x2l | Pb]
  int*   cnt1  = (int*)(bufB + (size_t)NN * 256);
  int*   cnt2  = cnt1 + NN;
  float* deg1  = (float*)(cnt2 + NN);
  float* dinv1 = deg1 + NN;
  float* dinv2 = dinv1 + NN;
  int*   off1  = (int*)(dinv2 + NN);          // N+1
  int*   pos1  = off1 + NN + 1;               // N
  int*   off2  = pos1 + NN;                   // N+1
  int*   pos2  = off2 + NN + 1;               // N
  // 16B-align the packed CSR arrays
  int4*  c1pack = (int4*)((((uintptr_t)(pos2 + NN)) + 15) & ~(uintptr_t)15);  // E
  int2*  c2pack = (int2*)(c1pack + NE);                                       // E
  short* w1th  = (short*)(c2pack + NE);
  short* w1tl  = w1th + 32768;
  short* w2th  = w1tl + 32768;
  short* w2tl  = w2th + 16384;
  int*   part  = (int*)(w2tl + 16384);        // 2*NCHUNK

  float* aggX  = bufA;
  float* h2    = bufA;                        // overwrites aggX (dead)
  float* Pa    = bufA;                        // overwrites h2 (dead after agg2)
  float* x1    = bufB;
  short* x2h   = (short*)bufB;                // overwrites x1 (dead)
  short* x2l   = x2h + (size_t)NN * 128;
  float* Pb    = bufB + (size_t)NN * 128;     // second half of bufB (free)

  // weight split
  k_wcvt<<<192, 256, 0, stream>>>(W1, W2, w1th, w1tl, w2th, w2tl);

  // CSR build: hist -> dinv -> scan(3-phase) -> fill
  hipMemsetAsync(cnt1, 0, 3 * (size_t)NN * sizeof(int), stream);  // cnt1,cnt2,deg1
  k_hist<<<NE / 256, 256, 0, stream>>>(ei, nei, eattr, cnt1, deg1, cnt2);
  k_dinvs<<<(NN + 255) / 256, 256, 0, stream>>>(deg1, cnt2, dinv1, dinv2);
  k_scan_part<<<2 * NCHUNK, 256, 0, stream>>>(cnt1, cnt2, part);
  k_scan_mid<<<1, 256, 0, stream>>>(part, off1 + NN, off2 + NN);
  k_scan_final<<<2 * NCHUNK, 256, 0, stream>>>(cnt1, cnt2, part,
                                               off1, pos1, off2, pos2);
  k_fill<<<NE / 256, 256, 0, stream>>>(ei, nei, eattr, dinv1, dinv2,
                                       pos1, c1pack, pos2, c2pack);

  // layer 1: aggregate (CSR) -> GEMM + bias + ELU
  k_agg1<<<NN / 4, 256, 0, stream>>>(off1, c1pack, node_ids, emb, aggX);
  k_gemm_aggin<<<(NN + 31) / 32, 256, 0, stream>>>(aggX, W_in, b_in, x1);

  // layer 2: transform-first -> aggregate (+bias+ELU+split fused)
  k_gemm_mid<<<(NN + 31) / 32, 256, 0, stream>>>(x1, W_out, h2);
  k_agg2<<<NN / 4, 256, 0, stream>>>(off2, c2pack, h2, b_out, x2h, x2l);

  // decoder layer-1 factorization: Pa/Pb per node (b1 folded into Pb)
  k_pab<<<(NN + 31) / 32, 256, 0, stream>>>(x2h, x2l, w1th, w1tl, b1, Pa, Pb);

  // decoder v8 (XCD-swizzled, no-T2)
  k_decoder<<<NE / 32, 256, 0, stream>>>(Pa, Pb, c1pack,
                                         w2th, w2tl, b2, W3, b3, out);
}

// Round 10
// 760.670 us; speedup vs baseline: 2.6633x; 1.0604x over previous
//
#include <hip/hip_runtime.h>
#include <math.h>

#define NN 50000
#define NE 800000
// D = 128, H = 256

typedef __attribute__((ext_vector_type(8))) short s8_t;   // 8 bf16
typedef __attribute__((ext_vector_type(4))) float f4_t;   // 4 fp32

__device__ __forceinline__ short bf16_rne(float v) {
  unsigned u = __float_as_uint(v);
  unsigned r = (u + 0x7FFFu + ((u >> 16) & 1u)) >> 16;
  return (short)r;
}
__device__ __forceinline__ float bf16_tof(short h) {
  return __uint_as_float(((unsigned)(unsigned short)h) << 16);
}
__device__ __forceinline__ void split2(float v, short& hi, short& lo) {
  hi = bf16_rne(v);
  lo = bf16_rne(v - bf16_tof(hi));
}

// ---------------- weight split/transpose (W1, W2, W_in, W_out) ----------------

__global__ __launch_bounds__(256) void k_wcvt(const float* __restrict__ W1,
                                              const float* __restrict__ W2,
                                              const float* __restrict__ W_in,
                                              const float* __restrict__ W_out,
                                              short* __restrict__ w1th,
                                              short* __restrict__ w1tl,
                                              short* __restrict__ w2th,
                                              short* __restrict__ w2tl,
                                              short* __restrict__ winth,
                                              short* __restrict__ wintl,
                                              short* __restrict__ woutth,
                                              short* __restrict__ wouttl) {
  int i = blockIdx.x * 256 + threadIdx.x;
  if (i < 32768) {                    // W1 [256,128] -> [128][256]
    int k = i >> 7, n = i & 127;
    short h, l; split2(W1[i], h, l);
    w1th[n * 256 + k] = h; w1tl[n * 256 + k] = l;
  } else if (i < 49152) {             // W2 [128,128] -> [128][128]
    int j = i - 32768;
    int k = j >> 7, n = j & 127;
    short h, l; split2(W2[j], h, l);
    w2th[n * 128 + k] = h; w2tl[n * 128 + k] = l;
  } else if (i < 81920) {             // W_in [128,256] -> [256][128]
    int j = i - 49152;
    int k = j >> 8, n = j & 255;
    short h, l; split2(W_in[j], h, l);
    winth[n * 128 + k] = h; wintl[n * 128 + k] = l;
  } else if (i < 114688) {            // W_out [256,128] -> [128][256]
    int j = i - 81920;
    int k = j >> 7, n = j & 127;
    short h, l; split2(W_out[j], h, l);
    woutth[n * 256 + k] = h; wouttl[n * 256 + k] = l;
  }
}

// ---------------- CSR build: histogram ----------------

__global__ __launch_bounds__(256) void k_hist(const int* __restrict__ ei,
                                              const int* __restrict__ nei,
                                              const float* __restrict__ w,
                                              int* __restrict__ cnt1,
                                              float* __restrict__ deg1,
                                              int* __restrict__ cnt2) {
  int e = blockIdx.x * 256 + threadIdx.x;
  if (e < NE) {
    int c1 = ei[NE + e];
    atomicAdd(&cnt1[c1], 1);
    atomicAdd(&deg1[c1], w[e]);
    atomicAdd(&cnt2[nei[NE + e]], 1);
  }
}

__global__ __launch_bounds__(256) void k_dinvs(const float* __restrict__ deg1,
                                               const int* __restrict__ cnt2,
                                               float* __restrict__ dinv1,
                                               float* __restrict__ dinv2) {
  int i = blockIdx.x * 256 + threadIdx.x;
  if (i < NN) {
    float d1 = deg1[i];
    dinv1[i] = d1 > 0.f ? (1.0f / sqrtf(d1)) : 0.f;
    int c2 = cnt2[i];
    dinv2[i] = c2 > 0 ? (1.0f / sqrtf((float)c2)) : 0.f;
  }
}

// ---------------- hierarchical exclusive scan ----------------

#define NCHUNK 196   // ceil(50000/256)

__global__ __launch_bounds__(256) void k_scan_part(const int* __restrict__ cnt1,
                                                   const int* __restrict__ cnt2,
                                                   int* __restrict__ part) {
  int g = blockIdx.x >= NCHUNK;
  int chunk = g ? blockIdx.x - NCHUNK : blockIdx.x;
  const int* cnt = g ? cnt2 : cnt1;
  int i = chunk * 256 + threadIdx.x;
  int v = (i < NN) ? cnt[i] : 0;
  __shared__ int sd[4];
#pragma unroll
  for (int o = 32; o; o >>= 1) v += __shfl_down(v, o);
  if ((threadIdx.x & 63) == 0) sd[threadIdx.x >> 6] = v;
  __syncthreads();
  if (threadIdx.x == 0) part[blockIdx.x] = sd[0] + sd[1] + sd[2] + sd[3];
}

__global__ __launch_bounds__(256) void k_scan_mid(int* __restrict__ part,
                                                  int* __restrict__ off1_last,
                                                  int* __restrict__ off2_last) {
  __shared__ int sd[256];
  for (int g = 0; g < 2; g++) {
    int base = g * NCHUNK;
    int v = (threadIdx.x < NCHUNK) ? part[base + threadIdx.x] : 0;
    sd[threadIdx.x] = v;
    __syncthreads();
    for (int o = 1; o < 256; o <<= 1) {
      int x = (threadIdx.x >= o) ? sd[threadIdx.x - o] : 0;
      __syncthreads();
      sd[threadIdx.x] += x;
      __syncthreads();
    }
    if (threadIdx.x < NCHUNK) part[base + threadIdx.x] = sd[threadIdx.x] - v;
    if (threadIdx.x == 255) *(g ? off2_last : off1_last) = sd[255];
    __syncthreads();
  }
}

__global__ __launch_bounds__(256) void k_scan_final(const int* __restrict__ cnt1,
                                                    const int* __restrict__ cnt2,
                                                    const int* __restrict__ part,
                                                    int* __restrict__ off1,
                                                    int* __restrict__ pos1,
                                                    int* __restrict__ off2,
                                                    int* __restrict__ pos2) {
  int g = blockIdx.x >= NCHUNK;
  int chunk = g ? blockIdx.x - NCHUNK : blockIdx.x;
  const int* cnt = g ? cnt2 : cnt1;
  int* off = g ? off2 : off1;
  int* pos = g ? pos2 : pos1;
  __shared__ int sd[256];
  int i = chunk * 256 + threadIdx.x;
  int v = (i < NN) ? cnt[i] : 0;
  sd[threadIdx.x] = v;
  __syncthreads();
  for (int o = 1; o < 256; o <<= 1) {
    int x = (threadIdx.x >= o) ? sd[threadIdx.x - o] : 0;
    __syncthreads();
    sd[threadIdx.x] += x;
    __syncthreads();
  }
  if (i < NN) {
    int ex = part[blockIdx.x] + sd[threadIdx.x] - v;
    off[i] = ex; pos[i] = ex;
  }
}

// ---------------- fill CSR (packed records) ----------------

__global__ __launch_bounds__(256) void k_fill(const int* __restrict__ ei,
                                              const int* __restrict__ nei,
                                              const float* __restrict__ w,
                                              const float* __restrict__ dinv1,
                                              const float* __restrict__ dinv2,
                                              int* __restrict__ pos1,
                                              int4* __restrict__ c1pack,
                                              int* __restrict__ pos2,
                                              int2* __restrict__ c2pack) {
  int e = blockIdx.x * 256 + threadIdx.x;
  if (e < NE) {
    int r = ei[e], c = ei[NE + e];
    float nv = dinv1[r] * w[e] * dinv1[c];
    int s = atomicAdd(&pos1[c], 1);
    c1pack[s] = make_int4(r, c, e, __float_as_int(nv));
    int r2 = nei[e], c2v = nei[NE + e];
    float nv2 = dinv2[r2] * dinv2[c2v];
    int s2 = atomicAdd(&pos2[c2v], 1);
    c2pack[s2] = make_int2(r2, __float_as_int(nv2));
  }
}

// ---------------- layer1 aggregate: float4 half-wave, bf16-split output -------
// Wave per node; 2 half-waves each cover one full 512B row per load (float4).

__global__ __launch_bounds__(256) void k_agg1(const int* __restrict__ off,
                                              const int4* __restrict__ c1pack,
                                              const int* __restrict__ ids,
                                              const float* __restrict__ emb,
                                              short* __restrict__ aggXh,
                                              short* __restrict__ aggXl) {
  int wave = threadIdx.x >> 6, lane = threadIdx.x & 63;
  int h = lane >> 5, sub = lane & 31;
  int node = blockIdx.x * 4 + wave;
  int start = off[node], end = off[node + 1];
  float4 acc = make_float4(0.f, 0.f, 0.f, 0.f);
  int i = start + h;
  for (; i + 14 < end; i += 16) {
    float4 v[8]; float n[8];
#pragma unroll
    for (int k = 0; k < 8; k++) {
      int4 p = c1pack[i + 2 * k];
      n[k] = __int_as_float(p.w);
      v[k] = *(const float4*)(emb + (size_t)ids[p.x] * 128 + sub * 4);
    }
#pragma unroll
    for (int k = 0; k < 8; k++) {
      acc.x = fmaf(n[k], v[k].x, acc.x);
      acc.y = fmaf(n[k], v[k].y, acc.y);
      acc.z = fmaf(n[k], v[k].z, acc.z);
      acc.w = fmaf(n[k], v[k].w, acc.w);
    }
  }
  for (; i < end; i += 2) {
    int4 p = c1pack[i];
    float n0 = __int_as_float(p.w);
    float4 v0 = *(const float4*)(emb + (size_t)ids[p.x] * 128 + sub * 4);
    acc.x = fmaf(n0, v0.x, acc.x);
    acc.y = fmaf(n0, v0.y, acc.y);
    acc.z = fmaf(n0, v0.z, acc.z);
    acc.w = fmaf(n0, v0.w, acc.w);
  }
  acc.x += __shfl_xor(acc.x, 32);
  acc.y += __shfl_xor(acc.y, 32);
  acc.z += __shfl_xor(acc.z, 32);
  acc.w += __shfl_xor(acc.w, 32);
  if (h == 0) {
    short h0, l0, h1, l1, h2, l2, h3, l3;
    split2(acc.x, h0, l0); split2(acc.y, h1, l1);
    split2(acc.z, h2, l2); split2(acc.w, h3, l3);
    uint2 hp, lp;
    hp.x = (unsigned)(unsigned short)h0 | ((unsigned)(unsigned short)h1 << 16);
    hp.y = (unsigned)(unsigned short)h2 | ((unsigned)(unsigned short)h3 << 16);
    lp.x = (unsigned)(unsigned short)l0 | ((unsigned)(unsigned short)l1 << 16);
    lp.y = (unsigned)(unsigned short)l2 | ((unsigned)(unsigned short)l3 << 16);
    *(uint2*)(aggXh + (size_t)node * 128 + sub * 4) = hp;
    *(uint2*)(aggXl + (size_t)node * 128 + sub * 4) = lp;
  }
}

// ---------------- layer2 aggregate + bias + ELU + bf16 split (float4) ---------

__global__ __launch_bounds__(256) void k_agg2(const int* __restrict__ off,
                                              const int2* __restrict__ c2pack,
                                              const float* __restrict__ h2,
                                              const float* __restrict__ b,
                                              short* __restrict__ xh,
                                              short* __restrict__ xl) {
  int wave = threadIdx.x >> 6, lane = threadIdx.x & 63;
  int h = lane >> 5, sub = lane & 31;
  int node = blockIdx.x * 4 + wave;
  int start = off[node], end = off[node + 1];
  float4 acc = make_float4(0.f, 0.f, 0.f, 0.f);
  int i = start + h;
  for (; i + 14 < end; i += 16) {
    float4 v[8]; float n[8];
#pragma unroll
    for (int k = 0; k < 8; k++) {
      int2 p = c2pack[i + 2 * k];
      n[k] = __int_as_float(p.y);
      v[k] = *(const float4*)(h2 + (size_t)p.x * 128 + sub * 4);
    }
#pragma unroll
    for (int k = 0; k < 8; k++) {
      acc.x = fmaf(n[k], v[k].x, acc.x);
      acc.y = fmaf(n[k], v[k].y, acc.y);
      acc.z = fmaf(n[k], v[k].z, acc.z);
      acc.w = fmaf(n[k], v[k].w, acc.w);
    }
  }
  for (; i < end; i += 2) {
    int2 p = c2pack[i];
    float n0 = __int_as_float(p.y);
    float4 v0 = *(const float4*)(h2 + (size_t)p.x * 128 + sub * 4);
    acc.x = fmaf(n0, v0.x, acc.x);
    acc.y = fmaf(n0, v0.y, acc.y);
    acc.z = fmaf(n0, v0.z, acc.z);
    acc.w = fmaf(n0, v0.w, acc.w);
  }
  acc.x += __shfl_xor(acc.x, 32);
  acc.y += __shfl_xor(acc.y, 32);
  acc.z += __shfl_xor(acc.z, 32);
  acc.w += __shfl_xor(acc.w, 32);
  if (h == 0) {
    float4 bb = *(const float4*)(b + sub * 4);
    float v0 = acc.x + bb.x, v1 = acc.y + bb.y;
    float v2 = acc.z + bb.z, v3 = acc.w + bb.w;
    v0 = v0 > 0.f ? v0 : expm1f(v0);
    v1 = v1 > 0.f ? v1 : expm1f(v1);
    v2 = v2 > 0.f ? v2 : expm1f(v2);
    v3 = v3 > 0.f ? v3 : expm1f(v3);
    short h0, l0, h1, l1, h2s, l2, h3, l3;
    split2(v0, h0, l0); split2(v1, h1, l1);
    split2(v2, h2s, l2); split2(v3, h3, l3);
    uint2 hp, lp;
    hp.x = (unsigned)(unsigned short)h0 | ((unsigned)(unsigned short)h1 << 16);
    hp.y = (unsigned)(unsigned short)h2s | ((unsigned)(unsigned short)h3 << 16);
    lp.x = (unsigned)(unsigned short)l0 | ((unsigned)(unsigned short)l1 << 16);
    lp.y = (unsigned)(unsigned short)l2 | ((unsigned)(unsigned short)l3 << 16);
    *(uint2*)(xh + (size_t)node * 128 + sub * 4) = hp;
    *(uint2*)(xl + (size_t)node * 128 + sub * 4) = lp;
  }
}

// ---------------- GEMM1 (MFMA): x1 = elu(aggX @ W_in + b) -> bf16 hi/lo -------
// 32-row tile; wave w owns cols [w*64, w*64+64) (4 n-tiles).

__global__ __launch_bounds__(256) void k_gemm1m(const short* __restrict__ aggXh,
                                                const short* __restrict__ aggXl,
                                                const short* __restrict__ winth,
                                                const short* __restrict__ wintl,
                                                const float* __restrict__ b,
                                                short* __restrict__ x1h,
                                                short* __restrict__ x1l) {
  __shared__ short Xh[32 * 136];
  __shared__ short Xl[32 * 136];
  int t = threadIdx.x;
  int n0 = blockIdx.x * 32;
#pragma unroll
  for (int j = 0; j < 2; j++) {
    int i = t + 256 * j;
    int row = i >> 4, q = i & 15;
    int node = n0 + row; if (node >= NN) node = NN - 1;
    *(uint4*)&Xh[row * 136 + q * 8] = *(const uint4*)(aggXh + (size_t)node * 128 + q * 8);
    *(uint4*)&Xl[row * 136 + q * 8] = *(const uint4*)(aggXl + (size_t)node * 128 + q * 8);
  }
  __syncthreads();

  int w = t >> 6, lane = t & 63;
  int quad = lane >> 4, l16 = lane & 15;
  int nb = w * 64;
  int aoff0 = l16 * 136 + quad * 8;
  int aoff1 = (16 + l16) * 136 + quad * 8;

  f4_t acc[2][4];
#pragma unroll
  for (int mi = 0; mi < 2; mi++)
#pragma unroll
    for (int ni = 0; ni < 4; ni++) acc[mi][ni] = (f4_t){0.f, 0.f, 0.f, 0.f};

#pragma unroll
  for (int kb = 0; kb < 4; kb++) {
    int k0 = kb * 32;
    s8_t ah0 = *(const s8_t*)&Xh[aoff0 + k0];
    s8_t ah1 = *(const s8_t*)&Xh[aoff1 + k0];
    s8_t al0 = *(const s8_t*)&Xl[aoff0 + k0];
    s8_t al1 = *(const s8_t*)&Xl[aoff1 + k0];
#pragma unroll
    for (int ni = 0; ni < 4; ni++) {
      int bo = (nb + ni * 16 + l16) * 128 + quad * 8 + k0;
      s8_t bh = *(const s8_t*)(winth + bo);
      s8_t bl = *(const s8_t*)(wintl + bo);
      acc[0][ni] = __builtin_amdgcn_mfma_f32_16x16x32_bf16(ah0, bh, acc[0][ni], 0, 0, 0);
      acc[0][ni] = __builtin_amdgcn_mfma_f32_16x16x32_bf16(ah0, bl, acc[0][ni], 0, 0, 0);
      acc[0][ni] = __builtin_amdgcn_mfma_f32_16x16x32_bf16(al0, bh, acc[0][ni], 0, 0, 0);
      acc[1][ni] = __builtin_amdgcn_mfma_f32_16x16x32_bf16(ah1, bh, acc[1][ni], 0, 0, 0);
      acc[1][ni] = __builtin_amdgcn_mfma_f32_16x16x32_bf16(ah1, bl, acc[1][ni], 0, 0, 0);
      acc[1][ni] = __builtin_amdgcn_mfma_f32_16x16x32_bf16(al1, bh, acc[1][ni], 0, 0, 0);
    }
  }

#pragma unroll
  for (int mi = 0; mi < 2; mi++)
#pragma unroll
    for (int ni = 0; ni < 4; ni++) {
      int col = nb + ni * 16 + l16;
      float bv = b[col];
#pragma unroll
      for (int r = 0; r < 4; r++) {
        int node = n0 + mi * 16 + quad * 4 + r;
        if (node < NN) {
          float v = acc[mi][ni][r] + bv;
          v = v > 0.f ? v : expm1f(v);
          short hh, ll; split2(v, hh, ll);
          x1h[(size_t)node * 256 + col] = hh;
          x1l[(size_t)node * 256 + col] = ll;
        }
      }
    }
}

// ---------------- GEMM2 (MFMA): h2 = x1 @ W_out (fp32 out) ----------------

__global__ __launch_bounds__(256) void k_gemm2m(const short* __restrict__ x1h,
                                                const short* __restrict__ x1l,
                                                const short* __restrict__ woutth,
                                                const short* __restrict__ wouttl,
                                                float* __restrict__ h2) {
  __shared__ short Xh[32 * 264];
  __shared__ short Xl[32 * 264];
  int t = threadIdx.x;
  int n0 = blockIdx.x * 32;
#pragma unroll
  for (int j = 0; j < 4; j++) {
    int i = t + 256 * j;
    int row = i >> 5, q = i & 31;
    int node = n0 + row; if (node >= NN) node = NN - 1;
    *(uint4*)&Xh[row * 264 + q * 8] = *(const uint4*)(x1h + (size_t)node * 256 + q * 8);
    *(uint4*)&Xl[row * 264 + q * 8] = *(const uint4*)(x1l + (size_t)node * 256 + q * 8);
  }
  __syncthreads();

  int w = t >> 6, lane = t & 63;
  int quad = lane >> 4, l16 = lane & 15;
  int nb = w * 32;
  int aoff0 = l16 * 264 + quad * 8;
  int aoff1 = (16 + l16) * 264 + quad * 8;

  f4_t acc[2][2];
#pragma unroll
  for (int mi = 0; mi < 2; mi++)
#pragma unroll
    for (int ni = 0; ni < 2; ni++) acc[mi][ni] = (f4_t){0.f, 0.f, 0.f, 0.f};

#pragma unroll
  for (int kb = 0; kb < 8; kb++) {
    int k0 = kb * 32;
    s8_t ah0 = *(const s8_t*)&Xh[aoff0 + k0];
    s8_t ah1 = *(const s8_t*)&Xh[aoff1 + k0];
    s8_t al0 = *(const s8_t*)&Xl[aoff0 + k0];
    s8_t al1 = *(const s8_t*)&Xl[aoff1 + k0];
#pragma unroll
    for (int ni = 0; ni < 2; ni++) {
      int bo = (nb + ni * 16 + l16) * 256 + quad * 8 + k0;
      s8_t bh = *(const s8_t*)(woutth + bo);
      s8_t bl = *(const s8_t*)(wouttl + bo);
      acc[0][ni] = __builtin_amdgcn_mfma_f32_16x16x32_bf16(ah0, bh, acc[0][ni], 0, 0, 0);
      acc[0][ni] = __builtin_amdgcn_mfma_f32_16x16x32_bf16(ah0, bl, acc[0][ni], 0, 0, 0);
      acc[0][ni] = __builtin_amdgcn_mfma_f32_16x16x32_bf16(al0, bh, acc[0][ni], 0, 0, 0);
      acc[1][ni] = __builtin_amdgcn_mfma_f32_16x16x32_bf16(ah1, bh, acc[1][ni], 0, 0, 0);
      acc[1][ni] = __builtin_amdgcn_mfma_f32_16x16x32_bf16(ah1, bl, acc[1][ni], 0, 0, 0);
      acc[1][ni] = __builtin_amdgcn_mfma_f32_16x16x32_bf16(al1, bh, acc[1][ni], 0, 0, 0);
    }
  }

#pragma unroll
  for (int mi = 0; mi < 2; mi++)
#pragma unroll
    for (int ni = 0; ni < 2; ni++) {
      int col = nb + ni * 16 + l16;
#pragma unroll
      for (int r = 0; r < 4; r++) {
        int node = n0 + mi * 16 + quad * 4 + r;
        if (node < NN) h2[(size_t)node * 128 + col] = acc[mi][ni][r];
      }
    }
}

// ---------------- node-level decoder-layer1 factorization ----------------

__global__ __launch_bounds__(256) void k_pab(const short* __restrict__ x2h,
                                             const short* __restrict__ x2l,
                                             const short* __restrict__ w1th,
                                             const short* __restrict__ w1tl,
                                             const float* __restrict__ b1,
                                             float* __restrict__ Pa,
                                             float* __restrict__ Pb) {
  __shared__ short Xh[32 * 136];
  __shared__ short Xl[32 * 136];
  int t = threadIdx.x;
  int n0 = blockIdx.x * 32;
#pragma unroll
  for (int j = 0; j < 2; j++) {
    int i = t + 256 * j;
    int row = i >> 4, q = i & 15;
    int node = n0 + row; if (node >= NN) node = NN - 1;
    *(uint4*)&Xh[row * 136 + q * 8] = *(const uint4*)(x2h + (size_t)node * 128 + q * 8);
    *(uint4*)&Xl[row * 136 + q * 8] = *(const uint4*)(x2l + (size_t)node * 128 + q * 8);
  }
  __syncthreads();

  int w = t >> 6, lane = t & 63;
  int quad = lane >> 4, l16 = lane & 15;
  int nb = w * 32;
  int aoff0 = l16 * 136 + quad * 8;
  int aoff1 = (16 + l16) * 136 + quad * 8;
  int bo0 = (nb + l16) * 256 + quad * 8;
  int bo1 = (nb + 16 + l16) * 256 + quad * 8;

  f4_t aa[2][2], ab[2][2];
#pragma unroll
  for (int mi = 0; mi < 2; mi++)
#pragma unroll
    for (int ni = 0; ni < 2; ni++) {
      aa[mi][ni] = (f4_t){0.f, 0.f, 0.f, 0.f};
      ab[mi][ni] = (f4_t){0.f, 0.f, 0.f, 0.f};
    }

#pragma unroll
  for (int kb = 0; kb < 4; kb++) {
    int k0 = kb * 32;
    s8_t ah0 = *(const s8_t*)&Xh[aoff0 + k0];
    s8_t ah1 = *(const s8_t*)&Xh[aoff1 + k0];
    s8_t al0 = *(const s8_t*)&Xl[aoff0 + k0];
    s8_t al1 = *(const s8_t*)&Xl[aoff1 + k0];
    {
      s8_t bh0 = *(const s8_t*)(w1th + bo0 + k0);
      s8_t bh1 = *(const s8_t*)(w1th + bo1 + k0);
      s8_t bl0 = *(const s8_t*)(w1tl + bo0 + k0);
      s8_t bl1 = *(const s8_t*)(w1tl + bo1 + k0);
      aa[0][0] = __builtin_amdgcn_mfma_f32_16x16x32_bf16(ah0, bh0, aa[0][0], 0, 0, 0);
      aa[0][0] = __builtin_amdgcn_mfma_f32_16x16x32_bf16(ah0, bl0, aa[0][0], 0, 0, 0);
      aa[0][0] = __builtin_amdgcn_mfma_f32_16x16x32_bf16(al0, bh0, aa[0][0], 0, 0, 0);
      aa[0][1] = __builtin_amdgcn_mfma_f32_16x16x32_bf16(ah0, bh1, aa[0][1], 0, 0, 0);
      aa[0][1] = __builtin_amdgcn_mfma_f32_16x16x32_bf16(ah0, bl1, aa[0][1], 0, 0, 0);
      aa[0][1] = __builtin_amdgcn_mfma_f32_16x16x32_bf16(al0, bh1, aa[0][1], 0, 0, 0);
      aa[1][0] = __builtin_amdgcn_mfma_f32_16x16x32_bf16(ah1, bh0, aa[1][0], 0, 0, 0);
      aa[1][0] = __builtin_amdgcn_mfma_f32_16x16x32_bf16(ah1, bl0, aa[1][0], 0, 0, 0);
      aa[1][0] = __builtin_amdgcn_mfma_f32_16x16x32_bf16(al1, bh0, aa[1][0], 0, 0, 0);
      aa[1][1] = __builtin_amdgcn_mfma_f32_16x16x32_bf16(ah1, bh1, aa[1][1], 0, 0, 0);
      aa[1][1] = __builtin_amdgcn_mfma_f32_16x16x32_bf16(ah1, bl1, aa[1][1], 0, 0, 0);
      aa[1][1] = __builtin_amdgcn_mfma_f32_16x16x32_bf16(al1, bh1, aa[1][1], 0, 0, 0);
    }
    {
      s8_t bh0 = *(const s8_t*)(w1th + bo0 + 128 + k0);
      s8_t bh1 = *(const s8_t*)(w1th + bo1 + 128 + k0);
      s8_t bl0 = *(const s8_t*)(w1tl + bo0 + 128 + k0);
      s8_t bl1 = *(const s8_t*)(w1tl + bo1 + 128 + k0);
      ab[0][0] = __builtin_amdgcn_mfma_f32_16x16x32_bf16(ah0, bh0, ab[0][0], 0, 0, 0);
      ab[0][0] = __builtin_amdgcn_mfma_f32_16x16x32_bf16(ah0, bl0, ab[0][0], 0, 0, 0);
      ab[0][0] = __builtin_amdgcn_mfma_f32_16x16x32_bf16(al0, bh0, ab[0][0], 0, 0, 0);
      ab[0][1] = __builtin_amdgcn_mfma_f32_16x16x32_bf16(ah0, bh1, ab[0][1], 0, 0, 0);
      ab[0][1] = __builtin_amdgcn_mfma_f32_16x16x32_bf16(ah0, bl1, ab[0][1], 0, 0, 0);
      ab[0][1] = __builtin_amdgcn_mfma_f32_16x16x32_bf16(al0, bh1, ab[0][1], 0, 0, 0);
      ab[1][0] = __builtin_amdgcn_mfma_f32_16x16x32_bf16(ah1, bh0, ab[1][0], 0, 0, 0);
      ab[1][0] = __builtin_amdgcn_mfma_f32_16x16x32_bf16(ah1, bl0, ab[1][0], 0, 0, 0);
      ab[1][0] = __builtin_amdgcn_mfma_f32_16x16x32_bf16(al1, bh0, ab[1][0], 0, 0, 0);
      ab[1][1] = __builtin_amdgcn_mfma_f32_16x16x32_bf16(ah1, bh1, ab[1][1], 0, 0, 0);
      ab[1][1] = __builtin_amdgcn_mfma_f32_16x16x32_bf16(ah1, bl1, ab[1][1], 0, 0, 0);
      ab[1][1] = __builtin_amdgcn_mfma_f32_16x16x32_bf16(al1, bh1, ab[1][1], 0, 0, 0);
    }
  }

  float b1v0 = b1[nb + l16], b1v1 = b1[nb + 16 + l16];
#pragma unroll
  for (int mi = 0; mi < 2; mi++)
#pragma unroll
    for (int ni = 0; ni < 2; ni++) {
      int col = nb + ni * 16 + l16;
      float bv = ni ? b1v1 : b1v0;
#pragma unroll
      for (int r = 0; r < 4; r++) {
        int node = n0 + mi * 16 + quad * 4 + r;
        if (node < NN) {
          Pa[(size_t)node * 128 + col] = aa[mi][ni][r];
          Pb[(size_t)node * 128 + col] = ab[mi][ni][r] + bv;
        }
      }
    }
}

// ---------------- fused edge decoder v8 (unchanged from round 9) --------------

#define ST 136   // t1 LDS stride (shorts)

__global__ __launch_bounds__(256, 4) void k_decoder(
    const float* __restrict__ Pa, const float* __restrict__ Pb,
    const int4* __restrict__ c1pack,
    const short* __restrict__ w2th, const short* __restrict__ w2tl,
    const float* __restrict__ b2,
    const float* __restrict__ W3, const float* __restrict__ b3,
    float* __restrict__ out) {
  __shared__ short Th[32 * ST];
  __shared__ short Tl[32 * ST];
  __shared__ float part[4][32];

  int t = threadIdx.x;
  int b = blockIdx.x;
  int id = (b & 7) * 3125 + (b >> 3);   // XCD-contiguous CSR ranges
  int s0base = id * 32;

#pragma unroll
  for (int j = 0; j < 2; j++) {
    int i = t + 256 * j;
    int le = i >> 4, q = i & 15;
    int4 p = c1pack[s0base + le];
    const float* pa = Pa + (size_t)p.x * 128 + q * 8;
    const float* pb = Pb + (size_t)p.y * 128 + q * 8;
    float4 a0 = *(const float4*)(pa);
    float4 a1 = *(const float4*)(pa + 4);
    float4 c0 = *(const float4*)(pb);
    float4 c1 = *(const float4*)(pb + 4);
    float v[8];
    v[0] = a0.x + c0.x; v[1] = a0.y + c0.y;
    v[2] = a0.z + c0.z; v[3] = a0.w + c0.w;
    v[4] = a1.x + c1.x; v[5] = a1.y + c1.y;
    v[6] = a1.z + c1.z; v[7] = a1.w + c1.w;
    s8_t hv, lv;
#pragma unroll
    for (int k = 0; k < 8; k++) {
      float x = fmaxf(v[k], 0.f);
      short h, l; split2(x, h, l);
      hv[k] = h; lv[k] = l;
    }
    *(s8_t*)&Th[le * ST + q * 8] = hv;
    *(s8_t*)&Tl[le * ST + q * 8] = lv;
  }
  __syncthreads();

  int w = t >> 6, lane = t & 63;
  int quad = lane >> 4, l16 = lane & 15;
  int nb = w * 32;
  float b2v0 = b2[nb + l16], b2v1 = b2[nb + 16 + l16];
  float w3a = W3[nb + l16], w3b = W3[nb + 16 + l16];

  int toff0 = l16 * ST + quad * 8;
  int toff1 = (16 + l16) * ST + quad * 8;
  int coff0 = (nb + l16) * 128 + quad * 8;
  int coff1 = (nb + 16 + l16) * 128 + quad * 8;

  f4_t acc2[2][2];
#pragma unroll
  for (int mi = 0; mi < 2; mi++)
#pragma unroll
    for (int ni = 0; ni < 2; ni++) acc2[mi][ni] = (f4_t){0.f, 0.f, 0.f, 0.f};

#pragma unroll
  for (int kb = 0; kb < 4; kb++) {
    int k0 = kb * 32;
    s8_t ah0 = *(const s8_t*)&Th[toff0 + k0];
    s8_t ah1 = *(const s8_t*)&Th[toff1 + k0];
    s8_t al0 = *(const s8_t*)&Tl[toff0 + k0];
    s8_t al1 = *(const s8_t*)&Tl[toff1 + k0];
    s8_t bh0 = *(const s8_t*)(w2th + coff0 + k0);
    s8_t bh1 = *(const s8_t*)(w2th + coff1 + k0);
    s8_t bl0 = *(const s8_t*)(w2tl + coff0 + k0);
    s8_t bl1 = *(const s8_t*)(w2tl + coff1 + k0);
    acc2[0][0] = __builtin_amdgcn_mfma_f32_16x16x32_bf16(ah0, bh0, acc2[0][0], 0, 0, 0);
    acc2[0][0] = __builtin_amdgcn_mfma_f32_16x16x32_bf16(ah0, bl0, acc2[0][0], 0, 0, 0);
    acc2[0][0] = __builtin_amdgcn_mfma_f32_16x16x32_bf16(al0, bh0, acc2[0][0], 0, 0, 0);
    acc2[0][1] = __builtin_amdgcn_mfma_f32_16x16x32_bf16(ah0, bh1, acc2[0][1], 0, 0, 0);
    acc2[0][1] = __builtin_amdgcn_mfma_f32_16x16x32_bf16(ah0, bl1, acc2[0][1], 0, 0, 0);
    acc2[0][1] = __builtin_amdgcn_mfma_f32_16x16x32_bf16(al0, bh1, acc2[0][1], 0, 0, 0);
    acc2[1][0] = __builtin_amdgcn_mfma_f32_16x16x32_bf16(ah1, bh0, acc2[1][0], 0, 0, 0);
    acc2[1][0] = __builtin_amdgcn_mfma_f32_16x16x32_bf16(ah1, bl0, acc2[1][0], 0, 0, 0);
    acc2[1][0] = __builtin_amdgcn_mfma_f32_16x16x32_bf16(al1, bh0, acc2[1][0], 0, 0, 0);
    acc2[1][1] = __builtin_amdgcn_mfma_f32_16x16x32_bf16(ah1, bh1, acc2[1][1], 0, 0, 0);
    acc2[1][1] = __builtin_amdgcn_mfma_f32_16x16x32_bf16(ah1, bl1, acc2[1][1], 0, 0, 0);
    acc2[1][1] = __builtin_amdgcn_mfma_f32_16x16x32_bf16(al1, bh1, acc2[1][1], 0, 0, 0);
  }

#pragma unroll
  for (int mi = 0; mi < 2; mi++) {
#pragma unroll
    for (int r = 0; r < 4; r++) {
      float pv = fmaxf(acc2[mi][0][r] + b2v0, 0.f) * w3a +
                 fmaxf(acc2[mi][1][r] + b2v1, 0.f) * w3b;
      pv += __shfl_xor(pv, 1);
      pv += __shfl_xor(pv, 2);
      pv += __shfl_xor(pv, 4);
      pv += __shfl_xor(pv, 8);
      if (l16 == 0) part[w][mi * 16 + quad * 4 + r] = pv;
    }
  }
  __syncthreads();

  if (t < 32) {
    float s = part[0][t] + part[1][t] + part[2][t] + part[3][t] + b3[0];
    int4 p = c1pack[s0base + t];
    out[p.z] = s;
  }
}

// ---------------- launch ----------------

extern "C" void kernel_launch(void* const* d_in, const int* in_sizes, int n_in,
                              void* d_out, int out_size, void* d_ws, size_t ws_size,
                              hipStream_t stream) {
  const int*   node_ids = (const int*)d_in[0];
  const int*   ei       = (const int*)d_in[1];
  const int*   nei      = (const int*)d_in[2];
  const float* eattr    = (const float*)d_in[3];
  const float* emb      = (const float*)d_in[4];
  const float* W_in     = (const float*)d_in[5];
  const float* b_in     = (const float*)d_in[6];
  const float* W_out    = (const float*)d_in[7];
  const float* b_out    = (const float*)d_in[8];
  const float* W1       = (const float*)d_in[9];
  const float* b1       = (const float*)d_in[10];
  const float* W2       = (const float*)d_in[11];
  const float* b2       = (const float*)d_in[12];
  const float* W3       = (const float*)d_in[13];
  const float* b3       = (const float*)d_in[14];
  float* out = (float*)d_out;

  // workspace layout (floats)
  float* ws    = (float*)d_ws;
  float* bufA  = ws;                          // N*128 f: aggXh/l -> h2 -> Pa
  float* bufB  = bufA + (size_t)NN * 128;     // N*256 f: x1h/l -> [x2h|x2l | Pb]
  int*   cnt1  = (int*)(bufB + (size_t)NN * 256);
  int*   cnt2  = cnt1 + NN;
  float* deg1  = (float*)(cnt2 + NN);
  float* dinv1 = deg1 + NN;
  float* dinv2 = dinv1 + NN;
  int*   off1  = (int*)(dinv2 + NN);          // N+1
  int*   pos1  = off1 + NN + 1;               // N
  int*   off2  = pos1 + NN;                   // N+1
  int*   pos2  = off2 + NN + 1;               // N
  int4*  c1pack = (int4*)((((uintptr_t)(pos2 + NN)) + 15) & ~(uintptr_t)15);  // E
  int2*  c2pack = (int2*)(c1pack + NE);                                       // E
  short* w1th   = (short*)(c2pack + NE);
  short* w1tl   = w1th + 32768;
  short* w2th   = w1tl + 32768;
  short* w2tl   = w2th + 16384;
  short* winth  = w2tl + 16384;
  short* wintl  = winth + 32768;
  short* woutth = wintl + 32768;
  short* wouttl = woutth + 32768;
  int*   part   = (int*)(wouttl + 32768);     // 2*NCHUNK

  short* aggXh = (short*)bufA;                // N*128 shorts
  short* aggXl = aggXh + (size_t)NN * 128;
  float* h2    = bufA;                        // overwrites aggX (dead)
  float* Pa    = bufA;                        // overwrites h2 (dead after agg2)
  short* x1h   = (short*)bufB;                // N*256 shorts
  short* x1l   = x1h + (size_t)NN * 256;
  short* x2h   = (short*)bufB;                // overwrites x1 (dead after gemm2m)
  short* x2l   = x2h + (size_t)NN * 128;
  float* Pb    = bufB + (size_t)NN * 128;     // second half of bufB

  // weight split (W1, W2, W_in^T, W_out^T)
  k_wcvt<<<448, 256, 0, stream>>>(W1, W2, W_in, W_out,
                                  w1th, w1tl, w2th, w2tl,
                                  winth, wintl, woutth, wouttl);

  // CSR build: hist -> dinv -> scan(3-phase) -> fill
  hipMemsetAsync(cnt1, 0, 3 * (size_t)NN * sizeof(int), stream);  // cnt1,cnt2,deg1
  k_hist<<<NE / 256, 256, 0, stream>>>(ei, nei, eattr, cnt1, deg1, cnt2);
  k_dinvs<<<(NN + 255) / 256, 256, 0, stream>>>(deg1, cnt2, dinv1, dinv2);
  k_scan_part<<<2 * NCHUNK, 256, 0, stream>>>(cnt1, cnt2, part);
  k_scan_mid<<<1, 256, 0, stream>>>(part, off1 + NN, off2 + NN);
  k_scan_final<<<2 * NCHUNK, 256, 0, stream>>>(cnt1, cnt2, part,
                                               off1, pos1, off2, pos2);
  k_fill<<<NE / 256, 256, 0, stream>>>(ei, nei, eattr, dinv1, dinv2,
                                       pos1, c1pack, pos2, c2pack);

  // layer 1: aggregate (float4 half-wave, bf16-split out) -> MFMA GEMM + ELU
  k_agg1<<<NN / 4, 256, 0, stream>>>(off1, c1pack, node_ids, emb, aggXh, aggXl);
  k_gemm1m<<<(NN + 31) / 32, 256, 0, stream>>>(aggXh, aggXl, winth, wintl,
                                               b_in, x1h, x1l);

  // layer 2: MFMA GEMM -> aggregate (+bias+ELU+split fused)
  k_gemm2m<<<(NN + 31) / 32, 256, 0, stream>>>(x1h, x1l, woutth, wouttl, h2);
  k_agg2<<<NN / 4, 256, 0, stream>>>(off2, c2pack, h2, b_out, x2h, x2l);

  // decoder layer-1 factorization: Pa/Pb per node (b1 folded into Pb)
  k_pab<<<(NN + 31) / 32, 256, 0, stream>>>(x2h, x2l, w1th, w1tl, b1, Pa, Pb);

  // decoder v8 (unchanged)
  k_decoder<<<NE / 32, 256, 0, stream>>>(Pa, Pb, c1pack,
                                         w2th, w2tl, b2, W3, b3, out);
}